// Round 1
// baseline (1716.423 us; speedup 1.0000x reference)
//
#include <hip/hip_runtime.h>
#include <math.h>

#define Bn 2
#define Cn_ 128
#define Hn 64
#define Wn 64
#define Ln 4096
#define Nn 16

static constexpr float EPS_LN_C = 1e-6f;
static constexpr float EPS_BN_C = 1e-5f;

__device__ __forceinline__ float softplusf_(float x) {
    return fmaxf(x, 0.f) + log1pf(__expf(-fabsf(x)));
}
__device__ __forceinline__ float sigmoidf_(float x) {
    return 1.f / (1.f + __expf(-x));
}

// ---------------- per-pixel LN stats over Cn channels (stride CS) ----------------
__global__ void ln_stats_kernel(const float* __restrict__ in, int CS, int Cc,
                                float* __restrict__ mean, float* __restrict__ rstd,
                                float eps) {
    int b = blockIdx.y;
    int l = blockIdx.x * blockDim.x + threadIdx.x;
    const float* p = in + (size_t)b * CS * Ln + l;
    float s = 0.f, s2 = 0.f;
    for (int c = 0; c < Cc; c++) {
        float v = p[(size_t)c * Ln];
        s += v; s2 += v * v;
    }
    float m = s / (float)Cc;
    float var = fmaxf(s2 / (float)Cc - m * m, 0.f);
    mean[b * Ln + l] = m;
    rstd[b * Ln + l] = 1.f / sqrtf(var + eps);
}

// ---------------- generic 1x1 conv: out[b,o,l] = bias[o] + sum_c w[o,c]*in(c,l) ----------------
// inA: cinA channels (optional per-pixel LN transform), inB: cinB channels appended.
// epilogue: 0 none, 1 BN+ReLU, 2 sigmoid
__global__ void conv1x1_kernel(const float* __restrict__ inA, const float* __restrict__ inB,
                               int cinA, int cinB, int cout,
                               const float* __restrict__ w, const float* __restrict__ bias,
                               const float* __restrict__ lnm, const float* __restrict__ lnr,
                               const float* __restrict__ lnw, const float* __restrict__ lnb,
                               const float* __restrict__ bng, const float* __restrict__ bnbe,
                               const float* __restrict__ bnm, const float* __restrict__ bnv,
                               int epilogue, float* __restrict__ out) {
    int b = blockIdx.z;
    int o0 = blockIdx.y * 8;
    int l = blockIdx.x * blockDim.x + threadIdx.x;
    int cin = cinA + cinB;
    float acc[8];
#pragma unroll
    for (int j = 0; j < 8; j++) acc[j] = bias[o0 + j];
    bool ln = (lnw != nullptr);
    float m = 0.f, r = 0.f;
    if (ln) { m = lnm[b * Ln + l]; r = lnr[b * Ln + l]; }
    const float* pa = inA + (size_t)b * cinA * Ln + l;
    for (int c = 0; c < cinA; c++) {
        float v = pa[(size_t)c * Ln];
        if (ln) v = (v - m) * r * lnw[c] + lnb[c];
#pragma unroll
        for (int j = 0; j < 8; j++) acc[j] = fmaf(w[(o0 + j) * cin + c], v, acc[j]);
    }
    if (inB) {
        const float* pb = inB + (size_t)b * cinB * Ln + l;
        for (int c = 0; c < cinB; c++) {
            float v = pb[(size_t)c * Ln];
#pragma unroll
            for (int j = 0; j < 8; j++) acc[j] = fmaf(w[(o0 + j) * cin + cinA + c], v, acc[j]);
        }
    }
#pragma unroll
    for (int j = 0; j < 8; j++) {
        float v = acc[j];
        int o = o0 + j;
        if (epilogue == 1) {
            v = (v - bnm[o]) * (1.f / sqrtf(bnv[o] + EPS_BN_C)) * bng[o] + bnbe[o];
            v = fmaxf(v, 0.f);
        } else if (epilogue == 2) {
            v = sigmoidf_(v);
        }
        out[((size_t)b * cout + o) * Ln + l] = v;
    }
}

// ---------------- depthwise 3x3 SAME + bias + SiLU; LN applied to first-128 channels' input ----------------
__global__ void dwconv_kernel(const float* __restrict__ xp,
                              const float* __restrict__ mean1, const float* __restrict__ rstd1,
                              const float* __restrict__ lnw, const float* __restrict__ lnb,
                              const float* __restrict__ wm, const float* __restrict__ bm,
                              const float* __restrict__ wr, const float* __restrict__ br,
                              float* __restrict__ xm, float* __restrict__ xr) {
    int b = blockIdx.z;
    int c2 = blockIdx.y;
    int l = blockIdx.x * blockDim.x + threadIdx.x;
    int h = l >> 6, w = l & 63;
    bool mamba = (c2 < 128);
    const float* in = xp + ((size_t)b * 256 + c2) * Ln;
    const float* wt = mamba ? (wm + c2 * 9) : (wr + (c2 - 128) * 9);
    float lw = 0.f, lbv = 0.f;
    if (mamba) { lw = lnw[c2]; lbv = lnb[c2]; }
    float acc = mamba ? bm[c2] : br[c2 - 128];
#pragma unroll
    for (int dh = -1; dh <= 1; dh++) {
#pragma unroll
        for (int dw = -1; dw <= 1; dw++) {
            int hh = h + dh, ww = w + dw;
            if (hh < 0 || hh > 63 || ww < 0 || ww > 63) continue;
            int l2 = hh * 64 + ww;
            float v = in[l2];
            if (mamba) v = (v - mean1[b * Ln + l2]) * rstd1[b * Ln + l2] * lw + lbv;
            acc = fmaf(v, wt[(dh + 1) * 3 + (dw + 1)], acc);
        }
    }
    float o = acc * sigmoidf_(acc);
    if (mamba) xm[((size_t)b * 128 + c2) * Ln + l] = o;
    else       xr[((size_t)b * 128 + (c2 - 128)) * Ln + l] = o;
}

// ---------------- counting sort (4 classes) per batch; within class, index DESCENDING ----------------
__global__ __launch_bounds__(1024) void sort_kernel(const float* __restrict__ mfg,
                                                    const float* __restrict__ mbg,
                                                    const float* __restrict__ muc,
                                                    int* __restrict__ sidx) {
    int b = blockIdx.x;
    int t = threadIdx.x;                 // 0..1023
    const int PT = 4;                    // 4096/1024
    __shared__ unsigned int wsum0[16], wsum1[16];
    __shared__ unsigned int tot01s, tot23s;

    int cls[PT];
    unsigned int c01 = 0, c23 = 0;       // low16=class0/2 count, high16=class1/3
#pragma unroll
    for (int q = 0; q < PT; q++) {
        int j = t * PT + q;
        int i = Ln - 1 - j;              // j ascending == index descending (stable order)
        float f = mfg[b * Ln + i], g = mbg[b * Ln + i], u = muc[b * Ln + i];
        int k = (f > 0.5f) ? 3 : (g > 0.5f) ? 2 : (u > 0.5f) ? 1 : 0;
        cls[q] = k;
        if (k == 0) c01 += 1u;
        else if (k == 1) c01 += (1u << 16);
        else if (k == 2) c23 += 1u;
        else c23 += (1u << 16);
    }
    unsigned int s01 = c01, s23 = c23;
    int lane = t & 63;
    for (int d = 1; d < 64; d <<= 1) {
        unsigned int o01 = __shfl_up(s01, (unsigned)d, 64);
        unsigned int o23 = __shfl_up(s23, (unsigned)d, 64);
        if (lane >= d) { s01 += o01; s23 += o23; }
    }
    int wid = t >> 6;                    // 16 waves
    if (lane == 63) { wsum0[wid] = s01; wsum1[wid] = s23; }
    __syncthreads();
    if (t == 0) {
        unsigned int a0 = 0, a1 = 0;
        for (int k2 = 0; k2 < 16; k2++) {
            unsigned int v0 = wsum0[k2], v1 = wsum1[k2];
            wsum0[k2] = a0; wsum1[k2] = a1;
            a0 += v0; a1 += v1;
        }
        tot01s = a0; tot23s = a1;
    }
    __syncthreads();
    unsigned int ex01 = s01 - c01 + wsum0[wid];
    unsigned int ex23 = s23 - c23 + wsum1[wid];
    unsigned int cnt1 = tot01s >> 16;
    unsigned int cnt2 = tot23s & 0xffffu, cnt3 = tot23s >> 16;
    unsigned int off3 = 0, off2 = cnt3, off1 = cnt3 + cnt2, off0 = cnt3 + cnt2 + cnt1;
    unsigned int run0 = ex01 & 0xffffu, run1 = ex01 >> 16;
    unsigned int run2 = ex23 & 0xffffu, run3 = ex23 >> 16;
#pragma unroll
    for (int q = 0; q < PT; q++) {
        int j = t * PT + q;
        int i = Ln - 1 - j;
        int k = cls[q];
        unsigned int pos;
        if (k == 0) pos = off0 + run0++;
        else if (k == 1) pos = off1 + run1++;
        else if (k == 2) pos = off2 + run2++;
        else pos = off3 + run3++;
        sidx[b * Ln + pos] = i;
    }
}

// ---------------- x_proj + dt_proj + softplus for fwd/bwd branches (pointwise per pixel) ----------------
__global__ void xproj_fb_kernel(const float* __restrict__ xm,
                                const float* __restrict__ xwf, const float* __restrict__ xbf,
                                const float* __restrict__ dtwf, const float* __restrict__ dtbf,
                                const float* __restrict__ xwb, const float* __restrict__ xbb,
                                const float* __restrict__ dtwb, const float* __restrict__ dtbb,
                                float* __restrict__ df, float* __restrict__ bsf, float* __restrict__ csf,
                                float* __restrict__ db, float* __restrict__ bsb, float* __restrict__ csb) {
    int br = blockIdx.z;                 // 0 = fwd (ch 0..63), 1 = bwd (ch 64..127)
    int b = blockIdx.y;
    int l = blockIdx.x * blockDim.x + threadIdx.x;
    const float* xw = br ? xwb : xwf;
    const float* xb = br ? xbb : xbf;
    const float* dtw = br ? dtwb : dtwf;
    const float* dtb = br ? dtbb : dtbf;
    float* dd = br ? db : df;
    float* bb = br ? bsb : bsf;
    float* cc = br ? csb : csf;
    const float* up = xm + ((size_t)b * 128 + br * 64) * Ln + l;
    float acc[36];
#pragma unroll
    for (int j = 0; j < 36; j++) acc[j] = xb[j];
    for (int c = 0; c < 64; c++) {
        float u = up[(size_t)c * Ln];
#pragma unroll
        for (int j = 0; j < 36; j++) acc[j] = fmaf(xw[j * 64 + c], u, acc[j]);
    }
    for (int c = 0; c < 64; c++) {
        float d = dtb[c];
#pragma unroll
        for (int r = 0; r < 4; r++) d = fmaf(dtw[c * 4 + r], acc[r], d);
        dd[((size_t)b * 64 + c) * Ln + l] = softplusf_(d);
    }
#pragma unroll
    for (int n2 = 0; n2 < 16; n2++) {
        bb[((size_t)b * 16 + n2) * Ln + l] = acc[4 + n2];
        cc[((size_t)b * 16 + n2) * Ln + l] = acc[20 + n2];
    }
}

// ---------------- gathered x_proj for SID branch ----------------
__global__ void xproj_s_kernel(const float* __restrict__ xm, const int* __restrict__ sidx,
                               const float* __restrict__ xw, const float* __restrict__ xb,
                               const float* __restrict__ dtw, const float* __restrict__ dtb,
                               float* __restrict__ us, float* __restrict__ ds,
                               float* __restrict__ bss, float* __restrict__ css) {
    int b = blockIdx.y;
    int t = blockIdx.x * blockDim.x + threadIdx.x;
    int pix = sidx[b * Ln + t];
    float acc[40];
#pragma unroll
    for (int j = 0; j < 40; j++) acc[j] = xb[j];
    for (int c = 0; c < 128; c++) {
        float u = xm[((size_t)b * 128 + c) * Ln + pix];
        us[((size_t)b * 128 + c) * Ln + t] = u;
#pragma unroll
        for (int j = 0; j < 40; j++) acc[j] = fmaf(xw[j * 128 + c], u, acc[j]);
    }
    for (int c = 0; c < 128; c++) {
        float d = dtb[c];
#pragma unroll
        for (int r = 0; r < 8; r++) d = fmaf(dtw[c * 8 + r], acc[r], d);
        ds[((size_t)b * 128 + c) * Ln + t] = softplusf_(d);
    }
#pragma unroll
    for (int n2 = 0; n2 < 16; n2++) {
        bss[((size_t)b * 16 + n2) * Ln + t] = acc[8 + n2];
        css[((size_t)b * 16 + n2) * Ln + t] = acc[24 + n2];
    }
}

// ---------------- the three selective scans, one kernel, 128 waves total ----------------
__global__ __launch_bounds__(256) void scan_kernel(
    const float* __restrict__ xm, const float* __restrict__ us,
    const float* __restrict__ df, const float* __restrict__ bsf, const float* __restrict__ csf,
    const float* __restrict__ Alf, const float* __restrict__ Dfp,
    const float* __restrict__ db, const float* __restrict__ bsb, const float* __restrict__ csb,
    const float* __restrict__ Alb, const float* __restrict__ Dbp,
    const float* __restrict__ dsd, const float* __restrict__ bss, const float* __restrict__ css,
    const float* __restrict__ Als, const float* __restrict__ Dsp,
    const int* __restrict__ sidx,
    float* __restrict__ yf, float* __restrict__ yb, float* __restrict__ ys) {
    int g = blockIdx.x * 4 + (threadIdx.x >> 6);
    int lane = threadIdx.x & 63;
    int n = lane & 15, cl = lane >> 4;
    const float *up, *dp, *bp, *cp, *Ap, *Dp;
    float* yp;
    const int* sp = nullptr;
    int b, c;
    int rev = 0;
    if (g < 32) {                         // forward branch
        b = g >> 4; int cg = g & 15; c = cg * 4 + cl;
        up = xm + ((size_t)b * 128 + c) * Ln;
        dp = df + ((size_t)b * 64 + c) * Ln;
        bp = bsf + ((size_t)b * 16 + n) * Ln;
        cp = csf + ((size_t)b * 16 + n) * Ln;
        Ap = Alf; Dp = Dfp;
        yp = yf + ((size_t)b * 64 + c) * Ln;
    } else if (g < 64) {                  // backward branch
        int g2 = g - 32; b = g2 >> 4; int cg = g2 & 15; c = cg * 4 + cl;
        up = xm + ((size_t)b * 128 + 64 + c) * Ln;
        dp = db + ((size_t)b * 64 + c) * Ln;
        bp = bsb + ((size_t)b * 16 + n) * Ln;
        cp = csb + ((size_t)b * 16 + n) * Ln;
        Ap = Alb; Dp = Dbp;
        yp = yb + ((size_t)b * 64 + c) * Ln;
        rev = 1;
    } else {                              // SID branch
        int g2 = g - 64; b = g2 >> 5; int cg = g2 & 31; c = cg * 4 + cl;
        up = us + ((size_t)b * 128 + c) * Ln;
        dp = dsd + ((size_t)b * 128 + c) * Ln;
        bp = bss + ((size_t)b * 16 + n) * Ln;
        cp = css + ((size_t)b * 16 + n) * Ln;
        Ap = Als; Dp = Dsp;
        yp = ys + ((size_t)b * 128 + c) * Ln;
        sp = sidx + b * Ln;
    }
    float A = -__expf(Ap[c * 16 + n]);
    float Dc = Dp[c];
    float h = 0.f;

    auto step = [&](float u, float dl, float Bv, float Cv, int l) {
        float dA = __expf(dl * A);
        h = fmaf(dA, h, dl * u * Bv);
        float p = h * Cv;
        p += __shfl_xor(p, 1);
        p += __shfl_xor(p, 2);
        p += __shfl_xor(p, 4);
        p += __shfl_xor(p, 8);
        if (n == 0) {
            int ol = sp ? sp[l] : l;
            yp[ol] = fmaf(u, Dc, p);
        }
    };

    if (!rev) {
        for (int base = 0; base < Ln; base += 4) {
            float4 u4 = *(const float4*)(up + base);
            float4 d4 = *(const float4*)(dp + base);
            float4 b4 = *(const float4*)(bp + base);
            float4 c4 = *(const float4*)(cp + base);
            step(u4.x, d4.x, b4.x, c4.x, base);
            step(u4.y, d4.y, b4.y, c4.y, base + 1);
            step(u4.z, d4.z, b4.z, c4.z, base + 2);
            step(u4.w, d4.w, b4.w, c4.w, base + 3);
        }
    } else {
        for (int base = Ln - 4; base >= 0; base -= 4) {
            float4 u4 = *(const float4*)(up + base);
            float4 d4 = *(const float4*)(dp + base);
            float4 b4 = *(const float4*)(bp + base);
            float4 c4 = *(const float4*)(cp + base);
            step(u4.w, d4.w, b4.w, c4.w, base + 3);
            step(u4.z, d4.z, b4.z, c4.z, base + 2);
            step(u4.y, d4.y, b4.y, c4.y, base + 1);
            step(u4.x, d4.x, b4.x, c4.x, base);
        }
    }
}

// ---------------- LN over concat(yf, yb) ----------------
__global__ void cat_ln_kernel(const float* __restrict__ yf, const float* __restrict__ yb,
                              const float* __restrict__ lw, const float* __restrict__ lb,
                              float* __restrict__ out) {
    int b = blockIdx.y;
    int l = blockIdx.x * blockDim.x + threadIdx.x;
    const float* pf = yf + (size_t)b * 64 * Ln + l;
    const float* pb = yb + (size_t)b * 64 * Ln + l;
    float s = 0.f, s2 = 0.f;
    for (int c = 0; c < 64; c++) { float v = pf[(size_t)c * Ln]; s += v; s2 += v * v; }
    for (int c = 0; c < 64; c++) { float v = pb[(size_t)c * Ln]; s += v; s2 += v * v; }
    float m = s / 128.f;
    float var = fmaxf(s2 / 128.f - m * m, 0.f);
    float r = 1.f / sqrtf(var + EPS_LN_C);
    for (int c = 0; c < 64; c++)
        out[((size_t)b * 128 + c) * Ln + l] = (pf[(size_t)c * Ln] - m) * r * lw[c] + lb[c];
    for (int c = 0; c < 64; c++)
        out[((size_t)b * 128 + 64 + c) * Ln + l] = (pb[(size_t)c * Ln] - m) * r * lw[64 + c] + lb[64 + c];
}

// ---------------- fused = g*sid + (1-g)*cat ----------------
__global__ void fuse_kernel(const float* __restrict__ gate, const float* __restrict__ ysb,
                            const float* __restrict__ cat, float* __restrict__ out, int ntot) {
    int i = blockIdx.x * blockDim.x + threadIdx.x;
    if (i < ntot) {
        float g = gate[i];
        out[i] = g * ysb[i] + (1.f - g) * cat[i];
    }
}

// ---------------- final LN -> d_out ----------------
__global__ void lnout_kernel(const float* __restrict__ in, const float* __restrict__ lw,
                             const float* __restrict__ lb, float* __restrict__ out) {
    int b = blockIdx.y;
    int l = blockIdx.x * blockDim.x + threadIdx.x;
    const float* p = in + (size_t)b * 128 * Ln + l;
    float s = 0.f, s2 = 0.f;
    for (int c = 0; c < 128; c++) { float v = p[(size_t)c * Ln]; s += v; s2 += v * v; }
    float m = s / 128.f;
    float var = fmaxf(s2 / 128.f - m * m, 0.f);
    float r = 1.f / sqrtf(var + EPS_LN_C);
    for (int c = 0; c < 128; c++)
        out[((size_t)b * 128 + c) * Ln + l] = (p[(size_t)c * Ln] - m) * r * lw[c] + lb[c];
}

extern "C" void kernel_launch(void* const* d_in, const int* in_sizes, int n_in,
                              void* d_out, int out_size, void* d_ws, size_t ws_size,
                              hipStream_t stream) {
    const float* x    = (const float*)d_in[0];
    const float* mfg  = (const float*)d_in[1];
    const float* mbg  = (const float*)d_in[2];
    const float* muc  = (const float*)d_in[3];
    const float* niw  = (const float*)d_in[4];
    const float* nib  = (const float*)d_in[5];
    const float* inw  = (const float*)d_in[6];
    const float* inb  = (const float*)d_in[7];
    const float* lmw  = (const float*)d_in[8];
    const float* lmb  = (const float*)d_in[9];
    const float* cmw  = (const float*)d_in[10];
    const float* cmb  = (const float*)d_in[11];
    const float* crw  = (const float*)d_in[12];
    const float* crb  = (const float*)d_in[13];
    const float* xwf  = (const float*)d_in[14];
    const float* xbf  = (const float*)d_in[15];
    const float* dtwf = (const float*)d_in[16];
    const float* dtbf = (const float*)d_in[17];
    const float* Alf  = (const float*)d_in[18];
    const float* Dfp  = (const float*)d_in[19];
    const float* xwb  = (const float*)d_in[20];
    const float* xbb  = (const float*)d_in[21];
    const float* dtwb = (const float*)d_in[22];
    const float* dtbb = (const float*)d_in[23];
    const float* Alb  = (const float*)d_in[24];
    const float* Dbp  = (const float*)d_in[25];
    const float* xws  = (const float*)d_in[26];
    const float* xbs  = (const float*)d_in[27];
    const float* dtws = (const float*)d_in[28];
    const float* dtbs = (const float*)d_in[29];
    const float* Als  = (const float*)d_in[30];
    const float* Dsp  = (const float*)d_in[31];
    const float* lcw  = (const float*)d_in[32];
    const float* lcb  = (const float*)d_in[33];
    const float* g0w  = (const float*)d_in[34];
    const float* g0b  = (const float*)d_in[35];
    const float* bng  = (const float*)d_in[36];
    const float* bnbe = (const float*)d_in[37];
    const float* bnm  = (const float*)d_in[38];
    const float* bnv  = (const float*)d_in[39];
    const float* g1w  = (const float*)d_in[40];
    const float* g1b  = (const float*)d_in[41];
    const float* outw = (const float*)d_in[42];
    const float* outb = (const float*)d_in[43];
    const float* now  = (const float*)d_in[44];
    const float* nob  = (const float*)d_in[45];

    float* W = (float*)d_ws;
    // offsets in floats
    const size_t O_XP    = 0;          // 2,097,152  (later reused: FUSED @0, OUTB @+1M)
    const size_t O_MEAN0 = 2097152;    // 8192
    const size_t O_RSTD0 = 2105344;
    const size_t O_MEAN1 = 2113536;
    const size_t O_RSTD1 = 2121728;
    const size_t O_XM    = 2129920;    // 1,048,576
    const size_t O_XR    = 3178496;    // 1,048,576
    const size_t O_DF    = 4227072;    // 524,288   (later: CATLN spans DF+DB)
    const size_t O_DB    = 4751360;    // 524,288
    const size_t O_BSF   = 5275648;    // 131,072
    const size_t O_CSF   = 5406720;
    const size_t O_BSB   = 5537792;
    const size_t O_CSB   = 5668864;
    const size_t O_US    = 5799936;    // 1,048,576 (later: GATE)
    const size_t O_DS    = 6848512;    // 1,048,576 (later: GBUF)
    const size_t O_BSS   = 7897088;
    const size_t O_CSS   = 8028160;
    const size_t O_YF    = 8159232;    // 524,288
    const size_t O_YB    = 8683520;
    const size_t O_YS    = 9207808;    // 1,048,576
    const size_t O_IDX   = 10256384;   // 8192 ints
    const size_t O_CATLN = O_DF;
    const size_t O_GBUF  = O_DS;
    const size_t O_GATE  = O_US;
    const size_t O_FUSED = O_XP;
    const size_t O_OUTB  = O_XP + 1048576;

    int* idxp = (int*)(W + O_IDX);
    dim3 blk(256);

    // 1. LN stats of input x
    ln_stats_kernel<<<dim3(16, 2), blk, 0, stream>>>(x, 128, 128, W + O_MEAN0, W + O_RSTD0, EPS_LN_C);
    // 2. in_proj (with input LN applied on the fly) -> xp (B,256,L)
    conv1x1_kernel<<<dim3(16, 32, 2), blk, 0, stream>>>(
        x, nullptr, 128, 0, 256, inw, inb,
        W + O_MEAN0, W + O_RSTD0, niw, nib,
        nullptr, nullptr, nullptr, nullptr, 0, W + O_XP);
    // 3. LN stats of x_mamba (xp channels 0..127)
    ln_stats_kernel<<<dim3(16, 2), blk, 0, stream>>>(W + O_XP, 256, 128, W + O_MEAN1, W + O_RSTD1, EPS_LN_C);
    // 4. depthwise 3x3 + SiLU for both halves -> xm, xr
    dwconv_kernel<<<dim3(16, 256, 2), blk, 0, stream>>>(
        W + O_XP, W + O_MEAN1, W + O_RSTD1, lmw, lmb, cmw, cmb, crw, crb, W + O_XM, W + O_XR);
    // 5. priority counting sort -> sorted_idx
    sort_kernel<<<2, 1024, 0, stream>>>(mfg, mbg, muc, idxp);
    // 6. x_proj + dt_proj fwd/bwd
    xproj_fb_kernel<<<dim3(16, 2, 2), blk, 0, stream>>>(
        W + O_XM, xwf, xbf, dtwf, dtbf, xwb, xbb, dtwb, dtbb,
        W + O_DF, W + O_BSF, W + O_CSF, W + O_DB, W + O_BSB, W + O_CSB);
    // 7. gathered x_proj for SID
    xproj_s_kernel<<<dim3(16, 2), blk, 0, stream>>>(
        W + O_XM, idxp, xws, xbs, dtws, dtbs, W + O_US, W + O_DS, W + O_BSS, W + O_CSS);
    // 8. all three selective scans
    scan_kernel<<<32, blk, 0, stream>>>(
        W + O_XM, W + O_US,
        W + O_DF, W + O_BSF, W + O_CSF, Alf, Dfp,
        W + O_DB, W + O_BSB, W + O_CSB, Alb, Dbp,
        W + O_DS, W + O_BSS, W + O_CSS, Als, Dsp,
        idxp, W + O_YF, W + O_YB, W + O_YS);
    // 9. LN of concat(y_f, y_b)
    cat_ln_kernel<<<dim3(16, 2), blk, 0, stream>>>(W + O_YF, W + O_YB, lcw, lcb, W + O_CATLN);
    // 10. g0 conv + BN + ReLU
    conv1x1_kernel<<<dim3(16, 16, 2), blk, 0, stream>>>(
        W + O_CATLN, W + O_YS, 128, 128, 128, g0w, g0b,
        nullptr, nullptr, nullptr, nullptr, bng, bnbe, bnm, bnv, 1, W + O_GBUF);
    // 11. g1 conv + sigmoid -> gate
    conv1x1_kernel<<<dim3(16, 16, 2), blk, 0, stream>>>(
        W + O_GBUF, nullptr, 128, 0, 128, g1w, g1b,
        nullptr, nullptr, nullptr, nullptr, nullptr, nullptr, nullptr, nullptr, 2, W + O_GATE);
    // 12. fused = g*sid + (1-g)*concat
    fuse_kernel<<<4096, blk, 0, stream>>>(W + O_GATE, W + O_YS, W + O_CATLN, W + O_FUSED, Bn * Cn_ * Ln);
    // 13. out conv
    conv1x1_kernel<<<dim3(16, 16, 2), blk, 0, stream>>>(
        W + O_FUSED, W + O_XR, 128, 128, 128, outw, outb,
        nullptr, nullptr, nullptr, nullptr, nullptr, nullptr, nullptr, nullptr, 0, W + O_OUTB);
    // 14. final LN -> d_out
    lnout_kernel<<<dim3(16, 2), blk, 0, stream>>>(W + O_OUTB, now, nob, (float*)d_out);
}

// Round 2
// 803.968 us; speedup vs baseline: 2.1349x; 2.1349x over previous
//
#include <hip/hip_runtime.h>
#include <math.h>

#define Bn 2
#define Cn_ 128
#define Hn 64
#define Wn 64
#define Ln 4096
#define Nn 16

static constexpr float EPS_LN_C = 1e-6f;
static constexpr float EPS_BN_C = 1e-5f;

__device__ __forceinline__ float softplusf_(float x) {
    return fmaxf(x, 0.f) + log1pf(__expf(-fabsf(x)));
}
__device__ __forceinline__ float sigmoidf_(float x) {
    return 1.f / (1.f + __expf(-x));
}

// ---------------- per-pixel LN stats over Cn channels (stride CS) ----------------
__global__ void ln_stats_kernel(const float* __restrict__ in, int CS, int Cc,
                                float* __restrict__ mean, float* __restrict__ rstd,
                                float eps) {
    int b = blockIdx.y;
    int l = blockIdx.x * blockDim.x + threadIdx.x;
    const float* p = in + (size_t)b * CS * Ln + l;
    float s = 0.f, s2 = 0.f;
    for (int c = 0; c < Cc; c++) {
        float v = p[(size_t)c * Ln];
        s += v; s2 += v * v;
    }
    float m = s / (float)Cc;
    float var = fmaxf(s2 / (float)Cc - m * m, 0.f);
    mean[b * Ln + l] = m;
    rstd[b * Ln + l] = 1.f / sqrtf(var + eps);
}

// ---------------- generic 1x1 conv ----------------
__global__ void conv1x1_kernel(const float* __restrict__ inA, const float* __restrict__ inB,
                               int cinA, int cinB, int cout,
                               const float* __restrict__ w, const float* __restrict__ bias,
                               const float* __restrict__ lnm, const float* __restrict__ lnr,
                               const float* __restrict__ lnw, const float* __restrict__ lnb,
                               const float* __restrict__ bng, const float* __restrict__ bnbe,
                               const float* __restrict__ bnm, const float* __restrict__ bnv,
                               int epilogue, float* __restrict__ out) {
    int b = blockIdx.z;
    int o0 = blockIdx.y * 8;
    int l = blockIdx.x * blockDim.x + threadIdx.x;
    int cin = cinA + cinB;
    float acc[8];
#pragma unroll
    for (int j = 0; j < 8; j++) acc[j] = bias[o0 + j];
    bool ln = (lnw != nullptr);
    float m = 0.f, r = 0.f;
    if (ln) { m = lnm[b * Ln + l]; r = lnr[b * Ln + l]; }
    const float* pa = inA + (size_t)b * cinA * Ln + l;
    for (int c = 0; c < cinA; c++) {
        float v = pa[(size_t)c * Ln];
        if (ln) v = (v - m) * r * lnw[c] + lnb[c];
#pragma unroll
        for (int j = 0; j < 8; j++) acc[j] = fmaf(w[(o0 + j) * cin + c], v, acc[j]);
    }
    if (inB) {
        const float* pb = inB + (size_t)b * cinB * Ln + l;
        for (int c = 0; c < cinB; c++) {
            float v = pb[(size_t)c * Ln];
#pragma unroll
            for (int j = 0; j < 8; j++) acc[j] = fmaf(w[(o0 + j) * cin + cinA + c], v, acc[j]);
        }
    }
#pragma unroll
    for (int j = 0; j < 8; j++) {
        float v = acc[j];
        int o = o0 + j;
        if (epilogue == 1) {
            v = (v - bnm[o]) * (1.f / sqrtf(bnv[o] + EPS_BN_C)) * bng[o] + bnbe[o];
            v = fmaxf(v, 0.f);
        } else if (epilogue == 2) {
            v = sigmoidf_(v);
        }
        out[((size_t)b * cout + o) * Ln + l] = v;
    }
}

// ---------------- depthwise 3x3 SAME + bias + SiLU ----------------
__global__ void dwconv_kernel(const float* __restrict__ xp,
                              const float* __restrict__ mean1, const float* __restrict__ rstd1,
                              const float* __restrict__ lnw, const float* __restrict__ lnb,
                              const float* __restrict__ wm, const float* __restrict__ bm,
                              const float* __restrict__ wr, const float* __restrict__ br,
                              float* __restrict__ xm, float* __restrict__ xr) {
    int b = blockIdx.z;
    int c2 = blockIdx.y;
    int l = blockIdx.x * blockDim.x + threadIdx.x;
    int h = l >> 6, w = l & 63;
    bool mamba = (c2 < 128);
    const float* in = xp + ((size_t)b * 256 + c2) * Ln;
    const float* wt = mamba ? (wm + c2 * 9) : (wr + (c2 - 128) * 9);
    float lw = 0.f, lbv = 0.f;
    if (mamba) { lw = lnw[c2]; lbv = lnb[c2]; }
    float acc = mamba ? bm[c2] : br[c2 - 128];
#pragma unroll
    for (int dh = -1; dh <= 1; dh++) {
#pragma unroll
        for (int dw = -1; dw <= 1; dw++) {
            int hh = h + dh, ww = w + dw;
            if (hh < 0 || hh > 63 || ww < 0 || ww > 63) continue;
            int l2 = hh * 64 + ww;
            float v = in[l2];
            if (mamba) v = (v - mean1[b * Ln + l2]) * rstd1[b * Ln + l2] * lw + lbv;
            acc = fmaf(v, wt[(dh + 1) * 3 + (dw + 1)], acc);
        }
    }
    float o = acc * sigmoidf_(acc);
    if (mamba) xm[((size_t)b * 128 + c2) * Ln + l] = o;
    else       xr[((size_t)b * 128 + (c2 - 128)) * Ln + l] = o;
}

// ---------------- counting sort (4 classes) per batch; within class, index DESCENDING ----------------
__global__ __launch_bounds__(1024) void sort_kernel(const float* __restrict__ mfg,
                                                    const float* __restrict__ mbg,
                                                    const float* __restrict__ muc,
                                                    int* __restrict__ sidx) {
    int b = blockIdx.x;
    int t = threadIdx.x;                 // 0..1023
    const int PT = 4;                    // 4096/1024
    __shared__ unsigned int wsum0[16], wsum1[16];
    __shared__ unsigned int tot01s, tot23s;

    int cls[PT];
    unsigned int c01 = 0, c23 = 0;
#pragma unroll
    for (int q = 0; q < PT; q++) {
        int j = t * PT + q;
        int i = Ln - 1 - j;              // j ascending == index descending (stable order)
        float f = mfg[b * Ln + i], g = mbg[b * Ln + i], u = muc[b * Ln + i];
        int k = (f > 0.5f) ? 3 : (g > 0.5f) ? 2 : (u > 0.5f) ? 1 : 0;
        cls[q] = k;
        if (k == 0) c01 += 1u;
        else if (k == 1) c01 += (1u << 16);
        else if (k == 2) c23 += 1u;
        else c23 += (1u << 16);
    }
    unsigned int s01 = c01, s23 = c23;
    int lane = t & 63;
    for (int d = 1; d < 64; d <<= 1) {
        unsigned int o01 = __shfl_up(s01, (unsigned)d, 64);
        unsigned int o23 = __shfl_up(s23, (unsigned)d, 64);
        if (lane >= d) { s01 += o01; s23 += o23; }
    }
    int wid = t >> 6;                    // 16 waves
    if (lane == 63) { wsum0[wid] = s01; wsum1[wid] = s23; }
    __syncthreads();
    if (t == 0) {
        unsigned int a0 = 0, a1 = 0;
        for (int k2 = 0; k2 < 16; k2++) {
            unsigned int v0 = wsum0[k2], v1 = wsum1[k2];
            wsum0[k2] = a0; wsum1[k2] = a1;
            a0 += v0; a1 += v1;
        }
        tot01s = a0; tot23s = a1;
    }
    __syncthreads();
    unsigned int ex01 = s01 - c01 + wsum0[wid];
    unsigned int ex23 = s23 - c23 + wsum1[wid];
    unsigned int cnt1 = tot01s >> 16;
    unsigned int cnt2 = tot23s & 0xffffu, cnt3 = tot23s >> 16;
    unsigned int off3 = 0, off2 = cnt3, off1 = cnt3 + cnt2, off0 = cnt3 + cnt2 + cnt1;
    unsigned int run0 = ex01 & 0xffffu, run1 = ex01 >> 16;
    unsigned int run2 = ex23 & 0xffffu, run3 = ex23 >> 16;
#pragma unroll
    for (int q = 0; q < PT; q++) {
        int j = t * PT + q;
        int i = Ln - 1 - j;
        int k = cls[q];
        unsigned int pos;
        if (k == 0) pos = off0 + run0++;
        else if (k == 1) pos = off1 + run1++;
        else if (k == 2) pos = off2 + run2++;
        else pos = off3 + run3++;
        sidx[b * Ln + pos] = i;
    }
}

// ---------------- x_proj + dt_proj + softplus for fwd/bwd branches ----------------
__global__ void xproj_fb_kernel(const float* __restrict__ xm,
                                const float* __restrict__ xwf, const float* __restrict__ xbf,
                                const float* __restrict__ dtwf, const float* __restrict__ dtbf,
                                const float* __restrict__ xwb, const float* __restrict__ xbb,
                                const float* __restrict__ dtwb, const float* __restrict__ dtbb,
                                float* __restrict__ df, float* __restrict__ bsf, float* __restrict__ csf,
                                float* __restrict__ db, float* __restrict__ bsb, float* __restrict__ csb) {
    int br = blockIdx.z;
    int b = blockIdx.y;
    int l = blockIdx.x * blockDim.x + threadIdx.x;
    const float* xw = br ? xwb : xwf;
    const float* xb = br ? xbb : xbf;
    const float* dtw = br ? dtwb : dtwf;
    const float* dtb = br ? dtbb : dtbf;
    float* dd = br ? db : df;
    float* bb = br ? bsb : bsf;
    float* cc = br ? csb : csf;
    const float* up = xm + ((size_t)b * 128 + br * 64) * Ln + l;
    float acc[36];
#pragma unroll
    for (int j = 0; j < 36; j++) acc[j] = xb[j];
    for (int c = 0; c < 64; c++) {
        float u = up[(size_t)c * Ln];
#pragma unroll
        for (int j = 0; j < 36; j++) acc[j] = fmaf(xw[j * 64 + c], u, acc[j]);
    }
    for (int c = 0; c < 64; c++) {
        float d = dtb[c];
#pragma unroll
        for (int r = 0; r < 4; r++) d = fmaf(dtw[c * 4 + r], acc[r], d);
        dd[((size_t)b * 64 + c) * Ln + l] = softplusf_(d);
    }
#pragma unroll
    for (int n2 = 0; n2 < 16; n2++) {
        bb[((size_t)b * 16 + n2) * Ln + l] = acc[4 + n2];
        cc[((size_t)b * 16 + n2) * Ln + l] = acc[20 + n2];
    }
}

// ---------------- gathered x_proj for SID branch ----------------
__global__ void xproj_s_kernel(const float* __restrict__ xm, const int* __restrict__ sidx,
                               const float* __restrict__ xw, const float* __restrict__ xb,
                               const float* __restrict__ dtw, const float* __restrict__ dtb,
                               float* __restrict__ us, float* __restrict__ ds,
                               float* __restrict__ bss, float* __restrict__ css) {
    int b = blockIdx.y;
    int t = blockIdx.x * blockDim.x + threadIdx.x;
    int pix = sidx[b * Ln + t];
    float acc[40];
#pragma unroll
    for (int j = 0; j < 40; j++) acc[j] = xb[j];
    for (int c = 0; c < 128; c++) {
        float u = xm[((size_t)b * 128 + c) * Ln + pix];
        us[((size_t)b * 128 + c) * Ln + t] = u;
#pragma unroll
        for (int j = 0; j < 40; j++) acc[j] = fmaf(xw[j * 128 + c], u, acc[j]);
    }
    for (int c = 0; c < 128; c++) {
        float d = dtb[c];
#pragma unroll
        for (int r = 0; r < 8; r++) d = fmaf(dtw[c * 8 + r], acc[r], d);
        ds[((size_t)b * 128 + c) * Ln + t] = softplusf_(d);
    }
#pragma unroll
    for (int n2 = 0; n2 < 16; n2++) {
        bss[((size_t)b * 16 + n2) * Ln + t] = acc[8 + n2];
        css[((size_t)b * 16 + n2) * Ln + t] = acc[24 + n2];
    }
}

// ================= selective scans: DPP lane-reduce + double-buffered prefetch =================
// 16-lane full reduction entirely on the VALU:
//   quad_perm xor1 (0xB1), quad_perm xor2 (0x4E), row_ror:4 (0x124), row_ror:8 (0x128).
// After these 4 add-rounds every lane of the 16-lane row holds the row sum. No LDS, no lgkmcnt.
#define DPPADD(p) do { \
    p += __int_as_float(__builtin_amdgcn_update_dpp(0, __float_as_int(p), 0xB1, 0xF, 0xF, true)); \
    p += __int_as_float(__builtin_amdgcn_update_dpp(0, __float_as_int(p), 0x4E, 0xF, 0xF, true)); \
    p += __int_as_float(__builtin_amdgcn_update_dpp(0, __float_as_int(p), 0x124, 0xF, 0xF, true)); \
    p += __int_as_float(__builtin_amdgcn_update_dpp(0, __float_as_int(p), 0x128, 0xF, 0xF, true)); \
} while (0)

#define STEP(u_, d_, B_, C_, ol_) do { \
    float dA_ = __expf((d_) * A); \
    h = fmaf(dA_, h, (d_) * (u_) * (B_)); \
    float p_ = h * (C_); \
    DPPADD(p_); \
    if (n == 0) yp[ol_] = fmaf((u_), Dc, p_); \
} while (0)

template <int MODE>  // 0 fwd, 1 rev, 2 sid (fwd order, scatter store)
__device__ __forceinline__ void scan_impl(const float* __restrict__ up, const float* __restrict__ dp,
                                          const float* __restrict__ bp, const float* __restrict__ cp,
                                          const int* __restrict__ sp, float* __restrict__ yp,
                                          float A, float Dc, int n) {
    constexpr bool REV = (MODE == 1);
    constexpr bool SIDM = (MODE == 2);
    float h = 0.f;
    float4 U0[4], D0[4], B0[4], C0[4], U1[4], D1[4], B1[4], C1[4];
    int4 I0[4] = {}, I1[4] = {};

#define PHYS(ci) (REV ? (255 - (ci)) : (ci))

#define LOADC(U, D, Bb, Cc, I, ci) do { int pb_ = PHYS(ci) * 16; \
    _Pragma("unroll") for (int j_ = 0; j_ < 4; ++j_) { \
        U[j_]  = *(const float4*)(up + pb_ + 4 * j_); \
        D[j_]  = *(const float4*)(dp + pb_ + 4 * j_); \
        Bb[j_] = *(const float4*)(bp + pb_ + 4 * j_); \
        Cc[j_] = *(const float4*)(cp + pb_ + 4 * j_); \
        if (SIDM) I[j_] = *(const int4*)(sp + pb_ + 4 * j_); \
    } } while (0)

#define COMPC(U, D, Bb, Cc, I, ci) do { int pb_ = PHYS(ci) * 16; \
    if (!REV) { \
        _Pragma("unroll") for (int j_ = 0; j_ < 4; ++j_) { \
            STEP(U[j_].x, D[j_].x, Bb[j_].x, Cc[j_].x, SIDM ? I[j_].x : pb_ + 4 * j_ + 0); \
            STEP(U[j_].y, D[j_].y, Bb[j_].y, Cc[j_].y, SIDM ? I[j_].y : pb_ + 4 * j_ + 1); \
            STEP(U[j_].z, D[j_].z, Bb[j_].z, Cc[j_].z, SIDM ? I[j_].z : pb_ + 4 * j_ + 2); \
            STEP(U[j_].w, D[j_].w, Bb[j_].w, Cc[j_].w, SIDM ? I[j_].w : pb_ + 4 * j_ + 3); \
        } \
    } else { \
        _Pragma("unroll") for (int j_ = 3; j_ >= 0; --j_) { \
            STEP(U[j_].w, D[j_].w, Bb[j_].w, Cc[j_].w, pb_ + 4 * j_ + 3); \
            STEP(U[j_].z, D[j_].z, Bb[j_].z, Cc[j_].z, pb_ + 4 * j_ + 2); \
            STEP(U[j_].y, D[j_].y, Bb[j_].y, Cc[j_].y, pb_ + 4 * j_ + 1); \
            STEP(U[j_].x, D[j_].x, Bb[j_].x, Cc[j_].x, pb_ + 4 * j_ + 0); \
        } \
    } } while (0)

    LOADC(U0, D0, B0, C0, I0, 0);
    for (int it = 0; it < 256; it += 2) {
        int c1 = it + 1;
        int c2 = (it + 2 < 256) ? it + 2 : 255;
        LOADC(U1, D1, B1, C1, I1, c1);
        COMPC(U0, D0, B0, C0, I0, it);
        LOADC(U0, D0, B0, C0, I0, c2);
        COMPC(U1, D1, B1, C1, I1, c1);
    }
#undef PHYS
#undef LOADC
#undef COMPC
}

__global__ __launch_bounds__(64) void scan_kernel(
    const float* __restrict__ xm, const float* __restrict__ us,
    const float* __restrict__ df, const float* __restrict__ bsf, const float* __restrict__ csf,
    const float* __restrict__ Alf, const float* __restrict__ Dfp,
    const float* __restrict__ db, const float* __restrict__ bsb, const float* __restrict__ csb,
    const float* __restrict__ Alb, const float* __restrict__ Dbp,
    const float* __restrict__ dsd, const float* __restrict__ bss, const float* __restrict__ css,
    const float* __restrict__ Als, const float* __restrict__ Dsp,
    const int* __restrict__ sidx,
    float* __restrict__ yf, float* __restrict__ yb, float* __restrict__ ys) {
    int g = blockIdx.x;                  // 0..127, one wave per block
    int lane = threadIdx.x;              // 0..63
    int n = lane & 15, cl = lane >> 4;

    if (g < 32) {                        // forward branch
        int b = g >> 4, cg = g & 15, c = cg * 4 + cl;
        const float* up = xm + ((size_t)b * 128 + c) * Ln;
        const float* dp = df + ((size_t)b * 64 + c) * Ln;
        const float* bp = bsf + ((size_t)b * 16 + n) * Ln;
        const float* cp = csf + ((size_t)b * 16 + n) * Ln;
        float* yp = yf + ((size_t)b * 64 + c) * Ln;
        float A = -__expf(Alf[c * 16 + n]);
        float Dc = Dfp[c];
        scan_impl<0>(up, dp, bp, cp, nullptr, yp, A, Dc, n);
    } else if (g < 64) {                 // backward branch
        int g2 = g - 32, b = g2 >> 4, cg = g2 & 15, c = cg * 4 + cl;
        const float* up = xm + ((size_t)b * 128 + 64 + c) * Ln;
        const float* dp = db + ((size_t)b * 64 + c) * Ln;
        const float* bp = bsb + ((size_t)b * 16 + n) * Ln;
        const float* cp = csb + ((size_t)b * 16 + n) * Ln;
        float* yp = yb + ((size_t)b * 64 + c) * Ln;
        float A = -__expf(Alb[c * 16 + n]);
        float Dc = Dbp[c];
        scan_impl<1>(up, dp, bp, cp, nullptr, yp, A, Dc, n);
    } else {                             // SID branch
        int g2 = g - 64, b = g2 >> 5, cg = g2 & 31, c = cg * 4 + cl;
        const float* up = us + ((size_t)b * 128 + c) * Ln;
        const float* dp = dsd + ((size_t)b * 128 + c) * Ln;
        const float* bp = bss + ((size_t)b * 16 + n) * Ln;
        const float* cp = css + ((size_t)b * 16 + n) * Ln;
        float* yp = ys + ((size_t)b * 128 + c) * Ln;
        const int* sp = sidx + b * Ln;
        float A = -__expf(Als[c * 16 + n]);
        float Dc = Dsp[c];
        scan_impl<2>(up, dp, bp, cp, sp, yp, A, Dc, n);
    }
}

// ---------------- LN over concat(yf, yb) ----------------
__global__ void cat_ln_kernel(const float* __restrict__ yf, const float* __restrict__ yb,
                              const float* __restrict__ lw, const float* __restrict__ lb,
                              float* __restrict__ out) {
    int b = blockIdx.y;
    int l = blockIdx.x * blockDim.x + threadIdx.x;
    const float* pf = yf + (size_t)b * 64 * Ln + l;
    const float* pb = yb + (size_t)b * 64 * Ln + l;
    float s = 0.f, s2 = 0.f;
    for (int c = 0; c < 64; c++) { float v = pf[(size_t)c * Ln]; s += v; s2 += v * v; }
    for (int c = 0; c < 64; c++) { float v = pb[(size_t)c * Ln]; s += v; s2 += v * v; }
    float m = s / 128.f;
    float var = fmaxf(s2 / 128.f - m * m, 0.f);
    float r = 1.f / sqrtf(var + EPS_LN_C);
    for (int c = 0; c < 64; c++)
        out[((size_t)b * 128 + c) * Ln + l] = (pf[(size_t)c * Ln] - m) * r * lw[c] + lb[c];
    for (int c = 0; c < 64; c++)
        out[((size_t)b * 128 + 64 + c) * Ln + l] = (pb[(size_t)c * Ln] - m) * r * lw[64 + c] + lb[64 + c];
}

// ---------------- fused = g*sid + (1-g)*cat ----------------
__global__ void fuse_kernel(const float* __restrict__ gate, const float* __restrict__ ysb,
                            const float* __restrict__ cat, float* __restrict__ out, int ntot) {
    int i = blockIdx.x * blockDim.x + threadIdx.x;
    if (i < ntot) {
        float g = gate[i];
        out[i] = g * ysb[i] + (1.f - g) * cat[i];
    }
}

// ---------------- final LN -> d_out ----------------
__global__ void lnout_kernel(const float* __restrict__ in, const float* __restrict__ lw,
                             const float* __restrict__ lb, float* __restrict__ out) {
    int b = blockIdx.y;
    int l = blockIdx.x * blockDim.x + threadIdx.x;
    const float* p = in + (size_t)b * 128 * Ln + l;
    float s = 0.f, s2 = 0.f;
    for (int c = 0; c < 128; c++) { float v = p[(size_t)c * Ln]; s += v; s2 += v * v; }
    float m = s / 128.f;
    float var = fmaxf(s2 / 128.f - m * m, 0.f);
    float r = 1.f / sqrtf(var + EPS_LN_C);
    for (int c = 0; c < 128; c++)
        out[((size_t)b * 128 + c) * Ln + l] = (p[(size_t)c * Ln] - m) * r * lw[c] + lb[c];
}

extern "C" void kernel_launch(void* const* d_in, const int* in_sizes, int n_in,
                              void* d_out, int out_size, void* d_ws, size_t ws_size,
                              hipStream_t stream) {
    const float* x    = (const float*)d_in[0];
    const float* mfg  = (const float*)d_in[1];
    const float* mbg  = (const float*)d_in[2];
    const float* muc  = (const float*)d_in[3];
    const float* niw  = (const float*)d_in[4];
    const float* nib  = (const float*)d_in[5];
    const float* inw  = (const float*)d_in[6];
    const float* inb  = (const float*)d_in[7];
    const float* lmw  = (const float*)d_in[8];
    const float* lmb  = (const float*)d_in[9];
    const float* cmw  = (const float*)d_in[10];
    const float* cmb  = (const float*)d_in[11];
    const float* crw  = (const float*)d_in[12];
    const float* crb  = (const float*)d_in[13];
    const float* xwf  = (const float*)d_in[14];
    const float* xbf  = (const float*)d_in[15];
    const float* dtwf = (const float*)d_in[16];
    const float* dtbf = (const float*)d_in[17];
    const float* Alf  = (const float*)d_in[18];
    const float* Dfp  = (const float*)d_in[19];
    const float* xwb  = (const float*)d_in[20];
    const float* xbb  = (const float*)d_in[21];
    const float* dtwb = (const float*)d_in[22];
    const float* dtbb = (const float*)d_in[23];
    const float* Alb  = (const float*)d_in[24];
    const float* Dbp  = (const float*)d_in[25];
    const float* xws  = (const float*)d_in[26];
    const float* xbs  = (const float*)d_in[27];
    const float* dtws = (const float*)d_in[28];
    const float* dtbs = (const float*)d_in[29];
    const float* Als  = (const float*)d_in[30];
    const float* Dsp  = (const float*)d_in[31];
    const float* lcw  = (const float*)d_in[32];
    const float* lcb  = (const float*)d_in[33];
    const float* g0w  = (const float*)d_in[34];
    const float* g0b  = (const float*)d_in[35];
    const float* bng  = (const float*)d_in[36];
    const float* bnbe = (const float*)d_in[37];
    const float* bnm  = (const float*)d_in[38];
    const float* bnv  = (const float*)d_in[39];
    const float* g1w  = (const float*)d_in[40];
    const float* g1b  = (const float*)d_in[41];
    const float* outw = (const float*)d_in[42];
    const float* outb = (const float*)d_in[43];
    const float* now  = (const float*)d_in[44];
    const float* nob  = (const float*)d_in[45];

    float* W = (float*)d_ws;
    const size_t O_XP    = 0;
    const size_t O_MEAN0 = 2097152;
    const size_t O_RSTD0 = 2105344;
    const size_t O_MEAN1 = 2113536;
    const size_t O_RSTD1 = 2121728;
    const size_t O_XM    = 2129920;
    const size_t O_XR    = 3178496;
    const size_t O_DF    = 4227072;
    const size_t O_DB    = 4751360;
    const size_t O_BSF   = 5275648;
    const size_t O_CSF   = 5406720;
    const size_t O_BSB   = 5537792;
    const size_t O_CSB   = 5668864;
    const size_t O_US    = 5799936;
    const size_t O_DS    = 6848512;
    const size_t O_BSS   = 7897088;
    const size_t O_CSS   = 8028160;
    const size_t O_YF    = 8159232;
    const size_t O_YB    = 8683520;
    const size_t O_YS    = 9207808;
    const size_t O_IDX   = 10256384;
    const size_t O_CATLN = O_DF;
    const size_t O_GBUF  = O_DS;
    const size_t O_GATE  = O_US;
    const size_t O_FUSED = O_XP;
    const size_t O_OUTB  = O_XP + 1048576;

    int* idxp = (int*)(W + O_IDX);
    dim3 blk(256);

    ln_stats_kernel<<<dim3(16, 2), blk, 0, stream>>>(x, 128, 128, W + O_MEAN0, W + O_RSTD0, EPS_LN_C);
    conv1x1_kernel<<<dim3(16, 32, 2), blk, 0, stream>>>(
        x, nullptr, 128, 0, 256, inw, inb,
        W + O_MEAN0, W + O_RSTD0, niw, nib,
        nullptr, nullptr, nullptr, nullptr, 0, W + O_XP);
    ln_stats_kernel<<<dim3(16, 2), blk, 0, stream>>>(W + O_XP, 256, 128, W + O_MEAN1, W + O_RSTD1, EPS_LN_C);
    dwconv_kernel<<<dim3(16, 256, 2), blk, 0, stream>>>(
        W + O_XP, W + O_MEAN1, W + O_RSTD1, lmw, lmb, cmw, cmb, crw, crb, W + O_XM, W + O_XR);
    sort_kernel<<<2, 1024, 0, stream>>>(mfg, mbg, muc, idxp);
    xproj_fb_kernel<<<dim3(16, 2, 2), blk, 0, stream>>>(
        W + O_XM, xwf, xbf, dtwf, dtbf, xwb, xbb, dtwb, dtbb,
        W + O_DF, W + O_BSF, W + O_CSF, W + O_DB, W + O_BSB, W + O_CSB);
    xproj_s_kernel<<<dim3(16, 2), blk, 0, stream>>>(
        W + O_XM, idxp, xws, xbs, dtws, dtbs, W + O_US, W + O_DS, W + O_BSS, W + O_CSS);
    scan_kernel<<<128, 64, 0, stream>>>(
        W + O_XM, W + O_US,
        W + O_DF, W + O_BSF, W + O_CSF, Alf, Dfp,
        W + O_DB, W + O_BSB, W + O_CSB, Alb, Dbp,
        W + O_DS, W + O_BSS, W + O_CSS, Als, Dsp,
        idxp, W + O_YF, W + O_YB, W + O_YS);
    cat_ln_kernel<<<dim3(16, 2), blk, 0, stream>>>(W + O_YF, W + O_YB, lcw, lcb, W + O_CATLN);
    conv1x1_kernel<<<dim3(16, 16, 2), blk, 0, stream>>>(
        W + O_CATLN, W + O_YS, 128, 128, 128, g0w, g0b,
        nullptr, nullptr, nullptr, nullptr, bng, bnbe, bnm, bnv, 1, W + O_GBUF);
    conv1x1_kernel<<<dim3(16, 16, 2), blk, 0, stream>>>(
        W + O_GBUF, nullptr, 128, 0, 128, g1w, g1b,
        nullptr, nullptr, nullptr, nullptr, nullptr, nullptr, nullptr, nullptr, 2, W + O_GATE);
    fuse_kernel<<<4096, blk, 0, stream>>>(W + O_GATE, W + O_YS, W + O_CATLN, W + O_FUSED, Bn * Cn_ * Ln);
    conv1x1_kernel<<<dim3(16, 16, 2), blk, 0, stream>>>(
        W + O_FUSED, W + O_XR, 128, 128, 128, outw, outb,
        nullptr, nullptr, nullptr, nullptr, nullptr, nullptr, nullptr, nullptr, 0, W + O_OUTB);
    lnout_kernel<<<dim3(16, 2), blk, 0, stream>>>(W + O_OUTB, now, nob, (float*)d_out);
}

// Round 3
// 616.505 us; speedup vs baseline: 2.7841x; 1.3041x over previous
//
#include <hip/hip_runtime.h>
#include <math.h>

#define Bn 2
#define Cn_ 128
#define Hn 64
#define Wn 64
#define Ln 4096
#define Nn 16

static constexpr float EPS_LN_C = 1e-6f;
static constexpr float EPS_BN_C = 1e-5f;

__device__ __forceinline__ float softplusf_(float x) {
    return fmaxf(x, 0.f) + log1pf(__expf(-fabsf(x)));
}
__device__ __forceinline__ float sigmoidf_(float x) {
    return 1.f / (1.f + __expf(-x));
}

// ---------------- per-pixel LN stats over Cc channels (stride CS) ----------------
__global__ void ln_stats_kernel(const float* __restrict__ in, int CS, int Cc,
                                float* __restrict__ mean, float* __restrict__ rstd,
                                float eps) {
    int b = blockIdx.y;
    int l = blockIdx.x * blockDim.x + threadIdx.x;
    const float* p = in + (size_t)b * CS * Ln + l;
    float s = 0.f, s2 = 0.f;
    for (int c = 0; c < Cc; c++) {
        float v = p[(size_t)c * Ln];
        s += v; s2 += v * v;
    }
    float m = s / (float)Cc;
    float var = fmaxf(s2 / (float)Cc - m * m, 0.f);
    mean[b * Ln + l] = m;
    rstd[b * Ln + l] = 1.f / sqrtf(var + eps);
}

// ---------------- generic 1x1 conv, 4 pixels per thread (float4) ----------------
__global__ void conv1x1_kernel(const float* __restrict__ inA, const float* __restrict__ inB,
                               int cinA, int cinB, int cout,
                               const float* __restrict__ w, const float* __restrict__ bias,
                               const float* __restrict__ lnm, const float* __restrict__ lnr,
                               const float* __restrict__ lnw, const float* __restrict__ lnb,
                               const float* __restrict__ bng, const float* __restrict__ bnbe,
                               const float* __restrict__ bnm, const float* __restrict__ bnv,
                               int epilogue, float* __restrict__ out) {
    int b = blockIdx.z;
    int o0 = blockIdx.y * 8;
    int l = (blockIdx.x * blockDim.x + threadIdx.x) * 4;
    int cin = cinA + cinB;
    float4 acc[8];
#pragma unroll
    for (int j = 0; j < 8; j++) { float bj = bias[o0 + j]; acc[j] = make_float4(bj, bj, bj, bj); }
    bool ln = (lnw != nullptr);
    float4 m4 = make_float4(0,0,0,0), r4 = make_float4(0,0,0,0);
    if (ln) {
        m4 = *(const float4*)(lnm + b * Ln + l);
        r4 = *(const float4*)(lnr + b * Ln + l);
    }
    const float* pa = inA + (size_t)b * cinA * Ln + l;
    for (int c = 0; c < cinA; c++) {
        float4 v = *(const float4*)(pa + (size_t)c * Ln);
        if (ln) {
            float lw = lnw[c], lb2 = lnb[c];
            v.x = (v.x - m4.x) * r4.x * lw + lb2;
            v.y = (v.y - m4.y) * r4.y * lw + lb2;
            v.z = (v.z - m4.z) * r4.z * lw + lb2;
            v.w = (v.w - m4.w) * r4.w * lw + lb2;
        }
#pragma unroll
        for (int j = 0; j < 8; j++) {
            float wv = w[(o0 + j) * cin + c];
            acc[j].x = fmaf(wv, v.x, acc[j].x);
            acc[j].y = fmaf(wv, v.y, acc[j].y);
            acc[j].z = fmaf(wv, v.z, acc[j].z);
            acc[j].w = fmaf(wv, v.w, acc[j].w);
        }
    }
    if (inB) {
        const float* pb = inB + (size_t)b * cinB * Ln + l;
        for (int c = 0; c < cinB; c++) {
            float4 v = *(const float4*)(pb + (size_t)c * Ln);
#pragma unroll
            for (int j = 0; j < 8; j++) {
                float wv = w[(o0 + j) * cin + cinA + c];
                acc[j].x = fmaf(wv, v.x, acc[j].x);
                acc[j].y = fmaf(wv, v.y, acc[j].y);
                acc[j].z = fmaf(wv, v.z, acc[j].z);
                acc[j].w = fmaf(wv, v.w, acc[j].w);
            }
        }
    }
#pragma unroll
    for (int j = 0; j < 8; j++) {
        float4 v = acc[j];
        int o = o0 + j;
        if (epilogue == 1) {
            float sc = (1.f / sqrtf(bnv[o] + EPS_BN_C)) * bng[o];
            float sh = bnbe[o] - bnm[o] * sc;
            v.x = fmaxf(fmaf(v.x, sc, sh), 0.f);
            v.y = fmaxf(fmaf(v.y, sc, sh), 0.f);
            v.z = fmaxf(fmaf(v.z, sc, sh), 0.f);
            v.w = fmaxf(fmaf(v.w, sc, sh), 0.f);
        } else if (epilogue == 2) {
            v.x = sigmoidf_(v.x); v.y = sigmoidf_(v.y);
            v.z = sigmoidf_(v.z); v.w = sigmoidf_(v.w);
        }
        *(float4*)(out + ((size_t)b * cout + o) * Ln + l) = v;
    }
}

// ---------------- depthwise 3x3 SAME + bias + SiLU ----------------
__global__ void dwconv_kernel(const float* __restrict__ xp,
                              const float* __restrict__ mean1, const float* __restrict__ rstd1,
                              const float* __restrict__ lnw, const float* __restrict__ lnb,
                              const float* __restrict__ wm, const float* __restrict__ bm,
                              const float* __restrict__ wr, const float* __restrict__ br,
                              float* __restrict__ xm, float* __restrict__ xr) {
    int b = blockIdx.z;
    int c2 = blockIdx.y;
    int l = blockIdx.x * blockDim.x + threadIdx.x;
    int h = l >> 6, w = l & 63;
    bool mamba = (c2 < 128);
    const float* in = xp + ((size_t)b * 256 + c2) * Ln;
    const float* wt = mamba ? (wm + c2 * 9) : (wr + (c2 - 128) * 9);
    float lw = 0.f, lbv = 0.f;
    if (mamba) { lw = lnw[c2]; lbv = lnb[c2]; }
    float acc = mamba ? bm[c2] : br[c2 - 128];
#pragma unroll
    for (int dh = -1; dh <= 1; dh++) {
#pragma unroll
        for (int dw = -1; dw <= 1; dw++) {
            int hh = h + dh, ww = w + dw;
            if (hh < 0 || hh > 63 || ww < 0 || ww > 63) continue;
            int l2 = hh * 64 + ww;
            float v = in[l2];
            if (mamba) v = (v - mean1[b * Ln + l2]) * rstd1[b * Ln + l2] * lw + lbv;
            acc = fmaf(v, wt[(dh + 1) * 3 + (dw + 1)], acc);
        }
    }
    float o = acc * sigmoidf_(acc);
    if (mamba) xm[((size_t)b * 128 + c2) * Ln + l] = o;
    else       xr[((size_t)b * 128 + (c2 - 128)) * Ln + l] = o;
}

// ---------------- counting sort (4 classes) per batch; within class, index DESCENDING ----------------
__global__ __launch_bounds__(1024) void sort_kernel(const float* __restrict__ mfg,
                                                    const float* __restrict__ mbg,
                                                    const float* __restrict__ muc,
                                                    int* __restrict__ sidx) {
    int b = blockIdx.x;
    int t = threadIdx.x;
    const int PT = 4;
    __shared__ unsigned int wsum0[16], wsum1[16];
    __shared__ unsigned int tot01s, tot23s;

    int cls[PT];
    unsigned int c01 = 0, c23 = 0;
#pragma unroll
    for (int q = 0; q < PT; q++) {
        int j = t * PT + q;
        int i = Ln - 1 - j;
        float f = mfg[b * Ln + i], g = mbg[b * Ln + i], u = muc[b * Ln + i];
        int k = (f > 0.5f) ? 3 : (g > 0.5f) ? 2 : (u > 0.5f) ? 1 : 0;
        cls[q] = k;
        if (k == 0) c01 += 1u;
        else if (k == 1) c01 += (1u << 16);
        else if (k == 2) c23 += 1u;
        else c23 += (1u << 16);
    }
    unsigned int s01 = c01, s23 = c23;
    int lane = t & 63;
    for (int d = 1; d < 64; d <<= 1) {
        unsigned int o01 = __shfl_up(s01, (unsigned)d, 64);
        unsigned int o23 = __shfl_up(s23, (unsigned)d, 64);
        if (lane >= d) { s01 += o01; s23 += o23; }
    }
    int wid = t >> 6;
    if (lane == 63) { wsum0[wid] = s01; wsum1[wid] = s23; }
    __syncthreads();
    if (t == 0) {
        unsigned int a0 = 0, a1 = 0;
        for (int k2 = 0; k2 < 16; k2++) {
            unsigned int v0 = wsum0[k2], v1 = wsum1[k2];
            wsum0[k2] = a0; wsum1[k2] = a1;
            a0 += v0; a1 += v1;
        }
        tot01s = a0; tot23s = a1;
    }
    __syncthreads();
    unsigned int ex01 = s01 - c01 + wsum0[wid];
    unsigned int ex23 = s23 - c23 + wsum1[wid];
    unsigned int cnt1 = tot01s >> 16;
    unsigned int cnt2 = tot23s & 0xffffu, cnt3 = tot23s >> 16;
    unsigned int off3 = 0, off2 = cnt3, off1 = cnt3 + cnt2, off0 = cnt3 + cnt2 + cnt1;
    unsigned int run0 = ex01 & 0xffffu, run1 = ex01 >> 16;
    unsigned int run2 = ex23 & 0xffffu, run3 = ex23 >> 16;
#pragma unroll
    for (int q = 0; q < PT; q++) {
        int j = t * PT + q;
        int i = Ln - 1 - j;
        int k = cls[q];
        unsigned int pos;
        if (k == 0) pos = off0 + run0++;
        else if (k == 1) pos = off1 + run1++;
        else if (k == 2) pos = off2 + run2++;
        else pos = off3 + run3++;
        sidx[b * Ln + pos] = i;
    }
}

// ---------------- x_proj + dt_proj + softplus for fwd/bwd branches ----------------
__global__ void xproj_fb_kernel(const float* __restrict__ xm,
                                const float* __restrict__ xwf, const float* __restrict__ xbf,
                                const float* __restrict__ dtwf, const float* __restrict__ dtbf,
                                const float* __restrict__ xwb, const float* __restrict__ xbb,
                                const float* __restrict__ dtwb, const float* __restrict__ dtbb,
                                float* __restrict__ df, float* __restrict__ bsf, float* __restrict__ csf,
                                float* __restrict__ db, float* __restrict__ bsb, float* __restrict__ csb) {
    int br = blockIdx.z;
    int b = blockIdx.y;
    int l = blockIdx.x * blockDim.x + threadIdx.x;
    const float* xw = br ? xwb : xwf;
    const float* xb = br ? xbb : xbf;
    const float* dtw = br ? dtwb : dtwf;
    const float* dtb = br ? dtbb : dtbf;
    float* dd = br ? db : df;
    float* bb = br ? bsb : bsf;
    float* cc = br ? csb : csf;
    const float* up = xm + ((size_t)b * 128 + br * 64) * Ln + l;
    float acc[36];
#pragma unroll
    for (int j = 0; j < 36; j++) acc[j] = xb[j];
    for (int c = 0; c < 64; c++) {
        float u = up[(size_t)c * Ln];
#pragma unroll
        for (int j = 0; j < 36; j++) acc[j] = fmaf(xw[j * 64 + c], u, acc[j]);
    }
    for (int c = 0; c < 64; c++) {
        float d = dtb[c];
#pragma unroll
        for (int r = 0; r < 4; r++) d = fmaf(dtw[c * 4 + r], acc[r], d);
        dd[((size_t)b * 64 + c) * Ln + l] = softplusf_(d);
    }
#pragma unroll
    for (int n2 = 0; n2 < 16; n2++) {
        bb[((size_t)b * 16 + n2) * Ln + l] = acc[4 + n2];
        cc[((size_t)b * 16 + n2) * Ln + l] = acc[20 + n2];
    }
}

// ---------------- gathered x_proj for SID branch ----------------
__global__ void xproj_s_kernel(const float* __restrict__ xm, const int* __restrict__ sidx,
                               const float* __restrict__ xw, const float* __restrict__ xb,
                               const float* __restrict__ dtw, const float* __restrict__ dtb,
                               float* __restrict__ us, float* __restrict__ ds,
                               float* __restrict__ bss, float* __restrict__ css) {
    int b = blockIdx.y;
    int t = blockIdx.x * blockDim.x + threadIdx.x;
    int pix = sidx[b * Ln + t];
    float acc[40];
#pragma unroll
    for (int j = 0; j < 40; j++) acc[j] = xb[j];
    for (int c = 0; c < 128; c++) {
        float u = xm[((size_t)b * 128 + c) * Ln + pix];
        us[((size_t)b * 128 + c) * Ln + t] = u;
#pragma unroll
        for (int j = 0; j < 40; j++) acc[j] = fmaf(xw[j * 128 + c], u, acc[j]);
    }
    for (int c = 0; c < 128; c++) {
        float d = dtb[c];
#pragma unroll
        for (int r = 0; r < 8; r++) d = fmaf(dtw[c * 8 + r], acc[r], d);
        ds[((size_t)b * 128 + c) * Ln + t] = softplusf_(d);
    }
#pragma unroll
    for (int n2 = 0; n2 < 16; n2++) {
        bss[((size_t)b * 16 + n2) * Ln + t] = acc[8 + n2];
        css[((size_t)b * 16 + n2) * Ln + t] = acc[24 + n2];
    }
}

// ================= chunked selective scan =================
// 8192 sequences of length 4096, organized as 128 "g" waves (64 lanes = 4 ch x 16 n),
// split into NCHUNK=32 chunks of 128 steps. Phase1: per-chunk (h_local, a-product).
// Stitch: compose 32 summaries serially (tiny). Phase2: re-run chunk with exact init.
#define NCHUNK 32
#define CG 8  // 16-step groups per chunk (chunk = 128 steps)

#define DPPADD(p) do { \
    p += __int_as_float(__builtin_amdgcn_update_dpp(0, __float_as_int(p), 0xB1, 0xF, 0xF, true)); \
    p += __int_as_float(__builtin_amdgcn_update_dpp(0, __float_as_int(p), 0x4E, 0xF, 0xF, true)); \
    p += __int_as_float(__builtin_amdgcn_update_dpp(0, __float_as_int(p), 0x124, 0xF, 0xF, true)); \
    p += __int_as_float(__builtin_amdgcn_update_dpp(0, __float_as_int(p), 0x128, 0xF, 0xF, true)); \
} while (0)

// ---- phase 1: local scan + a-product, no output, no C ----
template <int REV>
__device__ __forceinline__ void p1_chunk(const float* __restrict__ up, const float* __restrict__ dp,
                                         const float* __restrict__ bp, float A, int c0,
                                         float& hout, float& Pout) {
    float h = 0.f, P = 1.f;
    float4 U0[4], D0[4], B0[4], U1[4], D1[4], B1[4];
#define PHYS1(ci) (REV ? (255 - (ci)) : (ci))
#define LOAD1(U, D, Bb, ci) do { int pb_ = PHYS1(ci) * 16; \
    _Pragma("unroll") for (int j_ = 0; j_ < 4; ++j_) { \
        U[j_]  = *(const float4*)(up + pb_ + 4 * j_); \
        D[j_]  = *(const float4*)(dp + pb_ + 4 * j_); \
        Bb[j_] = *(const float4*)(bp + pb_ + 4 * j_); \
    } } while (0)
#define STEP1(u_, d_, B_) do { float a_ = __expf((d_) * A); h = fmaf(a_, h, (d_) * (u_) * (B_)); P *= a_; } while (0)
#define COMP1(U, D, Bb) do { \
    if (!REV) { _Pragma("unroll") for (int j_ = 0; j_ < 4; ++j_) { \
        STEP1(U[j_].x, D[j_].x, Bb[j_].x); STEP1(U[j_].y, D[j_].y, Bb[j_].y); \
        STEP1(U[j_].z, D[j_].z, Bb[j_].z); STEP1(U[j_].w, D[j_].w, Bb[j_].w); } } \
    else { _Pragma("unroll") for (int j_ = 3; j_ >= 0; --j_) { \
        STEP1(U[j_].w, D[j_].w, Bb[j_].w); STEP1(U[j_].z, D[j_].z, Bb[j_].z); \
        STEP1(U[j_].y, D[j_].y, Bb[j_].y); STEP1(U[j_].x, D[j_].x, Bb[j_].x); } } } while (0)
    LOAD1(U0, D0, B0, c0);
    for (int it = 0; it < CG; it += 2) {
        LOAD1(U1, D1, B1, c0 + it + 1);
        COMP1(U0, D0, B0);
        if (it + 2 < CG) LOAD1(U0, D0, B0, c0 + it + 2);
        COMP1(U1, D1, B1);
    }
    hout = h; Pout = P;
#undef PHYS1
#undef LOAD1
#undef STEP1
#undef COMP1
}

__global__ __launch_bounds__(64) void scan_p1_kernel(
    const float* __restrict__ xm, const float* __restrict__ us,
    const float* __restrict__ df, const float* __restrict__ bsf, const float* __restrict__ Alf,
    const float* __restrict__ db, const float* __restrict__ bsb, const float* __restrict__ Alb,
    const float* __restrict__ dsd, const float* __restrict__ bss, const float* __restrict__ Als,
    float* __restrict__ hf, float* __restrict__ Pp) {
    int g = blockIdx.x, k = blockIdx.y;
    int lane = threadIdx.x;
    int n = lane & 15, cl = lane >> 4;
    int c0 = k * CG;
    float h, P;
    if (g < 32) {
        int b = g >> 4, cg = g & 15, c = cg * 4 + cl;
        float A = -__expf(Alf[c * 16 + n]);
        p1_chunk<0>(xm + ((size_t)b * 128 + c) * Ln, df + ((size_t)b * 64 + c) * Ln,
                    bsf + ((size_t)b * 16 + n) * Ln, A, c0, h, P);
    } else if (g < 64) {
        int g2 = g - 32, b = g2 >> 4, cg = g2 & 15, c = cg * 4 + cl;
        float A = -__expf(Alb[c * 16 + n]);
        p1_chunk<1>(xm + ((size_t)b * 128 + 64 + c) * Ln, db + ((size_t)b * 64 + c) * Ln,
                    bsb + ((size_t)b * 16 + n) * Ln, A, c0, h, P);
    } else {
        int g2 = g - 64, b = g2 >> 5, cg = g2 & 31, c = cg * 4 + cl;
        float A = -__expf(Als[c * 16 + n]);
        p1_chunk<0>(us + ((size_t)b * 128 + c) * Ln, dsd + ((size_t)b * 128 + c) * Ln,
                    bss + ((size_t)b * 16 + n) * Ln, A, c0, h, P);
    }
    int o = (g * NCHUNK + k) * 64 + lane;
    hf[o] = h; Pp[o] = P;
}

// ---- stitch: compose chunk summaries into per-chunk initial states ----
__global__ void scan_stitch_kernel(const float* __restrict__ hf, const float* __restrict__ Pp,
                                   float* __restrict__ hi) {
    int id = blockIdx.x * blockDim.x + threadIdx.x;   // 0..8191
    int g = id >> 6, lane = id & 63;
    float Pk[NCHUNK], Hk[NCHUNK];
#pragma unroll
    for (int k = 0; k < NCHUNK; k++) {
        int o = (g * NCHUNK + k) * 64 + lane;
        Pk[k] = Pp[o]; Hk[k] = hf[o];
    }
    float h = 0.f;
#pragma unroll
    for (int k = 0; k < NCHUNK; k++) {
        int o = (g * NCHUNK + k) * 64 + lane;
        hi[o] = h;
        h = fmaf(Pk[k], h, Hk[k]);
    }
}

// ---- phase 2: full scan of one chunk with exact initial state ----
#define STEPP(u_, d_, B_, C_) ({ \
    float dA_ = __expf((d_) * A); \
    h = fmaf(dA_, h, (d_) * (u_) * (B_)); \
    float p_ = h * (C_); \
    DPPADD(p_); \
    fmaf((u_), Dc, p_); })

template <int MODE>  // 0 fwd, 1 rev, 2 sid
__device__ __forceinline__ void p2_chunk(const float* __restrict__ up, const float* __restrict__ dp,
                                         const float* __restrict__ bp, const float* __restrict__ cp,
                                         const int* __restrict__ sp, float* __restrict__ yp,
                                         float A, float Dc, int n, int c0, float h) {
    constexpr bool REV = (MODE == 1);
    constexpr bool SIDM = (MODE == 2);
    float4 U0[4], D0[4], B0[4], C0[4], U1[4], D1[4], B1[4], C1[4];
    int4 I0[4] = {}, I1[4] = {};
#define PHYS(ci) (REV ? (255 - (ci)) : (ci))
#define LOADC(U, D, Bb, Cc, I, ci) do { int pb_ = PHYS(ci) * 16; \
    _Pragma("unroll") for (int j_ = 0; j_ < 4; ++j_) { \
        U[j_]  = *(const float4*)(up + pb_ + 4 * j_); \
        D[j_]  = *(const float4*)(dp + pb_ + 4 * j_); \
        Bb[j_] = *(const float4*)(bp + pb_ + 4 * j_); \
        Cc[j_] = *(const float4*)(cp + pb_ + 4 * j_); \
        if (SIDM) I[j_] = *(const int4*)(sp + pb_ + 4 * j_); \
    } } while (0)
#define COMPC(U, D, Bb, Cc, I, ci) do { int pb_ = PHYS(ci) * 16; \
    if (SIDM) { \
        _Pragma("unroll") for (int j_ = 0; j_ < 4; ++j_) { \
            float y0_ = STEPP(U[j_].x, D[j_].x, Bb[j_].x, Cc[j_].x); if (n == 0) yp[I[j_].x] = y0_; \
            float y1_ = STEPP(U[j_].y, D[j_].y, Bb[j_].y, Cc[j_].y); if (n == 0) yp[I[j_].y] = y1_; \
            float y2_ = STEPP(U[j_].z, D[j_].z, Bb[j_].z, Cc[j_].z); if (n == 0) yp[I[j_].z] = y2_; \
            float y3_ = STEPP(U[j_].w, D[j_].w, Bb[j_].w, Cc[j_].w); if (n == 0) yp[I[j_].w] = y3_; \
        } \
    } else if (!REV) { \
        _Pragma("unroll") for (int j_ = 0; j_ < 4; ++j_) { \
            float4 y4_; \
            y4_.x = STEPP(U[j_].x, D[j_].x, Bb[j_].x, Cc[j_].x); \
            y4_.y = STEPP(U[j_].y, D[j_].y, Bb[j_].y, Cc[j_].y); \
            y4_.z = STEPP(U[j_].z, D[j_].z, Bb[j_].z, Cc[j_].z); \
            y4_.w = STEPP(U[j_].w, D[j_].w, Bb[j_].w, Cc[j_].w); \
            if (n == 0) *(float4*)(yp + pb_ + 4 * j_) = y4_; \
        } \
    } else { \
        _Pragma("unroll") for (int j_ = 3; j_ >= 0; --j_) { \
            float4 y4_; \
            y4_.w = STEPP(U[j_].w, D[j_].w, Bb[j_].w, Cc[j_].w); \
            y4_.z = STEPP(U[j_].z, D[j_].z, Bb[j_].z, Cc[j_].z); \
            y4_.y = STEPP(U[j_].y, D[j_].y, Bb[j_].y, Cc[j_].y); \
            y4_.x = STEPP(U[j_].x, D[j_].x, Bb[j_].x, Cc[j_].x); \
            if (n == 0) *(float4*)(yp + pb_ + 4 * j_) = y4_; \
        } \
    } } while (0)
    LOADC(U0, D0, B0, C0, I0, c0);
    for (int it = 0; it < CG; it += 2) {
        LOADC(U1, D1, B1, C1, I1, c0 + it + 1);
        COMPC(U0, D0, B0, C0, I0, c0 + it);
        if (it + 2 < CG) LOADC(U0, D0, B0, C0, I0, c0 + it + 2);
        COMPC(U1, D1, B1, C1, I1, c0 + it + 1);
    }
#undef PHYS
#undef LOADC
#undef COMPC
}

__global__ __launch_bounds__(64) void scan_p2_kernel(
    const float* __restrict__ xm, const float* __restrict__ us,
    const float* __restrict__ df, const float* __restrict__ bsf, const float* __restrict__ csf,
    const float* __restrict__ Alf, const float* __restrict__ Dfp,
    const float* __restrict__ db, const float* __restrict__ bsb, const float* __restrict__ csb,
    const float* __restrict__ Alb, const float* __restrict__ Dbp,
    const float* __restrict__ dsd, const float* __restrict__ bss, const float* __restrict__ css,
    const float* __restrict__ Als, const float* __restrict__ Dsp,
    const int* __restrict__ sidx, const float* __restrict__ hi,
    float* __restrict__ yf, float* __restrict__ yb, float* __restrict__ ys) {
    int g = blockIdx.x, k = blockIdx.y;
    int lane = threadIdx.x;
    int n = lane & 15, cl = lane >> 4;
    int c0 = k * CG;
    float h0 = hi[(g * NCHUNK + k) * 64 + lane];
    if (g < 32) {
        int b = g >> 4, cg = g & 15, c = cg * 4 + cl;
        float A = -__expf(Alf[c * 16 + n]);
        p2_chunk<0>(xm + ((size_t)b * 128 + c) * Ln, df + ((size_t)b * 64 + c) * Ln,
                    bsf + ((size_t)b * 16 + n) * Ln, csf + ((size_t)b * 16 + n) * Ln,
                    nullptr, yf + ((size_t)b * 64 + c) * Ln, A, Dfp[c], n, c0, h0);
    } else if (g < 64) {
        int g2 = g - 32, b = g2 >> 4, cg = g2 & 15, c = cg * 4 + cl;
        float A = -__expf(Alb[c * 16 + n]);
        p2_chunk<1>(xm + ((size_t)b * 128 + 64 + c) * Ln, db + ((size_t)b * 64 + c) * Ln,
                    bsb + ((size_t)b * 16 + n) * Ln, csb + ((size_t)b * 16 + n) * Ln,
                    nullptr, yb + ((size_t)b * 64 + c) * Ln, A, Dbp[c], n, c0, h0);
    } else {
        int g2 = g - 64, b = g2 >> 5, cg = g2 & 31, c = cg * 4 + cl;
        float A = -__expf(Als[c * 16 + n]);
        p2_chunk<2>(us + ((size_t)b * 128 + c) * Ln, dsd + ((size_t)b * 128 + c) * Ln,
                    bss + ((size_t)b * 16 + n) * Ln, css + ((size_t)b * 16 + n) * Ln,
                    sidx + b * Ln, ys + ((size_t)b * 128 + c) * Ln, A, Dsp[c], n, c0, h0);
    }
}

// ---------------- LN over concat(yf, yb) ----------------
__global__ void cat_ln_kernel(const float* __restrict__ yf, const float* __restrict__ yb,
                              const float* __restrict__ lw, const float* __restrict__ lb,
                              float* __restrict__ out) {
    int b = blockIdx.y;
    int l = blockIdx.x * blockDim.x + threadIdx.x;
    const float* pf = yf + (size_t)b * 64 * Ln + l;
    const float* pb = yb + (size_t)b * 64 * Ln + l;
    float s = 0.f, s2 = 0.f;
    for (int c = 0; c < 64; c++) { float v = pf[(size_t)c * Ln]; s += v; s2 += v * v; }
    for (int c = 0; c < 64; c++) { float v = pb[(size_t)c * Ln]; s += v; s2 += v * v; }
    float m = s / 128.f;
    float var = fmaxf(s2 / 128.f - m * m, 0.f);
    float r = 1.f / sqrtf(var + EPS_LN_C);
    for (int c = 0; c < 64; c++)
        out[((size_t)b * 128 + c) * Ln + l] = (pf[(size_t)c * Ln] - m) * r * lw[c] + lb[c];
    for (int c = 0; c < 64; c++)
        out[((size_t)b * 128 + 64 + c) * Ln + l] = (pb[(size_t)c * Ln] - m) * r * lw[64 + c] + lb[64 + c];
}

// ---------------- fused = g*sid + (1-g)*cat (float4) ----------------
__global__ void fuse_kernel(const float4* __restrict__ gate, const float4* __restrict__ ysb,
                            const float4* __restrict__ cat, float4* __restrict__ out, int n4) {
    int i = blockIdx.x * blockDim.x + threadIdx.x;
    if (i < n4) {
        float4 g = gate[i], s = ysb[i], c = cat[i], o;
        o.x = g.x * s.x + (1.f - g.x) * c.x;
        o.y = g.y * s.y + (1.f - g.y) * c.y;
        o.z = g.z * s.z + (1.f - g.z) * c.z;
        o.w = g.w * s.w + (1.f - g.w) * c.w;
        out[i] = o;
    }
}

// ---------------- final LN -> d_out ----------------
__global__ void lnout_kernel(const float* __restrict__ in, const float* __restrict__ lw,
                             const float* __restrict__ lb, float* __restrict__ out) {
    int b = blockIdx.y;
    int l = blockIdx.x * blockDim.x + threadIdx.x;
    const float* p = in + (size_t)b * 128 * Ln + l;
    float s = 0.f, s2 = 0.f;
    for (int c = 0; c < 128; c++) { float v = p[(size_t)c * Ln]; s += v; s2 += v * v; }
    float m = s / 128.f;
    float var = fmaxf(s2 / 128.f - m * m, 0.f);
    float r = 1.f / sqrtf(var + EPS_LN_C);
    for (int c = 0; c < 128; c++)
        out[((size_t)b * 128 + c) * Ln + l] = (p[(size_t)c * Ln] - m) * r * lw[c] + lb[c];
}

extern "C" void kernel_launch(void* const* d_in, const int* in_sizes, int n_in,
                              void* d_out, int out_size, void* d_ws, size_t ws_size,
                              hipStream_t stream) {
    const float* x    = (const float*)d_in[0];
    const float* mfg  = (const float*)d_in[1];
    const float* mbg  = (const float*)d_in[2];
    const float* muc  = (const float*)d_in[3];
    const float* niw  = (const float*)d_in[4];
    const float* nib  = (const float*)d_in[5];
    const float* inw  = (const float*)d_in[6];
    const float* inb  = (const float*)d_in[7];
    const float* lmw  = (const float*)d_in[8];
    const float* lmb  = (const float*)d_in[9];
    const float* cmw  = (const float*)d_in[10];
    const float* cmb  = (const float*)d_in[11];
    const float* crw  = (const float*)d_in[12];
    const float* crb  = (const float*)d_in[13];
    const float* xwf  = (const float*)d_in[14];
    const float* xbf  = (const float*)d_in[15];
    const float* dtwf = (const float*)d_in[16];
    const float* dtbf = (const float*)d_in[17];
    const float* Alf  = (const float*)d_in[18];
    const float* Dfp  = (const float*)d_in[19];
    const float* xwb  = (const float*)d_in[20];
    const float* xbb  = (const float*)d_in[21];
    const float* dtwb = (const float*)d_in[22];
    const float* dtbb = (const float*)d_in[23];
    const float* Alb  = (const float*)d_in[24];
    const float* Dbp  = (const float*)d_in[25];
    const float* xws  = (const float*)d_in[26];
    const float* xbs  = (const float*)d_in[27];
    const float* dtws = (const float*)d_in[28];
    const float* dtbs = (const float*)d_in[29];
    const float* Als  = (const float*)d_in[30];
    const float* Dsp  = (const float*)d_in[31];
    const float* lcw  = (const float*)d_in[32];
    const float* lcb  = (const float*)d_in[33];
    const float* g0w  = (const float*)d_in[34];
    const float* g0b  = (const float*)d_in[35];
    const float* bng  = (const float*)d_in[36];
    const float* bnbe = (const float*)d_in[37];
    const float* bnm  = (const float*)d_in[38];
    const float* bnv  = (const float*)d_in[39];
    const float* g1w  = (const float*)d_in[40];
    const float* g1b  = (const float*)d_in[41];
    const float* outw = (const float*)d_in[42];
    const float* outb = (const float*)d_in[43];
    const float* now  = (const float*)d_in[44];
    const float* nob  = (const float*)d_in[45];

    float* W = (float*)d_ws;
    const size_t O_XP    = 0;          // xp (dead after dwconv; reused: scan state, FUSED, OUTB)
    const size_t O_MEAN0 = 2097152;
    const size_t O_RSTD0 = 2105344;
    const size_t O_MEAN1 = 2113536;
    const size_t O_RSTD1 = 2121728;
    const size_t O_XM    = 2129920;
    const size_t O_XR    = 3178496;
    const size_t O_DF    = 4227072;
    const size_t O_DB    = 4751360;
    const size_t O_BSF   = 5275648;
    const size_t O_CSF   = 5406720;
    const size_t O_BSB   = 5537792;
    const size_t O_CSB   = 5668864;
    const size_t O_US    = 5799936;
    const size_t O_DS    = 6848512;
    const size_t O_BSS   = 7897088;
    const size_t O_CSS   = 8028160;
    const size_t O_YF    = 8159232;
    const size_t O_YB    = 8683520;
    const size_t O_YS    = 9207808;
    const size_t O_IDX   = 10256384;
    const size_t O_CATLN = O_DF;
    const size_t O_GBUF  = O_DS;
    const size_t O_GATE  = O_US;
    const size_t O_FUSED = O_XP;
    const size_t O_OUTB  = O_XP + 1048576;
    // scan chunk state (lives in dead XP region, before FUSED is written)
    const size_t O_HF    = O_XP;             // 128*32*64 = 262144
    const size_t O_PP    = O_XP + 262144;
    const size_t O_HI    = O_XP + 524288;

    int* idxp = (int*)(W + O_IDX);
    dim3 blk(256);

    ln_stats_kernel<<<dim3(16, 2), blk, 0, stream>>>(x, 128, 128, W + O_MEAN0, W + O_RSTD0, EPS_LN_C);
    conv1x1_kernel<<<dim3(4, 32, 2), blk, 0, stream>>>(
        x, nullptr, 128, 0, 256, inw, inb,
        W + O_MEAN0, W + O_RSTD0, niw, nib,
        nullptr, nullptr, nullptr, nullptr, 0, W + O_XP);
    ln_stats_kernel<<<dim3(16, 2), blk, 0, stream>>>(W + O_XP, 256, 128, W + O_MEAN1, W + O_RSTD1, EPS_LN_C);
    dwconv_kernel<<<dim3(16, 256, 2), blk, 0, stream>>>(
        W + O_XP, W + O_MEAN1, W + O_RSTD1, lmw, lmb, cmw, cmb, crw, crb, W + O_XM, W + O_XR);
    sort_kernel<<<2, 1024, 0, stream>>>(mfg, mbg, muc, idxp);
    xproj_fb_kernel<<<dim3(16, 2, 2), blk, 0, stream>>>(
        W + O_XM, xwf, xbf, dtwf, dtbf, xwb, xbb, dtwb, dtbb,
        W + O_DF, W + O_BSF, W + O_CSF, W + O_DB, W + O_BSB, W + O_CSB);
    xproj_s_kernel<<<dim3(16, 2), blk, 0, stream>>>(
        W + O_XM, idxp, xws, xbs, dtws, dtbs, W + O_US, W + O_DS, W + O_BSS, W + O_CSS);
    // chunked scan: phase1 -> stitch -> phase2
    scan_p1_kernel<<<dim3(128, NCHUNK), 64, 0, stream>>>(
        W + O_XM, W + O_US,
        W + O_DF, W + O_BSF, Alf,
        W + O_DB, W + O_BSB, Alb,
        W + O_DS, W + O_BSS, Als,
        W + O_HF, W + O_PP);
    scan_stitch_kernel<<<32, 256, 0, stream>>>(W + O_HF, W + O_PP, W + O_HI);
    scan_p2_kernel<<<dim3(128, NCHUNK), 64, 0, stream>>>(
        W + O_XM, W + O_US,
        W + O_DF, W + O_BSF, W + O_CSF, Alf, Dfp,
        W + O_DB, W + O_BSB, W + O_CSB, Alb, Dbp,
        W + O_DS, W + O_BSS, W + O_CSS, Als, Dsp,
        idxp, W + O_HI, W + O_YF, W + O_YB, W + O_YS);
    cat_ln_kernel<<<dim3(16, 2), blk, 0, stream>>>(W + O_YF, W + O_YB, lcw, lcb, W + O_CATLN);
    conv1x1_kernel<<<dim3(4, 16, 2), blk, 0, stream>>>(
        W + O_CATLN, W + O_YS, 128, 128, 128, g0w, g0b,
        nullptr, nullptr, nullptr, nullptr, bng, bnbe, bnm, bnv, 1, W + O_GBUF);
    conv1x1_kernel<<<dim3(4, 16, 2), blk, 0, stream>>>(
        W + O_GBUF, nullptr, 128, 0, 128, g1w, g1b,
        nullptr, nullptr, nullptr, nullptr, nullptr, nullptr, nullptr, nullptr, 2, W + O_GATE);
    fuse_kernel<<<1024, blk, 0, stream>>>(
        (const float4*)(W + O_GATE), (const float4*)(W + O_YS), (const float4*)(W + O_CATLN),
        (float4*)(W + O_FUSED), Bn * Cn_ * Ln / 4);
    conv1x1_kernel<<<dim3(4, 16, 2), blk, 0, stream>>>(
        W + O_FUSED, W + O_XR, 128, 128, 128, outw, outb,
        nullptr, nullptr, nullptr, nullptr, nullptr, nullptr, nullptr, nullptr, 0, W + O_OUTB);
    lnout_kernel<<<dim3(16, 2), blk, 0, stream>>>(W + O_OUTB, now, nob, (float*)d_out);
}

// Round 4
// 579.679 us; speedup vs baseline: 2.9610x; 1.0635x over previous
//
#include <hip/hip_runtime.h>
#include <math.h>

#define Bn 2
#define Cn_ 128
#define Hn 64
#define Wn 64
#define Ln 4096
#define Nn 16

static constexpr float EPS_LN_C = 1e-6f;
static constexpr float EPS_BN_C = 1e-5f;

__device__ __forceinline__ float softplusf_(float x) {
    return fmaxf(x, 0.f) + log1pf(__expf(-fabsf(x)));
}
__device__ __forceinline__ float sigmoidf_(float x) {
    return 1.f / (1.f + __expf(-x));
}

// ---------------- LayerNorm (channel-split 4-way, LDS reduce) ----------------
// 128 channels per pixel. Block = 256 threads = 64 pixels x 4 channel-quarters.
// WRITE_OUT=0: store mean/rstd arrays. WRITE_OUT=1: write normalized output.
// inB (optional) supplies channels 64..127 (for concat LN).
template <int WRITE_OUT>
__global__ __launch_bounds__(256) void ln_kernel(
    const float* __restrict__ inA, const float* __restrict__ inB, int csA,
    const float* __restrict__ lw, const float* __restrict__ lb,
    float* __restrict__ mean, float* __restrict__ rstd,
    float* __restrict__ out, int csOut) {
    int b = blockIdx.y;
    int lane = threadIdx.x & 63;
    int q = threadIdx.x >> 6;
    int px = blockIdx.x * 64 + lane;
    __shared__ float s_s[4][64], s_s2[4][64];
    __shared__ float s_m[64], s_r[64];
    float s = 0.f, s2 = 0.f;
#pragma unroll
    for (int i = 0; i < 32; i++) {
        int c = q * 32 + i;
        const float* ptr = (inB && c >= 64) ? (inB + ((size_t)b * 64 + (c - 64)) * Ln)
                                            : (inA + ((size_t)b * csA + c) * Ln);
        float v = ptr[px];
        s += v; s2 += v * v;
    }
    s_s[q][lane] = s; s_s2[q][lane] = s2;
    __syncthreads();
    if (q == 0) {
        float ts = s_s[0][lane] + s_s[1][lane] + s_s[2][lane] + s_s[3][lane];
        float t2 = s_s2[0][lane] + s_s2[1][lane] + s_s2[2][lane] + s_s2[3][lane];
        float m = ts / 128.f;
        float var = fmaxf(t2 / 128.f - m * m, 0.f);
        float r = 1.f / sqrtf(var + EPS_LN_C);
        if (!WRITE_OUT) { mean[b * Ln + px] = m; rstd[b * Ln + px] = r; }
        s_m[lane] = m; s_r[lane] = r;
    }
    __syncthreads();
    if (WRITE_OUT) {
        float m = s_m[lane], r = s_r[lane];
#pragma unroll
        for (int i = 0; i < 32; i++) {
            int c = q * 32 + i;
            const float* ptr = (inB && c >= 64) ? (inB + ((size_t)b * 64 + (c - 64)) * Ln)
                                                : (inA + ((size_t)b * csA + c) * Ln);
            float v = ptr[px];
            out[((size_t)b * csOut + c) * Ln + px] = (v - m) * r * lw[c] + lb[c];
        }
    }
}

// ---------------- generic 1x1 conv, 4 pixels/thread (float4), clamped rows ----------------
__global__ __launch_bounds__(256) void conv1x1_kernel(
    const float* __restrict__ inA, const float* __restrict__ inB,
    int cinA, int csA, int cinB, int csB, int cout, int csOut,
    const float* __restrict__ w, const float* __restrict__ bias,
    const float* __restrict__ lnm, const float* __restrict__ lnr,
    const float* __restrict__ lnw, const float* __restrict__ lnb,
    const float* __restrict__ bng, const float* __restrict__ bnbe,
    const float* __restrict__ bnm, const float* __restrict__ bnv,
    int epilogue, float* __restrict__ out) {
    int b = blockIdx.z;
    int o0 = blockIdx.y * 8;
    int l = (blockIdx.x * blockDim.x + threadIdx.x) * 4;
    int cin = cinA + cinB;
    const float* wr_[8];
    float4 acc[8];
#pragma unroll
    for (int j = 0; j < 8; j++) {
        int o = min(o0 + j, cout - 1);
        wr_[j] = w + (size_t)o * cin;
        float bj = bias[o];
        acc[j] = make_float4(bj, bj, bj, bj);
    }
    bool ln = (lnw != nullptr);
    float4 m4 = make_float4(0, 0, 0, 0), r4 = make_float4(0, 0, 0, 0);
    if (ln) {
        m4 = *(const float4*)(lnm + b * Ln + l);
        r4 = *(const float4*)(lnr + b * Ln + l);
    }
    const float* pa = inA + (size_t)b * csA * Ln + l;
    for (int c = 0; c < cinA; c++) {
        float4 v = *(const float4*)(pa + (size_t)c * Ln);
        if (ln) {
            float lwv = lnw[c], lb2 = lnb[c];
            v.x = (v.x - m4.x) * r4.x * lwv + lb2;
            v.y = (v.y - m4.y) * r4.y * lwv + lb2;
            v.z = (v.z - m4.z) * r4.z * lwv + lb2;
            v.w = (v.w - m4.w) * r4.w * lwv + lb2;
        }
#pragma unroll
        for (int j = 0; j < 8; j++) {
            float wv = wr_[j][c];
            acc[j].x = fmaf(wv, v.x, acc[j].x);
            acc[j].y = fmaf(wv, v.y, acc[j].y);
            acc[j].z = fmaf(wv, v.z, acc[j].z);
            acc[j].w = fmaf(wv, v.w, acc[j].w);
        }
    }
    if (inB) {
        const float* pb = inB + (size_t)b * csB * Ln + l;
        for (int c = 0; c < cinB; c++) {
            float4 v = *(const float4*)(pb + (size_t)c * Ln);
#pragma unroll
            for (int j = 0; j < 8; j++) {
                float wv = wr_[j][cinA + c];
                acc[j].x = fmaf(wv, v.x, acc[j].x);
                acc[j].y = fmaf(wv, v.y, acc[j].y);
                acc[j].z = fmaf(wv, v.z, acc[j].z);
                acc[j].w = fmaf(wv, v.w, acc[j].w);
            }
        }
    }
#pragma unroll
    for (int j = 0; j < 8; j++) {
        int o = o0 + j;
        if (o >= cout) continue;
        float4 v = acc[j];
        if (epilogue == 1) {
            float sc = (1.f / sqrtf(bnv[o] + EPS_BN_C)) * bng[o];
            float sh = bnbe[o] - bnm[o] * sc;
            v.x = fmaxf(fmaf(v.x, sc, sh), 0.f);
            v.y = fmaxf(fmaf(v.y, sc, sh), 0.f);
            v.z = fmaxf(fmaf(v.z, sc, sh), 0.f);
            v.w = fmaxf(fmaf(v.w, sc, sh), 0.f);
        } else if (epilogue == 2) {
            v.x = sigmoidf_(v.x); v.y = sigmoidf_(v.y);
            v.z = sigmoidf_(v.z); v.w = sigmoidf_(v.w);
        }
        *(float4*)(out + ((size_t)b * csOut + o) * Ln + l) = v;
    }
}

// ---------------- depthwise 3x3 SAME + bias + SiLU (LN inline on mamba half) ----------------
__global__ void dwconv_kernel(const float* __restrict__ xp,
                              const float* __restrict__ mean1, const float* __restrict__ rstd1,
                              const float* __restrict__ lnw, const float* __restrict__ lnb,
                              const float* __restrict__ wm, const float* __restrict__ bm,
                              const float* __restrict__ wr, const float* __restrict__ br,
                              float* __restrict__ xm, float* __restrict__ xr) {
    int b = blockIdx.z;
    int c2 = blockIdx.y;
    int l = blockIdx.x * blockDim.x + threadIdx.x;
    int h = l >> 6, w = l & 63;
    bool mamba = (c2 < 128);
    const float* in = xp + ((size_t)b * 256 + c2) * Ln;
    const float* wt = mamba ? (wm + c2 * 9) : (wr + (c2 - 128) * 9);
    float lw = 0.f, lbv = 0.f;
    if (mamba) { lw = lnw[c2]; lbv = lnb[c2]; }
    float acc = mamba ? bm[c2] : br[c2 - 128];
#pragma unroll
    for (int dh = -1; dh <= 1; dh++) {
#pragma unroll
        for (int dw = -1; dw <= 1; dw++) {
            int hh = h + dh, ww = w + dw;
            if (hh < 0 || hh > 63 || ww < 0 || ww > 63) continue;
            int l2 = hh * 64 + ww;
            float v = in[l2];
            if (mamba) v = (v - mean1[b * Ln + l2]) * rstd1[b * Ln + l2] * lw + lbv;
            acc = fmaf(v, wt[(dh + 1) * 3 + (dw + 1)], acc);
        }
    }
    float o = acc * sigmoidf_(acc);
    if (mamba) xm[((size_t)b * 128 + c2) * Ln + l] = o;
    else       xr[((size_t)b * 128 + (c2 - 128)) * Ln + l] = o;
}

// ---------------- counting sort (4 classes) per batch; within class, index DESCENDING ----------------
__global__ __launch_bounds__(1024) void sort_kernel(const float* __restrict__ mfg,
                                                    const float* __restrict__ mbg,
                                                    const float* __restrict__ muc,
                                                    int* __restrict__ sidx) {
    int b = blockIdx.x;
    int t = threadIdx.x;
    const int PT = 4;
    __shared__ unsigned int wsum0[16], wsum1[16];
    __shared__ unsigned int tot01s, tot23s;

    int cls[PT];
    unsigned int c01 = 0, c23 = 0;
#pragma unroll
    for (int q = 0; q < PT; q++) {
        int j = t * PT + q;
        int i = Ln - 1 - j;
        float f = mfg[b * Ln + i], g = mbg[b * Ln + i], u = muc[b * Ln + i];
        int k = (f > 0.5f) ? 3 : (g > 0.5f) ? 2 : (u > 0.5f) ? 1 : 0;
        cls[q] = k;
        if (k == 0) c01 += 1u;
        else if (k == 1) c01 += (1u << 16);
        else if (k == 2) c23 += 1u;
        else c23 += (1u << 16);
    }
    unsigned int s01 = c01, s23 = c23;
    int lane = t & 63;
    for (int d = 1; d < 64; d <<= 1) {
        unsigned int o01 = __shfl_up(s01, (unsigned)d, 64);
        unsigned int o23 = __shfl_up(s23, (unsigned)d, 64);
        if (lane >= d) { s01 += o01; s23 += o23; }
    }
    int wid = t >> 6;
    if (lane == 63) { wsum0[wid] = s01; wsum1[wid] = s23; }
    __syncthreads();
    if (t == 0) {
        unsigned int a0 = 0, a1 = 0;
        for (int k2 = 0; k2 < 16; k2++) {
            unsigned int v0 = wsum0[k2], v1 = wsum1[k2];
            wsum0[k2] = a0; wsum1[k2] = a1;
            a0 += v0; a1 += v1;
        }
        tot01s = a0; tot23s = a1;
    }
    __syncthreads();
    unsigned int ex01 = s01 - c01 + wsum0[wid];
    unsigned int ex23 = s23 - c23 + wsum1[wid];
    unsigned int cnt1 = tot01s >> 16;
    unsigned int cnt2 = tot23s & 0xffffu, cnt3 = tot23s >> 16;
    unsigned int off3 = 0, off2 = cnt3, off1 = cnt3 + cnt2, off0 = cnt3 + cnt2 + cnt1;
    unsigned int run0 = ex01 & 0xffffu, run1 = ex01 >> 16;
    unsigned int run2 = ex23 & 0xffffu, run3 = ex23 >> 16;
#pragma unroll
    for (int q = 0; q < PT; q++) {
        int j = t * PT + q;
        int i = Ln - 1 - j;
        int k = cls[q];
        unsigned int pos;
        if (k == 0) pos = off0 + run0++;
        else if (k == 1) pos = off1 + run1++;
        else if (k == 2) pos = off2 + run2++;
        else pos = off3 + run3++;
        sidx[b * Ln + pos] = i;
    }
}

// ---------------- gather: us[b,c,t] = xm[b,c,sidx[b,t]] ----------------
__global__ __launch_bounds__(256) void gather_kernel(const float* __restrict__ xm,
                                                     const int* __restrict__ sidx,
                                                     float* __restrict__ us) {
    int b = blockIdx.z;
    int c = blockIdx.y;
    int t = blockIdx.x * 256 + threadIdx.x;
    int pix = sidx[b * Ln + t];
    us[((size_t)b * 128 + c) * Ln + t] = xm[((size_t)b * 128 + c) * Ln + pix];
}

// ---------------- delta: ds[b,c,l] = softplus(dtb[c] + sum_r dtw[c,r]*dbl[b,r,l]) ----------------
template <int R>
__global__ __launch_bounds__(256) void delta_kernel(
    const float* __restrict__ dbl, int nout,
    const float* __restrict__ dtw, const float* __restrict__ dtb, int Cch,
    float* __restrict__ ds) {
    int b = blockIdx.z;
    int c0 = blockIdx.y * 8;
    int l = (blockIdx.x * blockDim.x + threadIdx.x) * 4;
    float4 a[R];
#pragma unroll
    for (int r = 0; r < R; r++) a[r] = *(const float4*)(dbl + ((size_t)b * nout + r) * Ln + l);
#pragma unroll
    for (int j = 0; j < 8; j++) {
        int c = c0 + j;
        float bj = dtb[c];
        float4 acc = make_float4(bj, bj, bj, bj);
#pragma unroll
        for (int r = 0; r < R; r++) {
            float wv = dtw[c * R + r];
            acc.x = fmaf(wv, a[r].x, acc.x);
            acc.y = fmaf(wv, a[r].y, acc.y);
            acc.z = fmaf(wv, a[r].z, acc.z);
            acc.w = fmaf(wv, a[r].w, acc.w);
        }
        float4 o;
        o.x = softplusf_(acc.x); o.y = softplusf_(acc.y);
        o.z = softplusf_(acc.z); o.w = softplusf_(acc.w);
        *(float4*)(ds + ((size_t)b * Cch + c) * Ln + l) = o;
    }
}

// ================= chunked selective scan =================
#define NCHUNK 32
#define CG 8  // 16-step groups per chunk (chunk = 128 steps)

#define DPPADD(p) do { \
    p += __int_as_float(__builtin_amdgcn_update_dpp(0, __float_as_int(p), 0xB1, 0xF, 0xF, true)); \
    p += __int_as_float(__builtin_amdgcn_update_dpp(0, __float_as_int(p), 0x4E, 0xF, 0xF, true)); \
    p += __int_as_float(__builtin_amdgcn_update_dpp(0, __float_as_int(p), 0x124, 0xF, 0xF, true)); \
    p += __int_as_float(__builtin_amdgcn_update_dpp(0, __float_as_int(p), 0x128, 0xF, 0xF, true)); \
} while (0)

// ---- phase 1: local scan + a-product, no output, no C ----
template <int REV>
__device__ __forceinline__ void p1_chunk(const float* __restrict__ up, const float* __restrict__ dp,
                                         const float* __restrict__ bp, float A, int c0,
                                         float& hout, float& Pout) {
    float h = 0.f, P = 1.f;
    float4 U0[4], D0[4], B0[4], U1[4], D1[4], B1[4];
#define PHYS1(ci) (REV ? (255 - (ci)) : (ci))
#define LOAD1(U, D, Bb, ci) do { int pb_ = PHYS1(ci) * 16; \
    _Pragma("unroll") for (int j_ = 0; j_ < 4; ++j_) { \
        U[j_]  = *(const float4*)(up + pb_ + 4 * j_); \
        D[j_]  = *(const float4*)(dp + pb_ + 4 * j_); \
        Bb[j_] = *(const float4*)(bp + pb_ + 4 * j_); \
    } } while (0)
#define STEP1(u_, d_, B_) do { float a_ = __expf((d_) * A); h = fmaf(a_, h, (d_) * (u_) * (B_)); P *= a_; } while (0)
#define COMP1(U, D, Bb) do { \
    if (!REV) { _Pragma("unroll") for (int j_ = 0; j_ < 4; ++j_) { \
        STEP1(U[j_].x, D[j_].x, Bb[j_].x); STEP1(U[j_].y, D[j_].y, Bb[j_].y); \
        STEP1(U[j_].z, D[j_].z, Bb[j_].z); STEP1(U[j_].w, D[j_].w, Bb[j_].w); } } \
    else { _Pragma("unroll") for (int j_ = 3; j_ >= 0; --j_) { \
        STEP1(U[j_].w, D[j_].w, Bb[j_].w); STEP1(U[j_].z, D[j_].z, Bb[j_].z); \
        STEP1(U[j_].y, D[j_].y, Bb[j_].y); STEP1(U[j_].x, D[j_].x, Bb[j_].x); } } } while (0)
    LOAD1(U0, D0, B0, c0);
    for (int it = 0; it < CG; it += 2) {
        LOAD1(U1, D1, B1, c0 + it + 1);
        COMP1(U0, D0, B0);
        if (it + 2 < CG) LOAD1(U0, D0, B0, c0 + it + 2);
        COMP1(U1, D1, B1);
    }
    hout = h; Pout = P;
#undef PHYS1
#undef LOAD1
#undef STEP1
#undef COMP1
}

__global__ __launch_bounds__(64) void scan_p1_kernel(
    const float* __restrict__ xm, const float* __restrict__ us,
    const float* __restrict__ df, const float* __restrict__ dblf, const float* __restrict__ Alf,
    const float* __restrict__ db, const float* __restrict__ dblb, const float* __restrict__ Alb,
    const float* __restrict__ dsd, const float* __restrict__ dbls, const float* __restrict__ Als,
    float* __restrict__ hf, float* __restrict__ Pp) {
    int g = blockIdx.x, k = blockIdx.y;
    int lane = threadIdx.x;
    int n = lane & 15, cl = lane >> 4;
    int c0 = k * CG;
    float h, P;
    if (g < 32) {
        int b = g >> 4, cg = g & 15, c = cg * 4 + cl;
        float A = -__expf(Alf[c * 16 + n]);
        p1_chunk<0>(xm + ((size_t)b * 128 + c) * Ln, df + ((size_t)b * 64 + c) * Ln,
                    dblf + ((size_t)b * 36 + 4 + n) * Ln, A, c0, h, P);
    } else if (g < 64) {
        int g2 = g - 32, b = g2 >> 4, cg = g2 & 15, c = cg * 4 + cl;
        float A = -__expf(Alb[c * 16 + n]);
        p1_chunk<1>(xm + ((size_t)b * 128 + 64 + c) * Ln, db + ((size_t)b * 64 + c) * Ln,
                    dblb + ((size_t)b * 36 + 4 + n) * Ln, A, c0, h, P);
    } else {
        int g2 = g - 64, b = g2 >> 5, cg = g2 & 31, c = cg * 4 + cl;
        float A = -__expf(Als[c * 16 + n]);
        p1_chunk<0>(us + ((size_t)b * 128 + c) * Ln, dsd + ((size_t)b * 128 + c) * Ln,
                    dbls + ((size_t)b * 40 + 8 + n) * Ln, A, c0, h, P);
    }
    int o = (g * NCHUNK + k) * 64 + lane;
    hf[o] = h; Pp[o] = P;
}

// ---- stitch ----
__global__ void scan_stitch_kernel(const float* __restrict__ hf, const float* __restrict__ Pp,
                                   float* __restrict__ hi) {
    int id = blockIdx.x * blockDim.x + threadIdx.x;
    int g = id >> 6, lane = id & 63;
    float Pk[NCHUNK], Hk[NCHUNK];
#pragma unroll
    for (int k = 0; k < NCHUNK; k++) {
        int o = (g * NCHUNK + k) * 64 + lane;
        Pk[k] = Pp[o]; Hk[k] = hf[o];
    }
    float h = 0.f;
#pragma unroll
    for (int k = 0; k < NCHUNK; k++) {
        int o = (g * NCHUNK + k) * 64 + lane;
        hi[o] = h;
        h = fmaf(Pk[k], h, Hk[k]);
    }
}

// ---- phase 2 ----
#define STEPP(u_, d_, B_, C_) ({ \
    float dA_ = __expf((d_) * A); \
    h = fmaf(dA_, h, (d_) * (u_) * (B_)); \
    float p_ = h * (C_); \
    DPPADD(p_); \
    fmaf((u_), Dc, p_); })

template <int MODE>  // 0 fwd, 1 rev, 2 sid
__device__ __forceinline__ void p2_chunk(const float* __restrict__ up, const float* __restrict__ dp,
                                         const float* __restrict__ bp, const float* __restrict__ cp,
                                         const int* __restrict__ sp, float* __restrict__ yp,
                                         float A, float Dc, int n, int c0, float h) {
    constexpr bool REV = (MODE == 1);
    constexpr bool SIDM = (MODE == 2);
    float4 U0[4], D0[4], B0[4], C0[4], U1[4], D1[4], B1[4], C1[4];
    int4 I0[4] = {}, I1[4] = {};
#define PHYS(ci) (REV ? (255 - (ci)) : (ci))
#define LOADC(U, D, Bb, Cc, I, ci) do { int pb_ = PHYS(ci) * 16; \
    _Pragma("unroll") for (int j_ = 0; j_ < 4; ++j_) { \
        U[j_]  = *(const float4*)(up + pb_ + 4 * j_); \
        D[j_]  = *(const float4*)(dp + pb_ + 4 * j_); \
        Bb[j_] = *(const float4*)(bp + pb_ + 4 * j_); \
        Cc[j_] = *(const float4*)(cp + pb_ + 4 * j_); \
        if (SIDM) I[j_] = *(const int4*)(sp + pb_ + 4 * j_); \
    } } while (0)
#define COMPC(U, D, Bb, Cc, I, ci) do { int pb_ = PHYS(ci) * 16; \
    if (SIDM) { \
        _Pragma("unroll") for (int j_ = 0; j_ < 4; ++j_) { \
            float y0_ = STEPP(U[j_].x, D[j_].x, Bb[j_].x, Cc[j_].x); if (n == 0) yp[I[j_].x] = y0_; \
            float y1_ = STEPP(U[j_].y, D[j_].y, Bb[j_].y, Cc[j_].y); if (n == 0) yp[I[j_].y] = y1_; \
            float y2_ = STEPP(U[j_].z, D[j_].z, Bb[j_].z, Cc[j_].z); if (n == 0) yp[I[j_].z] = y2_; \
            float y3_ = STEPP(U[j_].w, D[j_].w, Bb[j_].w, Cc[j_].w); if (n == 0) yp[I[j_].w] = y3_; \
        } \
    } else if (!REV) { \
        _Pragma("unroll") for (int j_ = 0; j_ < 4; ++j_) { \
            float4 y4_; \
            y4_.x = STEPP(U[j_].x, D[j_].x, Bb[j_].x, Cc[j_].x); \
            y4_.y = STEPP(U[j_].y, D[j_].y, Bb[j_].y, Cc[j_].y); \
            y4_.z = STEPP(U[j_].z, D[j_].z, Bb[j_].z, Cc[j_].z); \
            y4_.w = STEPP(U[j_].w, D[j_].w, Bb[j_].w, Cc[j_].w); \
            if (n == 0) *(float4*)(yp + pb_ + 4 * j_) = y4_; \
        } \
    } else { \
        _Pragma("unroll") for (int j_ = 3; j_ >= 0; --j_) { \
            float4 y4_; \
            y4_.w = STEPP(U[j_].w, D[j_].w, Bb[j_].w, Cc[j_].w); \
            y4_.z = STEPP(U[j_].z, D[j_].z, Bb[j_].z, Cc[j_].z); \
            y4_.y = STEPP(U[j_].y, D[j_].y, Bb[j_].y, Cc[j_].y); \
            y4_.x = STEPP(U[j_].x, D[j_].x, Bb[j_].x, Cc[j_].x); \
            if (n == 0) *(float4*)(yp + pb_ + 4 * j_) = y4_; \
        } \
    } } while (0)
    LOADC(U0, D0, B0, C0, I0, c0);
    for (int it = 0; it < CG; it += 2) {
        LOADC(U1, D1, B1, C1, I1, c0 + it + 1);
        COMPC(U0, D0, B0, C0, I0, c0 + it);
        if (it + 2 < CG) LOADC(U0, D0, B0, C0, I0, c0 + it + 2);
        COMPC(U1, D1, B1, C1, I1, c0 + it + 1);
    }
#undef PHYS
#undef LOADC
#undef COMPC
}

__global__ __launch_bounds__(64) void scan_p2_kernel(
    const float* __restrict__ xm, const float* __restrict__ us,
    const float* __restrict__ df, const float* __restrict__ dblf,
    const float* __restrict__ Alf, const float* __restrict__ Dfp,
    const float* __restrict__ db, const float* __restrict__ dblb,
    const float* __restrict__ Alb, const float* __restrict__ Dbp,
    const float* __restrict__ dsd, const float* __restrict__ dbls,
    const float* __restrict__ Als, const float* __restrict__ Dsp,
    const int* __restrict__ sidx, const float* __restrict__ hi,
    float* __restrict__ yf, float* __restrict__ yb, float* __restrict__ ys) {
    int g = blockIdx.x, k = blockIdx.y;
    int lane = threadIdx.x;
    int n = lane & 15, cl = lane >> 4;
    int c0 = k * CG;
    float h0 = hi[(g * NCHUNK + k) * 64 + lane];
    if (g < 32) {
        int b = g >> 4, cg = g & 15, c = cg * 4 + cl;
        float A = -__expf(Alf[c * 16 + n]);
        p2_chunk<0>(xm + ((size_t)b * 128 + c) * Ln, df + ((size_t)b * 64 + c) * Ln,
                    dblf + ((size_t)b * 36 + 4 + n) * Ln, dblf + ((size_t)b * 36 + 20 + n) * Ln,
                    nullptr, yf + ((size_t)b * 64 + c) * Ln, A, Dfp[c], n, c0, h0);
    } else if (g < 64) {
        int g2 = g - 32, b = g2 >> 4, cg = g2 & 15, c = cg * 4 + cl;
        float A = -__expf(Alb[c * 16 + n]);
        p2_chunk<1>(xm + ((size_t)b * 128 + 64 + c) * Ln, db + ((size_t)b * 64 + c) * Ln,
                    dblb + ((size_t)b * 36 + 4 + n) * Ln, dblb + ((size_t)b * 36 + 20 + n) * Ln,
                    nullptr, yb + ((size_t)b * 64 + c) * Ln, A, Dbp[c], n, c0, h0);
    } else {
        int g2 = g - 64, b = g2 >> 5, cg = g2 & 31, c = cg * 4 + cl;
        float A = -__expf(Als[c * 16 + n]);
        p2_chunk<2>(us + ((size_t)b * 128 + c) * Ln, dsd + ((size_t)b * 128 + c) * Ln,
                    dbls + ((size_t)b * 40 + 8 + n) * Ln, dbls + ((size_t)b * 40 + 24 + n) * Ln,
                    sidx + b * Ln, ys + ((size_t)b * 128 + c) * Ln, A, Dsp[c], n, c0, h0);
    }
}

// ---------------- fused = g*sid + (1-g)*cat (float4) ----------------
__global__ void fuse_kernel(const float4* __restrict__ gate, const float4* __restrict__ ysb,
                            const float4* __restrict__ cat, float4* __restrict__ out, int n4) {
    int i = blockIdx.x * blockDim.x + threadIdx.x;
    if (i < n4) {
        float4 g = gate[i], s = ysb[i], c = cat[i], o;
        o.x = g.x * s.x + (1.f - g.x) * c.x;
        o.y = g.y * s.y + (1.f - g.y) * c.y;
        o.z = g.z * s.z + (1.f - g.z) * c.z;
        o.w = g.w * s.w + (1.f - g.w) * c.w;
        out[i] = o;
    }
}

extern "C" void kernel_launch(void* const* d_in, const int* in_sizes, int n_in,
                              void* d_out, int out_size, void* d_ws, size_t ws_size,
                              hipStream_t stream) {
    const float* x    = (const float*)d_in[0];
    const float* mfg  = (const float*)d_in[1];
    const float* mbg  = (const float*)d_in[2];
    const float* muc  = (const float*)d_in[3];
    const float* niw  = (const float*)d_in[4];
    const float* nib  = (const float*)d_in[5];
    const float* inw  = (const float*)d_in[6];
    const float* inb  = (const float*)d_in[7];
    const float* lmw  = (const float*)d_in[8];
    const float* lmb  = (const float*)d_in[9];
    const float* cmw  = (const float*)d_in[10];
    const float* cmb  = (const float*)d_in[11];
    const float* crw  = (const float*)d_in[12];
    const float* crb  = (const float*)d_in[13];
    const float* xwf  = (const float*)d_in[14];
    const float* xbf  = (const float*)d_in[15];
    const float* dtwf = (const float*)d_in[16];
    const float* dtbf = (const float*)d_in[17];
    const float* Alf  = (const float*)d_in[18];
    const float* Dfp  = (const float*)d_in[19];
    const float* xwb  = (const float*)d_in[20];
    const float* xbb  = (const float*)d_in[21];
    const float* dtwb = (const float*)d_in[22];
    const float* dtbb = (const float*)d_in[23];
    const float* Alb  = (const float*)d_in[24];
    const float* Dbp  = (const float*)d_in[25];
    const float* xws  = (const float*)d_in[26];
    const float* xbs  = (const float*)d_in[27];
    const float* dtws = (const float*)d_in[28];
    const float* dtbs = (const float*)d_in[29];
    const float* Als  = (const float*)d_in[30];
    const float* Dsp  = (const float*)d_in[31];
    const float* lcw  = (const float*)d_in[32];
    const float* lcb  = (const float*)d_in[33];
    const float* g0w  = (const float*)d_in[34];
    const float* g0b  = (const float*)d_in[35];
    const float* bng  = (const float*)d_in[36];
    const float* bnbe = (const float*)d_in[37];
    const float* bnm  = (const float*)d_in[38];
    const float* bnv  = (const float*)d_in[39];
    const float* g1w  = (const float*)d_in[40];
    const float* g1b  = (const float*)d_in[41];
    const float* outw = (const float*)d_in[42];
    const float* outb = (const float*)d_in[43];
    const float* now  = (const float*)d_in[44];
    const float* nob  = (const float*)d_in[45];

    float* W = (float*)d_ws;
    const size_t O_XP    = 0;          // (B,256,L); dead after dwconv -> HF/PP/HI, then FUSED/OUTB
    const size_t O_MEAN0 = 2097152;
    const size_t O_RSTD0 = 2105344;
    const size_t O_MEAN1 = 2113536;
    const size_t O_RSTD1 = 2121728;
    const size_t O_XM    = 2129920;    // (B,128,L)
    const size_t O_XR    = 3178496;    // (B,128,L)
    const size_t O_DBLF  = 4227072;    // (B,36,L)
    const size_t O_DBLB  = 4521984;    // (B,36,L)
    const size_t O_DBLS  = 4816896;    // (B,40,L)
    const size_t O_DF    = 5144576;    // (B,64,L)   } contiguous 1M -> CATLN reuse
    const size_t O_DB    = 5668864;    // (B,64,L)   }
    const size_t O_DS    = 6193152;    // (B,128,L)  -> GBUF reuse
    const size_t O_US    = 7241728;    // (B,128,L)  -> GATE reuse
    const size_t O_YF    = 8290304;    // (B,64,L)
    const size_t O_YB    = 8814592;
    const size_t O_YS    = 9338880;    // (B,128,L)
    const size_t O_IDX   = 10387456;   // 8192 ints
    const size_t O_CATLN = O_DF;
    const size_t O_GBUF  = O_DS;
    const size_t O_GATE  = O_US;
    const size_t O_FUSED = O_XP;
    const size_t O_OUTB  = O_XP + 1048576;
    const size_t O_HF    = O_XP;           // 262144 each, dead-XP region during scan
    const size_t O_PP    = O_XP + 262144;
    const size_t O_HI    = O_XP + 524288;

    int* idxp = (int*)(W + O_IDX);
    dim3 blk(256);

    // 1. LN stats of input x
    ln_kernel<0><<<dim3(64, 2), blk, 0, stream>>>(x, nullptr, 128, nullptr, nullptr,
                                                  W + O_MEAN0, W + O_RSTD0, nullptr, 0);
    // 2. in_proj (LN inline) -> xp
    conv1x1_kernel<<<dim3(4, 32, 2), blk, 0, stream>>>(
        x, nullptr, 128, 128, 0, 0, 256, 256, inw, inb,
        W + O_MEAN0, W + O_RSTD0, niw, nib,
        nullptr, nullptr, nullptr, nullptr, 0, W + O_XP);
    // 3. LN stats of x_mamba (xp ch 0..127)
    ln_kernel<0><<<dim3(64, 2), blk, 0, stream>>>(W + O_XP, nullptr, 256, nullptr, nullptr,
                                                  W + O_MEAN1, W + O_RSTD1, nullptr, 0);
    // 4. dwconv both halves
    dwconv_kernel<<<dim3(16, 256, 2), blk, 0, stream>>>(
        W + O_XP, W + O_MEAN1, W + O_RSTD1, lmw, lmb, cmw, cmb, crw, crb, W + O_XM, W + O_XR);
    // 5. priority sort
    sort_kernel<<<2, 1024, 0, stream>>>(mfg, mbg, muc, idxp);
    // 6. x_proj fwd/bwd -> dbl buffers
    conv1x1_kernel<<<dim3(4, 5, 2), blk, 0, stream>>>(
        W + O_XM, nullptr, 64, 128, 0, 0, 36, 36, xwf, xbf,
        nullptr, nullptr, nullptr, nullptr, nullptr, nullptr, nullptr, nullptr, 0, W + O_DBLF);
    conv1x1_kernel<<<dim3(4, 5, 2), blk, 0, stream>>>(
        W + O_XM + (size_t)64 * Ln, nullptr, 64, 128, 0, 0, 36, 36, xwb, xbb,
        nullptr, nullptr, nullptr, nullptr, nullptr, nullptr, nullptr, nullptr, 0, W + O_DBLB);
    // 7. delta fwd/bwd
    delta_kernel<4><<<dim3(4, 8, 2), blk, 0, stream>>>(W + O_DBLF, 36, dtwf, dtbf, 64, W + O_DF);
    delta_kernel<4><<<dim3(4, 8, 2), blk, 0, stream>>>(W + O_DBLB, 36, dtwb, dtbb, 64, W + O_DB);
    // 8. gather for SID
    gather_kernel<<<dim3(16, 128, 2), blk, 0, stream>>>(W + O_XM, idxp, W + O_US);
    // 9. x_proj SID
    conv1x1_kernel<<<dim3(4, 5, 2), blk, 0, stream>>>(
        W + O_US, nullptr, 128, 128, 0, 0, 40, 40, xws, xbs,
        nullptr, nullptr, nullptr, nullptr, nullptr, nullptr, nullptr, nullptr, 0, W + O_DBLS);
    // 10. delta SID
    delta_kernel<8><<<dim3(4, 16, 2), blk, 0, stream>>>(W + O_DBLS, 40, dtws, dtbs, 128, W + O_DS);
    // 11. chunked scan
    scan_p1_kernel<<<dim3(128, NCHUNK), 64, 0, stream>>>(
        W + O_XM, W + O_US,
        W + O_DF, W + O_DBLF, Alf,
        W + O_DB, W + O_DBLB, Alb,
        W + O_DS, W + O_DBLS, Als,
        W + O_HF, W + O_PP);
    scan_stitch_kernel<<<32, 256, 0, stream>>>(W + O_HF, W + O_PP, W + O_HI);
    scan_p2_kernel<<<dim3(128, NCHUNK), 64, 0, stream>>>(
        W + O_XM, W + O_US,
        W + O_DF, W + O_DBLF, Alf, Dfp,
        W + O_DB, W + O_DBLB, Alb, Dbp,
        W + O_DS, W + O_DBLS, Als, Dsp,
        idxp, W + O_HI, W + O_YF, W + O_YB, W + O_YS);
    // 12. LN of concat(yf, yb)
    ln_kernel<1><<<dim3(64, 2), blk, 0, stream>>>(W + O_YF, W + O_YB, 64, lcw, lcb,
                                                  nullptr, nullptr, W + O_CATLN, 128);
    // 13. g0 conv + BN + ReLU
    conv1x1_kernel<<<dim3(4, 16, 2), blk, 0, stream>>>(
        W + O_CATLN, W + O_YS, 128, 128, 128, 128, 128, 128, g0w, g0b,
        nullptr, nullptr, nullptr, nullptr, bng, bnbe, bnm, bnv, 1, W + O_GBUF);
    // 14. g1 conv + sigmoid
    conv1x1_kernel<<<dim3(4, 16, 2), blk, 0, stream>>>(
        W + O_GBUF, nullptr, 128, 128, 0, 0, 128, 128, g1w, g1b,
        nullptr, nullptr, nullptr, nullptr, nullptr, nullptr, nullptr, nullptr, 2, W + O_GATE);
    // 15. fuse
    fuse_kernel<<<1024, blk, 0, stream>>>(
        (const float4*)(W + O_GATE), (const float4*)(W + O_YS), (const float4*)(W + O_CATLN),
        (float4*)(W + O_FUSED), Bn * Cn_ * Ln / 4);
    // 16. out conv
    conv1x1_kernel<<<dim3(4, 16, 2), blk, 0, stream>>>(
        W + O_FUSED, W + O_XR, 128, 128, 128, 128, 128, 128, outw, outb,
        nullptr, nullptr, nullptr, nullptr, nullptr, nullptr, nullptr, nullptr, 0, W + O_OUTB);
    // 17. final LN -> d_out
    ln_kernel<1><<<dim3(64, 2), blk, 0, stream>>>(W + O_OUTB, nullptr, 128, now, nob,
                                                  nullptr, nullptr, (float*)d_out, 128);
}

// Round 5
// 336.042 us; speedup vs baseline: 5.1078x; 1.7250x over previous
//
#include <hip/hip_runtime.h>
#include <math.h>

#define Bn 2
#define Cn_ 128
#define Hn 64
#define Wn 64
#define Ln 4096
#define Nn 16

static constexpr float EPS_LN_C = 1e-6f;
static constexpr float EPS_BN_C = 1e-5f;

__device__ __forceinline__ float softplusf_(float x) {
    return fmaxf(x, 0.f) + log1pf(__expf(-fabsf(x)));
}
__device__ __forceinline__ float sigmoidf_(float x) {
    return 1.f / (1.f + __expf(-x));
}

// ---------------- LayerNorm: compute stats + write normalized output ----------------
// 128 channels/pixel. Block = 256 threads = 64 pixels x 4 channel-quarters.
// inB (optional) supplies channels 64..127 (concat LN).
__global__ __launch_bounds__(256) void ln_kernel(
    const float* __restrict__ inA, const float* __restrict__ inB, int csA,
    const float* __restrict__ lw, const float* __restrict__ lb,
    float* __restrict__ out, int csOut) {
    int b = blockIdx.y;
    int lane = threadIdx.x & 63;
    int q = threadIdx.x >> 6;
    int px = blockIdx.x * 64 + lane;
    __shared__ float s_s[4][64], s_s2[4][64];
    __shared__ float s_m[64], s_r[64];
    float s = 0.f, s2 = 0.f;
#pragma unroll
    for (int i = 0; i < 32; i++) {
        int c = q * 32 + i;
        const float* ptr = (inB && c >= 64) ? (inB + ((size_t)b * 64 + (c - 64)) * Ln)
                                            : (inA + ((size_t)b * csA + c) * Ln);
        float v = ptr[px];
        s += v; s2 += v * v;
    }
    s_s[q][lane] = s; s_s2[q][lane] = s2;
    __syncthreads();
    if (q == 0) {
        float ts = s_s[0][lane] + s_s[1][lane] + s_s[2][lane] + s_s[3][lane];
        float t2 = s_s2[0][lane] + s_s2[1][lane] + s_s2[2][lane] + s_s2[3][lane];
        float m = ts / 128.f;
        float var = fmaxf(t2 / 128.f - m * m, 0.f);
        s_m[lane] = m; s_r[lane] = 1.f / sqrtf(var + EPS_LN_C);
    }
    __syncthreads();
    float m = s_m[lane], r = s_r[lane];
#pragma unroll
    for (int i = 0; i < 32; i++) {
        int c = q * 32 + i;
        const float* ptr = (inB && c >= 64) ? (inB + ((size_t)b * 64 + (c - 64)) * Ln)
                                            : (inA + ((size_t)b * csA + c) * Ln);
        float v = ptr[px];
        out[((size_t)b * csOut + c) * Ln + px] = (v - m) * r * lw[c] + lb[c];
    }
}

// ---------------- 1x1 conv, split-K, double-buffered inner loop ----------------
// 4 pixels/thread (float4), 8 outputs/block. blockIdx.y = og*ksn + ks.
// blockIdx.z >= Bn selects the "alt branch" (wB/inAoffB) for fused f/b xproj.
// ksn==1: write bias+epilogue directly to out. ksn>1: write raw partial to p[ks].
__global__ __launch_bounds__(256) void conv1x1_kernel(
    const float* __restrict__ inA, const float* __restrict__ inB,
    int cinA, int csA, int cinB, int csB, int cout, int csOut,
    const float* __restrict__ w, const float* __restrict__ wB,
    const float* __restrict__ bias, const float* __restrict__ biasB, long inAoffB,
    const float* __restrict__ bng, const float* __restrict__ bnbe,
    const float* __restrict__ bnm, const float* __restrict__ bnv,
    int epilogue, float* __restrict__ out,
    int ksn, int kchunk,
    float* __restrict__ p0, float* __restrict__ p1,
    float* __restrict__ p2, float* __restrict__ p3, long pbrOff) {
    int z = blockIdx.z;
    int br = 0, b = z;
    if (z >= Bn) { br = 1; b = z - Bn; }
    int ks = 0, og = blockIdx.y;
    if (ksn > 1) { ks = blockIdx.y % ksn; og = blockIdx.y / ksn; }
    int o0 = og * 8;
    int k0 = ks * kchunk;
    int CL = kchunk;
    int cin = cinA + cinB;
    const float* wsel = br ? wB : w;
    const float* bsel = br ? biasB : bias;
    const float* wrow[8];
#pragma unroll
    for (int j = 0; j < 8; j++)
        wrow[j] = wsel + (size_t)min(o0 + j, cout - 1) * cin + k0;
    int l = (blockIdx.x * 256 + threadIdx.x) * 4;
    const float* src;
    if (k0 < cinA) src = inA + (br ? inAoffB : 0) + ((size_t)b * csA + k0) * Ln + l;
    else           src = inB + ((size_t)b * csB + (k0 - cinA)) * Ln + l;
    float4 acc[8];
#pragma unroll
    for (int j = 0; j < 8; j++) {
        float bj = (ksn > 1) ? 0.f : bsel[min(o0 + j, cout - 1)];
        acc[j] = make_float4(bj, bj, bj, bj);
    }
    float4 v0[4], v1[4];
#define CLD(V, c0_) do { _Pragma("unroll") for (int j_ = 0; j_ < 4; ++j_) \
        V[j_] = *(const float4*)(src + (size_t)((c0_) + j_) * Ln); } while (0)
#define CFM(V, c0_) do { _Pragma("unroll") for (int j_ = 0; j_ < 4; ++j_) { \
        _Pragma("unroll") for (int o_ = 0; o_ < 8; ++o_) { \
            float wv_ = wrow[o_][(c0_) + j_]; \
            acc[o_].x = fmaf(wv_, V[j_].x, acc[o_].x); \
            acc[o_].y = fmaf(wv_, V[j_].y, acc[o_].y); \
            acc[o_].z = fmaf(wv_, V[j_].z, acc[o_].z); \
            acc[o_].w = fmaf(wv_, V[j_].w, acc[o_].w); } } } while (0)
    CLD(v0, 0);
    for (int cc = 0; cc < CL; cc += 8) {
        CLD(v1, cc + 4);
        CFM(v0, cc);
        if (cc + 8 < CL) CLD(v0, cc + 8);
        CFM(v1, cc + 4);
    }
#undef CLD
#undef CFM
    if (ksn > 1) {
        float* pp = (ks == 0) ? p0 : (ks == 1) ? p1 : (ks == 2) ? p2 : p3;
        if (br) pp += pbrOff;
#pragma unroll
        for (int j = 0; j < 8; j++) {
            int o = o0 + j;
            if (o >= cout) continue;
            *(float4*)(pp + ((size_t)b * cout + o) * Ln + l) = acc[j];
        }
    } else {
#pragma unroll
        for (int j = 0; j < 8; j++) {
            int o = o0 + j;
            if (o >= cout) continue;
            float4 v = acc[j];
            if (epilogue == 1) {
                float sc = (1.f / sqrtf(bnv[o] + EPS_BN_C)) * bng[o];
                float sh = bnbe[o] - bnm[o] * sc;
                v.x = fmaxf(fmaf(v.x, sc, sh), 0.f);
                v.y = fmaxf(fmaf(v.y, sc, sh), 0.f);
                v.z = fmaxf(fmaf(v.z, sc, sh), 0.f);
                v.w = fmaxf(fmaf(v.w, sc, sh), 0.f);
            } else if (epilogue == 2) {
                v.x = sigmoidf_(v.x); v.y = sigmoidf_(v.y);
                v.z = sigmoidf_(v.z); v.w = sigmoidf_(v.w);
            }
            *(float4*)(out + ((size_t)b * csOut + o) * Ln + l) = v;
        }
    }
}

// ---------------- combine: sum partials + bias + epilogue ----------------
__global__ __launch_bounds__(256) void combine_kernel(
    const float* __restrict__ p0, const float* __restrict__ p1,
    const float* __restrict__ p2, const float* __restrict__ p3, int ksn,
    const float* __restrict__ bias,
    const float* __restrict__ bng, const float* __restrict__ bnbe,
    const float* __restrict__ bnm, const float* __restrict__ bnv,
    int epilogue, float* __restrict__ out, int cout, int n4) {
    int i = blockIdx.x * 256 + threadIdx.x;
    if (i >= n4) return;
    size_t e = (size_t)i * 4;
    int o = (int)((e / Ln) % cout);
    float4 a = *(const float4*)(p0 + e);
    if (ksn > 1) { float4 t = *(const float4*)(p1 + e); a.x += t.x; a.y += t.y; a.z += t.z; a.w += t.w; }
    if (ksn > 2) { float4 t = *(const float4*)(p2 + e); a.x += t.x; a.y += t.y; a.z += t.z; a.w += t.w; }
    if (ksn > 3) { float4 t = *(const float4*)(p3 + e); a.x += t.x; a.y += t.y; a.z += t.z; a.w += t.w; }
    float bj = bias[o];
    a.x += bj; a.y += bj; a.z += bj; a.w += bj;
    if (epilogue == 1) {
        float sc = (1.f / sqrtf(bnv[o] + EPS_BN_C)) * bng[o];
        float sh = bnbe[o] - bnm[o] * sc;
        a.x = fmaxf(fmaf(a.x, sc, sh), 0.f);
        a.y = fmaxf(fmaf(a.y, sc, sh), 0.f);
        a.z = fmaxf(fmaf(a.z, sc, sh), 0.f);
        a.w = fmaxf(fmaf(a.w, sc, sh), 0.f);
    } else if (epilogue == 2) {
        a.x = sigmoidf_(a.x); a.y = sigmoidf_(a.y);
        a.z = sigmoidf_(a.z); a.w = sigmoidf_(a.w);
    }
    *(float4*)(out + e) = a;
}

// ---------------- depthwise 3x3 SAME + bias + SiLU (inputs pre-normalized) ----------------
__global__ void dwconv_kernel(const float* __restrict__ xmn, const float* __restrict__ xp,
                              const float* __restrict__ wm, const float* __restrict__ bm,
                              const float* __restrict__ wr, const float* __restrict__ brr,
                              float* __restrict__ xm, float* __restrict__ xr) {
    int b = blockIdx.z;
    int c2 = blockIdx.y;
    int l = blockIdx.x * blockDim.x + threadIdx.x;
    int h = l >> 6, w = l & 63;
    bool mamba = (c2 < 128);
    const float* in = mamba ? (xmn + ((size_t)b * 128 + c2) * Ln)
                            : (xp + ((size_t)b * 256 + c2) * Ln);
    const float* wt = mamba ? (wm + c2 * 9) : (wr + (c2 - 128) * 9);
    float acc = mamba ? bm[c2] : brr[c2 - 128];
#pragma unroll
    for (int dh = -1; dh <= 1; dh++) {
#pragma unroll
        for (int dw = -1; dw <= 1; dw++) {
            int hh = h + dh, ww = w + dw;
            if (hh < 0 || hh > 63 || ww < 0 || ww > 63) continue;
            acc = fmaf(in[hh * 64 + ww], wt[(dh + 1) * 3 + (dw + 1)], acc);
        }
    }
    float o = acc * sigmoidf_(acc);
    if (mamba) xm[((size_t)b * 128 + c2) * Ln + l] = o;
    else       xr[((size_t)b * 128 + (c2 - 128)) * Ln + l] = o;
}

// ---------------- counting sort (4 classes) per batch; within class, index DESCENDING ----------------
__global__ __launch_bounds__(1024) void sort_kernel(const float* __restrict__ mfg,
                                                    const float* __restrict__ mbg,
                                                    const float* __restrict__ muc,
                                                    int* __restrict__ sidx) {
    int b = blockIdx.x;
    int t = threadIdx.x;
    const int PT = 4;
    __shared__ unsigned int wsum0[16], wsum1[16];
    __shared__ unsigned int tot01s, tot23s;

    int cls[PT];
    unsigned int c01 = 0, c23 = 0;
#pragma unroll
    for (int q = 0; q < PT; q++) {
        int j = t * PT + q;
        int i = Ln - 1 - j;
        float f = mfg[b * Ln + i], g = mbg[b * Ln + i], u = muc[b * Ln + i];
        int k = (f > 0.5f) ? 3 : (g > 0.5f) ? 2 : (u > 0.5f) ? 1 : 0;
        cls[q] = k;
        if (k == 0) c01 += 1u;
        else if (k == 1) c01 += (1u << 16);
        else if (k == 2) c23 += 1u;
        else c23 += (1u << 16);
    }
    unsigned int s01 = c01, s23 = c23;
    int lane = t & 63;
    for (int d = 1; d < 64; d <<= 1) {
        unsigned int o01 = __shfl_up(s01, (unsigned)d, 64);
        unsigned int o23 = __shfl_up(s23, (unsigned)d, 64);
        if (lane >= d) { s01 += o01; s23 += o23; }
    }
    int wid = t >> 6;
    if (lane == 63) { wsum0[wid] = s01; wsum1[wid] = s23; }
    __syncthreads();
    if (t == 0) {
        unsigned int a0 = 0, a1 = 0;
        for (int k2 = 0; k2 < 16; k2++) {
            unsigned int v0 = wsum0[k2], v1 = wsum1[k2];
            wsum0[k2] = a0; wsum1[k2] = a1;
            a0 += v0; a1 += v1;
        }
        tot01s = a0; tot23s = a1;
    }
    __syncthreads();
    unsigned int ex01 = s01 - c01 + wsum0[wid];
    unsigned int ex23 = s23 - c23 + wsum1[wid];
    unsigned int cnt1 = tot01s >> 16;
    unsigned int cnt2 = tot23s & 0xffffu, cnt3 = tot23s >> 16;
    unsigned int off3 = 0, off2 = cnt3, off1 = cnt3 + cnt2, off0 = cnt3 + cnt2 + cnt1;
    unsigned int run0 = ex01 & 0xffffu, run1 = ex01 >> 16;
    unsigned int run2 = ex23 & 0xffffu, run3 = ex23 >> 16;
#pragma unroll
    for (int q = 0; q < PT; q++) {
        int j = t * PT + q;
        int i = Ln - 1 - j;
        int k = cls[q];
        unsigned int pos;
        if (k == 0) pos = off0 + run0++;
        else if (k == 1) pos = off1 + run1++;
        else if (k == 2) pos = off2 + run2++;
        else pos = off3 + run3++;
        sidx[b * Ln + pos] = i;
    }
}

// ---------------- gather: us[b,c,t] = xm[b,c,sidx[b,t]] ----------------
__global__ __launch_bounds__(256) void gather_kernel(const float* __restrict__ xm,
                                                     const int* __restrict__ sidx,
                                                     float* __restrict__ us) {
    int b = blockIdx.z;
    int c = blockIdx.y;
    int t = blockIdx.x * 256 + threadIdx.x;
    int pix = sidx[b * Ln + t];
    us[((size_t)b * 128 + c) * Ln + t] = xm[((size_t)b * 128 + c) * Ln + pix];
}

// ---------------- delta: ds[b,c,l] = softplus(dtb[c] + sum_r dtw[c,r]*dbl[b,r,l]) ----------------
template <int R>
__global__ __launch_bounds__(256) void delta_kernel(
    const float* __restrict__ dbl, int nout,
    const float* __restrict__ dtw, const float* __restrict__ dtb, int Cch,
    float* __restrict__ ds) {
    int b = blockIdx.z;
    int c0 = blockIdx.y * 8;
    int l = (blockIdx.x * blockDim.x + threadIdx.x) * 4;
    float4 a[R];
#pragma unroll
    for (int r = 0; r < R; r++) a[r] = *(const float4*)(dbl + ((size_t)b * nout + r) * Ln + l);
#pragma unroll
    for (int j = 0; j < 8; j++) {
        int c = c0 + j;
        float bj = dtb[c];
        float4 acc = make_float4(bj, bj, bj, bj);
#pragma unroll
        for (int r = 0; r < R; r++) {
            float wv = dtw[c * R + r];
            acc.x = fmaf(wv, a[r].x, acc.x);
            acc.y = fmaf(wv, a[r].y, acc.y);
            acc.z = fmaf(wv, a[r].z, acc.z);
            acc.w = fmaf(wv, a[r].w, acc.w);
        }
        float4 o;
        o.x = softplusf_(acc.x); o.y = softplusf_(acc.y);
        o.z = softplusf_(acc.z); o.w = softplusf_(acc.w);
        *(float4*)(ds + ((size_t)b * Cch + c) * Ln + l) = o;
    }
}

// ================= chunked selective scan =================
#define NCHUNK 32
#define CG 8  // 16-step groups per chunk (chunk = 128 steps)

#define DPPADD(p) do { \
    p += __int_as_float(__builtin_amdgcn_update_dpp(0, __float_as_int(p), 0xB1, 0xF, 0xF, true)); \
    p += __int_as_float(__builtin_amdgcn_update_dpp(0, __float_as_int(p), 0x4E, 0xF, 0xF, true)); \
    p += __int_as_float(__builtin_amdgcn_update_dpp(0, __float_as_int(p), 0x124, 0xF, 0xF, true)); \
    p += __int_as_float(__builtin_amdgcn_update_dpp(0, __float_as_int(p), 0x128, 0xF, 0xF, true)); \
} while (0)

// ---- phase 1: local scan + a-product ----
template <int REV>
__device__ __forceinline__ void p1_chunk(const float* __restrict__ up, const float* __restrict__ dp,
                                         const float* __restrict__ bp, float A, int c0,
                                         float& hout, float& Pout) {
    float h = 0.f, P = 1.f;
    float4 U0[4], D0[4], B0[4], U1[4], D1[4], B1[4];
#define PHYS1(ci) (REV ? (255 - (ci)) : (ci))
#define LOAD1(U, D, Bb, ci) do { int pb_ = PHYS1(ci) * 16; \
    _Pragma("unroll") for (int j_ = 0; j_ < 4; ++j_) { \
        U[j_]  = *(const float4*)(up + pb_ + 4 * j_); \
        D[j_]  = *(const float4*)(dp + pb_ + 4 * j_); \
        Bb[j_] = *(const float4*)(bp + pb_ + 4 * j_); \
    } } while (0)
#define STEP1(u_, d_, B_) do { float a_ = __expf((d_) * A); h = fmaf(a_, h, (d_) * (u_) * (B_)); P *= a_; } while (0)
#define COMP1(U, D, Bb) do { \
    if (!REV) { _Pragma("unroll") for (int j_ = 0; j_ < 4; ++j_) { \
        STEP1(U[j_].x, D[j_].x, Bb[j_].x); STEP1(U[j_].y, D[j_].y, Bb[j_].y); \
        STEP1(U[j_].z, D[j_].z, Bb[j_].z); STEP1(U[j_].w, D[j_].w, Bb[j_].w); } } \
    else { _Pragma("unroll") for (int j_ = 3; j_ >= 0; --j_) { \
        STEP1(U[j_].w, D[j_].w, Bb[j_].w); STEP1(U[j_].z, D[j_].z, Bb[j_].z); \
        STEP1(U[j_].y, D[j_].y, Bb[j_].y); STEP1(U[j_].x, D[j_].x, Bb[j_].x); } } } while (0)
    LOAD1(U0, D0, B0, c0);
    for (int it = 0; it < CG; it += 2) {
        LOAD1(U1, D1, B1, c0 + it + 1);
        COMP1(U0, D0, B0);
        if (it + 2 < CG) LOAD1(U0, D0, B0, c0 + it + 2);
        COMP1(U1, D1, B1);
    }
    hout = h; Pout = P;
#undef PHYS1
#undef LOAD1
#undef STEP1
#undef COMP1
}

__global__ __launch_bounds__(64) void scan_p1_kernel(
    const float* __restrict__ xm, const float* __restrict__ us,
    const float* __restrict__ df, const float* __restrict__ dblf, const float* __restrict__ Alf,
    const float* __restrict__ db, const float* __restrict__ dblb, const float* __restrict__ Alb,
    const float* __restrict__ dsd, const float* __restrict__ dbls, const float* __restrict__ Als,
    float* __restrict__ hf, float* __restrict__ Pp) {
    int g = blockIdx.x, k = blockIdx.y;
    int lane = threadIdx.x;
    int n = lane & 15, cl = lane >> 4;
    int c0 = k * CG;
    float h, P;
    if (g < 32) {
        int b = g >> 4, cg = g & 15, c = cg * 4 + cl;
        float A = -__expf(Alf[c * 16 + n]);
        p1_chunk<0>(xm + ((size_t)b * 128 + c) * Ln, df + ((size_t)b * 64 + c) * Ln,
                    dblf + ((size_t)b * 36 + 4 + n) * Ln, A, c0, h, P);
    } else if (g < 64) {
        int g2 = g - 32, b = g2 >> 4, cg = g2 & 15, c = cg * 4 + cl;
        float A = -__expf(Alb[c * 16 + n]);
        p1_chunk<1>(xm + ((size_t)b * 128 + 64 + c) * Ln, db + ((size_t)b * 64 + c) * Ln,
                    dblb + ((size_t)b * 36 + 4 + n) * Ln, A, c0, h, P);
    } else {
        int g2 = g - 64, b = g2 >> 5, cg = g2 & 31, c = cg * 4 + cl;
        float A = -__expf(Als[c * 16 + n]);
        p1_chunk<0>(us + ((size_t)b * 128 + c) * Ln, dsd + ((size_t)b * 128 + c) * Ln,
                    dbls + ((size_t)b * 40 + 8 + n) * Ln, A, c0, h, P);
    }
    int o = (g * NCHUNK + k) * 64 + lane;
    hf[o] = h; Pp[o] = P;
}

// ---- stitch ----
__global__ void scan_stitch_kernel(const float* __restrict__ hf, const float* __restrict__ Pp,
                                   float* __restrict__ hi) {
    int id = blockIdx.x * blockDim.x + threadIdx.x;
    int g = id >> 6, lane = id & 63;
    float Pk[NCHUNK], Hk[NCHUNK];
#pragma unroll
    for (int k = 0; k < NCHUNK; k++) {
        int o = (g * NCHUNK + k) * 64 + lane;
        Pk[k] = Pp[o]; Hk[k] = hf[o];
    }
    float h = 0.f;
#pragma unroll
    for (int k = 0; k < NCHUNK; k++) {
        int o = (g * NCHUNK + k) * 64 + lane;
        hi[o] = h;
        h = fmaf(Pk[k], h, Hk[k]);
    }
}

// ---- phase 2 ----
#define STEPP(u_, d_, B_, C_) ({ \
    float dA_ = __expf((d_) * A); \
    h = fmaf(dA_, h, (d_) * (u_) * (B_)); \
    float p_ = h * (C_); \
    DPPADD(p_); \
    fmaf((u_), Dc, p_); })

template <int MODE>  // 0 fwd, 1 rev, 2 sid
__device__ __forceinline__ void p2_chunk(const float* __restrict__ up, const float* __restrict__ dp,
                                         const float* __restrict__ bp, const float* __restrict__ cp,
                                         const int* __restrict__ sp, float* __restrict__ yp,
                                         float A, float Dc, int n, int c0, float h) {
    constexpr bool REV = (MODE == 1);
    constexpr bool SIDM = (MODE == 2);
    float4 U0[4], D0[4], B0[4], C0[4], U1[4], D1[4], B1[4], C1[4];
    int4 I0[4] = {}, I1[4] = {};
#define PHYS(ci) (REV ? (255 - (ci)) : (ci))
#define LOADC(U, D, Bb, Cc, I, ci) do { int pb_ = PHYS(ci) * 16; \
    _Pragma("unroll") for (int j_ = 0; j_ < 4; ++j_) { \
        U[j_]  = *(const float4*)(up + pb_ + 4 * j_); \
        D[j_]  = *(const float4*)(dp + pb_ + 4 * j_); \
        Bb[j_] = *(const float4*)(bp + pb_ + 4 * j_); \
        Cc[j_] = *(const float4*)(cp + pb_ + 4 * j_); \
        if (SIDM) I[j_] = *(const int4*)(sp + pb_ + 4 * j_); \
    } } while (0)
#define COMPC(U, D, Bb, Cc, I, ci) do { int pb_ = PHYS(ci) * 16; \
    if (SIDM) { \
        _Pragma("unroll") for (int j_ = 0; j_ < 4; ++j_) { \
            float y0_ = STEPP(U[j_].x, D[j_].x, Bb[j_].x, Cc[j_].x); if (n == 0) yp[I[j_].x] = y0_; \
            float y1_ = STEPP(U[j_].y, D[j_].y, Bb[j_].y, Cc[j_].y); if (n == 0) yp[I[j_].y] = y1_; \
            float y2_ = STEPP(U[j_].z, D[j_].z, Bb[j_].z, Cc[j_].z); if (n == 0) yp[I[j_].z] = y2_; \
            float y3_ = STEPP(U[j_].w, D[j_].w, Bb[j_].w, Cc[j_].w); if (n == 0) yp[I[j_].w] = y3_; \
        } \
    } else if (!REV) { \
        _Pragma("unroll") for (int j_ = 0; j_ < 4; ++j_) { \
            float4 y4_; \
            y4_.x = STEPP(U[j_].x, D[j_].x, Bb[j_].x, Cc[j_].x); \
            y4_.y = STEPP(U[j_].y, D[j_].y, Bb[j_].y, Cc[j_].y); \
            y4_.z = STEPP(U[j_].z, D[j_].z, Bb[j_].z, Cc[j_].z); \
            y4_.w = STEPP(U[j_].w, D[j_].w, Bb[j_].w, Cc[j_].w); \
            if (n == 0) *(float4*)(yp + pb_ + 4 * j_) = y4_; \
        } \
    } else { \
        _Pragma("unroll") for (int j_ = 3; j_ >= 0; --j_) { \
            float4 y4_; \
            y4_.w = STEPP(U[j_].w, D[j_].w, Bb[j_].w, Cc[j_].w); \
            y4_.z = STEPP(U[j_].z, D[j_].z, Bb[j_].z, Cc[j_].z); \
            y4_.y = STEPP(U[j_].y, D[j_].y, Bb[j_].y, Cc[j_].y); \
            y4_.x = STEPP(U[j_].x, D[j_].x, Bb[j_].x, Cc[j_].x); \
            if (n == 0) *(float4*)(yp + pb_ + 4 * j_) = y4_; \
        } \
    } } while (0)
    LOADC(U0, D0, B0, C0, I0, c0);
    for (int it = 0; it < CG; it += 2) {
        LOADC(U1, D1, B1, C1, I1, c0 + it + 1);
        COMPC(U0, D0, B0, C0, I0, c0 + it);
        if (it + 2 < CG) LOADC(U0, D0, B0, C0, I0, c0 + it + 2);
        COMPC(U1, D1, B1, C1, I1, c0 + it + 1);
    }
#undef PHYS
#undef LOADC
#undef COMPC
}

__global__ __launch_bounds__(64) void scan_p2_kernel(
    const float* __restrict__ xm, const float* __restrict__ us,
    const float* __restrict__ df, const float* __restrict__ dblf,
    const float* __restrict__ Alf, const float* __restrict__ Dfp,
    const float* __restrict__ db, const float* __restrict__ dblb,
    const float* __restrict__ Alb, const float* __restrict__ Dbp,
    const float* __restrict__ dsd, const float* __restrict__ dbls,
    const float* __restrict__ Als, const float* __restrict__ Dsp,
    const int* __restrict__ sidx, const float* __restrict__ hi,
    float* __restrict__ yf, float* __restrict__ yb, float* __restrict__ ys) {
    int g = blockIdx.x, k = blockIdx.y;
    int lane = threadIdx.x;
    int n = lane & 15, cl = lane >> 4;
    int c0 = k * CG;
    float h0 = hi[(g * NCHUNK + k) * 64 + lane];
    if (g < 32) {
        int b = g >> 4, cg = g & 15, c = cg * 4 + cl;
        float A = -__expf(Alf[c * 16 + n]);
        p2_chunk<0>(xm + ((size_t)b * 128 + c) * Ln, df + ((size_t)b * 64 + c) * Ln,
                    dblf + ((size_t)b * 36 + 4 + n) * Ln, dblf + ((size_t)b * 36 + 20 + n) * Ln,
                    nullptr, yf + ((size_t)b * 64 + c) * Ln, A, Dfp[c], n, c0, h0);
    } else if (g < 64) {
        int g2 = g - 32, b = g2 >> 4, cg = g2 & 15, c = cg * 4 + cl;
        float A = -__expf(Alb[c * 16 + n]);
        p2_chunk<1>(xm + ((size_t)b * 128 + 64 + c) * Ln, db + ((size_t)b * 64 + c) * Ln,
                    dblb + ((size_t)b * 36 + 4 + n) * Ln, dblb + ((size_t)b * 36 + 20 + n) * Ln,
                    nullptr, yb + ((size_t)b * 64 + c) * Ln, A, Dbp[c], n, c0, h0);
    } else {
        int g2 = g - 64, b = g2 >> 5, cg = g2 & 31, c = cg * 4 + cl;
        float A = -__expf(Als[c * 16 + n]);
        p2_chunk<2>(us + ((size_t)b * 128 + c) * Ln, dsd + ((size_t)b * 128 + c) * Ln,
                    dbls + ((size_t)b * 40 + 8 + n) * Ln, dbls + ((size_t)b * 40 + 24 + n) * Ln,
                    sidx + b * Ln, ys + ((size_t)b * 128 + c) * Ln, A, Dsp[c], n, c0, h0);
    }
}

// ---------------- fused = g*sid + (1-g)*cat (float4) ----------------
__global__ void fuse_kernel(const float4* __restrict__ gate, const float4* __restrict__ ysb,
                            const float4* __restrict__ cat, float4* __restrict__ out, int n4) {
    int i = blockIdx.x * blockDim.x + threadIdx.x;
    if (i < n4) {
        float4 g = gate[i], s = ysb[i], c = cat[i], o;
        o.x = g.x * s.x + (1.f - g.x) * c.x;
        o.y = g.y * s.y + (1.f - g.y) * c.y;
        o.z = g.z * s.z + (1.f - g.z) * c.z;
        o.w = g.w * s.w + (1.f - g.w) * c.w;
        out[i] = o;
    }
}

extern "C" void kernel_launch(void* const* d_in, const int* in_sizes, int n_in,
                              void* d_out, int out_size, void* d_ws, size_t ws_size,
                              hipStream_t stream) {
    const float* x    = (const float*)d_in[0];
    const float* mfg  = (const float*)d_in[1];
    const float* mbg  = (const float*)d_in[2];
    const float* muc  = (const float*)d_in[3];
    const float* niw  = (const float*)d_in[4];
    const float* nib  = (const float*)d_in[5];
    const float* inw  = (const float*)d_in[6];
    const float* inb  = (const float*)d_in[7];
    const float* lmw  = (const float*)d_in[8];
    const float* lmb  = (const float*)d_in[9];
    const float* cmw  = (const float*)d_in[10];
    const float* cmb  = (const float*)d_in[11];
    const float* crw  = (const float*)d_in[12];
    const float* crb  = (const float*)d_in[13];
    const float* xwf  = (const float*)d_in[14];
    const float* xbf  = (const float*)d_in[15];
    const float* dtwf = (const float*)d_in[16];
    const float* dtbf = (const float*)d_in[17];
    const float* Alf  = (const float*)d_in[18];
    const float* Dfp  = (const float*)d_in[19];
    const float* xwb  = (const float*)d_in[20];
    const float* xbb  = (const float*)d_in[21];
    const float* dtwb = (const float*)d_in[22];
    const float* dtbb = (const float*)d_in[23];
    const float* Alb  = (const float*)d_in[24];
    const float* Dbp  = (const float*)d_in[25];
    const float* xws  = (const float*)d_in[26];
    const float* xbs  = (const float*)d_in[27];
    const float* dtws = (const float*)d_in[28];
    const float* dtbs = (const float*)d_in[29];
    const float* Als  = (const float*)d_in[30];
    const float* Dsp  = (const float*)d_in[31];
    const float* lcw  = (const float*)d_in[32];
    const float* lcb  = (const float*)d_in[33];
    const float* g0w  = (const float*)d_in[34];
    const float* g0b  = (const float*)d_in[35];
    const float* bng  = (const float*)d_in[36];
    const float* bnbe = (const float*)d_in[37];
    const float* bnm  = (const float*)d_in[38];
    const float* bnv  = (const float*)d_in[39];
    const float* g1w  = (const float*)d_in[40];
    const float* g1b  = (const float*)d_in[41];
    const float* outw = (const float*)d_in[42];
    const float* outb = (const float*)d_in[43];
    const float* now  = (const float*)d_in[44];
    const float* nob  = (const float*)d_in[45];

    float* W = (float*)d_ws;
    // persistent buffers (floats)
    const size_t O_XP   = 0;          // (B,256,L) in_proj out; region reused heavily (see below)
    const size_t O_XM   = 2129920;    // (B,128,L) xnorm (step1-2), then dwconv xm
    const size_t O_XR   = 3178496;    // (B,128,L) dwconv xr (live to the end)
    const size_t O_DBLF = 4227072;    // (B,36,L)
    const size_t O_DBLB = 4521984;    // (B,36,L)
    const size_t O_DBLS = 4816896;    // (B,40,L)
    const size_t O_DF   = 5144576;    // (B,64,L)  } DF+DB = CATLN later
    const size_t O_DB   = 5668864;    // (B,64,L)  }
    const size_t O_DS   = 6193152;    // (B,128,L) xmnorm (step4-5), delta_s, then GBUF
    const size_t O_US   = 7241728;    // (B,128,L) gathered u; later GATE, then OUTB
    const size_t O_YF   = 8290304;    // (B,64,L)
    const size_t O_YB   = 8814592;    // (B,64,L)
    const size_t O_YS   = 9338880;    // (B,128,L)
    const size_t O_IDX  = 10387456;   // 8192 ints
    // time-multiplexed scratch
    const size_t S_INP  = O_XR;            // in_proj partials: 2 x 2,097,152 (XR..US dead at step 2)
    const size_t S_XP0  = O_XP;            // generic scratch in dead XP region
    const size_t O_HF   = O_XP;            // scan summaries (XP dead during scan)
    const size_t O_PP   = O_XP + 262144;
    const size_t O_HI   = O_XP + 524288;
    const size_t O_CATLN = O_DF;
    const size_t O_GBUF  = O_DS;
    const size_t O_GATE  = O_US;
    const size_t O_FUSED = O_XP;
    const size_t O_OUTB  = O_US;           // written after GATE is dead (post-fuse)

    int* idxp = (int*)(W + O_IDX);
    dim3 blk(256);
    const float* nil = nullptr;

    // 1. LN(x) -> xnorm @ XM
    ln_kernel<<<dim3(64, 2), blk, 0, stream>>>(x, nullptr, 128, niw, nib, W + O_XM, 128);
    // 2. in_proj conv, KS=2 (chunk 64): xnorm -> partials @ S_INP
    conv1x1_kernel<<<dim3(4, 32 * 2, 2), blk, 0, stream>>>(
        W + O_XM, nullptr, 128, 128, 0, 0, 256, 256, inw, nullptr, inb, nullptr, 0,
        nil, nil, nil, nil, 0, nullptr,
        2, 64, W + S_INP, W + S_INP + 2097152, nullptr, nullptr, 0);
    // 3. combine -> XP
    combine_kernel<<<2048, blk, 0, stream>>>(
        W + S_INP, W + S_INP + 2097152, nullptr, nullptr, 2, inb,
        nil, nil, nil, nil, 0, W + O_XP, 256, 524288);
    // 4. LN(xp[:,0:128]) -> xmnorm @ DS
    ln_kernel<<<dim3(64, 2), blk, 0, stream>>>(W + O_XP, nullptr, 256, lmw, lmb, W + O_DS, 128);
    // 5. dwconv -> XM (mamba), XR (res)
    dwconv_kernel<<<dim3(16, 256, 2), blk, 0, stream>>>(
        W + O_DS, W + O_XP, cmw, cmb, crw, crb, W + O_XM, W + O_XR);
    // 6. priority sort
    sort_kernel<<<2, 1024, 0, stream>>>(mfg, mbg, muc, idxp);
    // 7. xproj f+b fused conv, KS=2 (chunk 32): partials @ XP (XP dead after dwconv)
    //    layout: [f_ks0, f_ks1, b_ks0, b_ks1] x 294,912 floats
    conv1x1_kernel<<<dim3(4, 5 * 2, 4), blk, 0, stream>>>(
        W + O_XM, nullptr, 64, 128, 0, 0, 36, 36, xwf, xwb, xbf, xbb, (long)64 * Ln,
        nil, nil, nil, nil, 0, nullptr,
        2, 32, W + S_XP0, W + S_XP0 + 294912, nullptr, nullptr, (long)589824);
    // 8. combines -> DBLF, DBLB
    combine_kernel<<<288, blk, 0, stream>>>(
        W + S_XP0, W + S_XP0 + 294912, nullptr, nullptr, 2, xbf,
        nil, nil, nil, nil, 0, W + O_DBLF, 36, 73728);
    combine_kernel<<<288, blk, 0, stream>>>(
        W + S_XP0 + 589824, W + S_XP0 + 884736, nullptr, nullptr, 2, xbb,
        nil, nil, nil, nil, 0, W + O_DBLB, 36, 73728);
    // 9. delta f, b
    delta_kernel<4><<<dim3(4, 8, 2), blk, 0, stream>>>(W + O_DBLF, 36, dtwf, dtbf, 64, W + O_DF);
    delta_kernel<4><<<dim3(4, 8, 2), blk, 0, stream>>>(W + O_DBLB, 36, dtwb, dtbb, 64, W + O_DB);
    // 10. gather -> US
    gather_kernel<<<dim3(16, 128, 2), blk, 0, stream>>>(W + O_XM, idxp, W + O_US);
    // 11. xproj_s conv, KS=4 (chunk 32): partials @ XP
    conv1x1_kernel<<<dim3(4, 5 * 4, 2), blk, 0, stream>>>(
        W + O_US, nullptr, 128, 128, 0, 0, 40, 40, xws, nullptr, xbs, nullptr, 0,
        nil, nil, nil, nil, 0, nullptr,
        4, 32, W + S_XP0, W + S_XP0 + 327680, W + S_XP0 + 655360, W + S_XP0 + 983040, 0);
    // 12. combine -> DBLS
    combine_kernel<<<320, blk, 0, stream>>>(
        W + S_XP0, W + S_XP0 + 327680, W + S_XP0 + 655360, W + S_XP0 + 983040, 4, xbs,
        nil, nil, nil, nil, 0, W + O_DBLS, 40, 81920);
    // 13. delta s
    delta_kernel<8><<<dim3(4, 16, 2), blk, 0, stream>>>(W + O_DBLS, 40, dtws, dtbs, 128, W + O_DS);
    // 14. chunked scan (summaries in dead XP region)
    scan_p1_kernel<<<dim3(128, NCHUNK), 64, 0, stream>>>(
        W + O_XM, W + O_US,
        W + O_DF, W + O_DBLF, Alf,
        W + O_DB, W + O_DBLB, Alb,
        W + O_DS, W + O_DBLS, Als,
        W + O_HF, W + O_PP);
    scan_stitch_kernel<<<32, 256, 0, stream>>>(W + O_HF, W + O_PP, W + O_HI);
    scan_p2_kernel<<<dim3(128, NCHUNK), 64, 0, stream>>>(
        W + O_XM, W + O_US,
        W + O_DF, W + O_DBLF, Alf, Dfp,
        W + O_DB, W + O_DBLB, Alb, Dbp,
        W + O_DS, W + O_DBLS, Als, Dsp,
        idxp, W + O_HI, W + O_YF, W + O_YB, W + O_YS);
    // 15. LN(concat(yf,yb)) -> CATLN @ DF..DB
    ln_kernel<<<dim3(64, 2), blk, 0, stream>>>(W + O_YF, W + O_YB, 64, lcw, lcb, W + O_CATLN, 128);
    // 16. g0 conv, KS=4 (chunk 64): partials @ XP(x2), XM, US (all dead)
    conv1x1_kernel<<<dim3(4, 16 * 4, 2), blk, 0, stream>>>(
        W + O_CATLN, W + O_YS, 128, 128, 128, 128, 128, 128, g0w, nullptr, g0b, nullptr, 0,
        nil, nil, nil, nil, 0, nullptr,
        4, 64, W + O_XP, W + O_XP + 1048576, W + O_XM, W + O_US, 0);
    // 17. combine + BN + ReLU -> GBUF @ DS
    combine_kernel<<<1024, blk, 0, stream>>>(
        W + O_XP, W + O_XP + 1048576, W + O_XM, W + O_US, 4, g0b,
        bng, bnbe, bnm, bnv, 1, W + O_GBUF, 128, 262144);
    // 18. g1 conv, KS=2 (chunk 64): partials @ XP(x2); combine + sigmoid -> GATE @ US
    conv1x1_kernel<<<dim3(4, 16 * 2, 2), blk, 0, stream>>>(
        W + O_GBUF, nullptr, 128, 128, 0, 0, 128, 128, g1w, nullptr, g1b, nullptr, 0,
        nil, nil, nil, nil, 0, nullptr,
        2, 64, W + O_XP, W + O_XP + 1048576, nullptr, nullptr, 0);
    combine_kernel<<<1024, blk, 0, stream>>>(
        W + O_XP, W + O_XP + 1048576, nullptr, nullptr, 2, g1b,
        nil, nil, nil, nil, 2, W + O_GATE, 128, 262144);
    // 19. fuse -> FUSED @ XP[0:1M]
    fuse_kernel<<<1024, blk, 0, stream>>>(
        (const float4*)(W + O_GATE), (const float4*)(W + O_YS), (const float4*)(W + O_CATLN),
        (float4*)(W + O_FUSED), Bn * Cn_ * Ln / 4);
    // 20. out conv, KS=4 (chunk 64): partials @ XP[1M:2M], XM, GBUF(DS), YS (all dead)
    conv1x1_kernel<<<dim3(4, 16 * 4, 2), blk, 0, stream>>>(
        W + O_FUSED, W + O_XR, 128, 128, 128, 128, 128, 128, outw, nullptr, outb, nullptr, 0,
        nil, nil, nil, nil, 0, nullptr,
        4, 64, W + O_XP + 1048576, W + O_XM, W + O_GBUF, W + O_YS, 0);
    // 21. combine -> OUTB @ US (GATE dead after fuse)
    combine_kernel<<<1024, blk, 0, stream>>>(
        W + O_XP + 1048576, W + O_XM, W + O_GBUF, W + O_YS, 4, outb,
        nil, nil, nil, nil, 0, W + O_OUTB, 128, 262144);
    // 22. final LN -> d_out
    ln_kernel<<<dim3(64, 2), blk, 0, stream>>>(W + O_OUTB, nullptr, 128, now, nob,
                                               (float*)d_out, 128);
}

// Round 6
// 306.431 us; speedup vs baseline: 5.6013x; 1.0966x over previous
//
#include <hip/hip_runtime.h>
#include <math.h>

#define Bn 2
#define Cn_ 128
#define Hn 64
#define Wn 64
#define Ln 4096
#define Nn 16

static constexpr float EPS_LN_C = 1e-6f;
static constexpr float EPS_BN_C = 1e-5f;

__device__ __forceinline__ float softplusf_(float x) {
    return fmaxf(x, 0.f) + log1pf(__expf(-fabsf(x)));
}
__device__ __forceinline__ float sigmoidf_(float x) {
    return 1.f / (1.f + __expf(-x));
}

// ---------------- LayerNorm: stats + normalized output ----------------
__global__ __launch_bounds__(256) void ln_kernel(
    const float* __restrict__ inA, const float* __restrict__ inB, int csA,
    const float* __restrict__ lw, const float* __restrict__ lb,
    float* __restrict__ out, int csOut) {
    int b = blockIdx.y;
    int lane = threadIdx.x & 63;
    int q = threadIdx.x >> 6;
    int px = blockIdx.x * 64 + lane;
    __shared__ float s_s[4][64], s_s2[4][64];
    __shared__ float s_m[64], s_r[64];
    float s = 0.f, s2 = 0.f;
#pragma unroll
    for (int i = 0; i < 32; i++) {
        int c = q * 32 + i;
        const float* ptr = (inB && c >= 64) ? (inB + ((size_t)b * 64 + (c - 64)) * Ln)
                                            : (inA + ((size_t)b * csA + c) * Ln);
        float v = ptr[px];
        s += v; s2 += v * v;
    }
    s_s[q][lane] = s; s_s2[q][lane] = s2;
    __syncthreads();
    if (q == 0) {
        float ts = s_s[0][lane] + s_s[1][lane] + s_s[2][lane] + s_s[3][lane];
        float t2 = s_s2[0][lane] + s_s2[1][lane] + s_s2[2][lane] + s_s2[3][lane];
        float m = ts / 128.f;
        float var = fmaxf(t2 / 128.f - m * m, 0.f);
        s_m[lane] = m; s_r[lane] = 1.f / sqrtf(var + EPS_LN_C);
    }
    __syncthreads();
    float m = s_m[lane], r = s_r[lane];
#pragma unroll
    for (int i = 0; i < 32; i++) {
        int c = q * 32 + i;
        const float* ptr = (inB && c >= 64) ? (inB + ((size_t)b * 64 + (c - 64)) * Ln)
                                            : (inA + ((size_t)b * csA + c) * Ln);
        float v = ptr[px];
        out[((size_t)b * csOut + c) * Ln + px] = (v - m) * r * lw[c] + lb[c];
    }
}

// ---------------- 1x1 conv, split-K, 4 outputs/block, double-buffered ----------------
__global__ __launch_bounds__(256) void conv1x1_kernel(
    const float* __restrict__ inA, const float* __restrict__ inB,
    int cinA, int csA, int cinB, int csB, int cout, int csOut,
    const float* __restrict__ w, const float* __restrict__ wB,
    const float* __restrict__ bias, const float* __restrict__ biasB, long inAoffB,
    const float* __restrict__ bng, const float* __restrict__ bnbe,
    const float* __restrict__ bnm, const float* __restrict__ bnv,
    int epilogue, float* __restrict__ out,
    int ksn, int kchunk,
    float* __restrict__ p0, float* __restrict__ p1,
    float* __restrict__ p2, float* __restrict__ p3, long pbrOff) {
    int z = blockIdx.z;
    int br = 0, b = z;
    if (z >= Bn) { br = 1; b = z - Bn; }
    int ks = 0, og = blockIdx.y;
    if (ksn > 1) { ks = blockIdx.y % ksn; og = blockIdx.y / ksn; }
    int o0 = og * 4;
    int k0 = ks * kchunk;
    int CL = kchunk;
    int cin = cinA + cinB;
    const float* wsel = br ? wB : w;
    const float* bsel = br ? biasB : bias;
    const float* wrow[4];
#pragma unroll
    for (int j = 0; j < 4; j++)
        wrow[j] = wsel + (size_t)min(o0 + j, cout - 1) * cin + k0;
    int l = (blockIdx.x * 256 + threadIdx.x) * 4;
    const float* src;
    if (k0 < cinA) src = inA + (br ? inAoffB : 0) + ((size_t)b * csA + k0) * Ln + l;
    else           src = inB + ((size_t)b * csB + (k0 - cinA)) * Ln + l;
    float4 acc[4];
#pragma unroll
    for (int j = 0; j < 4; j++) {
        float bj = (ksn > 1) ? 0.f : bsel[min(o0 + j, cout - 1)];
        acc[j] = make_float4(bj, bj, bj, bj);
    }
    float4 v0[4], v1[4];
#define CLD(V, c0_) do { _Pragma("unroll") for (int j_ = 0; j_ < 4; ++j_) \
        V[j_] = *(const float4*)(src + (size_t)((c0_) + j_) * Ln); } while (0)
#define CFM(V, c0_) do { _Pragma("unroll") for (int j_ = 0; j_ < 4; ++j_) { \
        _Pragma("unroll") for (int o_ = 0; o_ < 4; ++o_) { \
            float wv_ = wrow[o_][(c0_) + j_]; \
            acc[o_].x = fmaf(wv_, V[j_].x, acc[o_].x); \
            acc[o_].y = fmaf(wv_, V[j_].y, acc[o_].y); \
            acc[o_].z = fmaf(wv_, V[j_].z, acc[o_].z); \
            acc[o_].w = fmaf(wv_, V[j_].w, acc[o_].w); } } } while (0)
    CLD(v0, 0);
    for (int cc = 0; cc < CL; cc += 8) {
        CLD(v1, cc + 4);
        CFM(v0, cc);
        if (cc + 8 < CL) CLD(v0, cc + 8);
        CFM(v1, cc + 4);
    }
#undef CLD
#undef CFM
    if (ksn > 1) {
        float* pp = (ks == 0) ? p0 : (ks == 1) ? p1 : (ks == 2) ? p2 : p3;
        if (br) pp += pbrOff;
#pragma unroll
        for (int j = 0; j < 4; j++) {
            int o = o0 + j;
            if (o >= cout) continue;
            *(float4*)(pp + ((size_t)b * cout + o) * Ln + l) = acc[j];
        }
    } else {
#pragma unroll
        for (int j = 0; j < 4; j++) {
            int o = o0 + j;
            if (o >= cout) continue;
            float4 v = acc[j];
            if (epilogue == 1) {
                float sc = (1.f / sqrtf(bnv[o] + EPS_BN_C)) * bng[o];
                float sh = bnbe[o] - bnm[o] * sc;
                v.x = fmaxf(fmaf(v.x, sc, sh), 0.f);
                v.y = fmaxf(fmaf(v.y, sc, sh), 0.f);
                v.z = fmaxf(fmaf(v.z, sc, sh), 0.f);
                v.w = fmaxf(fmaf(v.w, sc, sh), 0.f);
            } else if (epilogue == 2) {
                v.x = sigmoidf_(v.x); v.y = sigmoidf_(v.y);
                v.z = sigmoidf_(v.z); v.w = sigmoidf_(v.w);
            }
            *(float4*)(out + ((size_t)b * csOut + o) * Ln + l) = v;
        }
    }
}

// ---------------- combine: sum partials + bias + epilogue ----------------
__global__ __launch_bounds__(256) void combine_kernel(
    const float* __restrict__ p0, const float* __restrict__ p1,
    const float* __restrict__ p2, const float* __restrict__ p3, int ksn,
    const float* __restrict__ bias,
    const float* __restrict__ bng, const float* __restrict__ bnbe,
    const float* __restrict__ bnm, const float* __restrict__ bnv,
    int epilogue, float* __restrict__ out, int cout, int n4) {
    int i = blockIdx.x * 256 + threadIdx.x;
    if (i >= n4) return;
    size_t e = (size_t)i * 4;
    int o = (int)((e / Ln) % cout);
    float4 a = *(const float4*)(p0 + e);
    if (ksn > 1) { float4 t = *(const float4*)(p1 + e); a.x += t.x; a.y += t.y; a.z += t.z; a.w += t.w; }
    if (ksn > 2) { float4 t = *(const float4*)(p2 + e); a.x += t.x; a.y += t.y; a.z += t.z; a.w += t.w; }
    if (ksn > 3) { float4 t = *(const float4*)(p3 + e); a.x += t.x; a.y += t.y; a.z += t.z; a.w += t.w; }
    float bj = bias[o];
    a.x += bj; a.y += bj; a.z += bj; a.w += bj;
    if (epilogue == 1) {
        float sc = (1.f / sqrtf(bnv[o] + EPS_BN_C)) * bng[o];
        float sh = bnbe[o] - bnm[o] * sc;
        a.x = fmaxf(fmaf(a.x, sc, sh), 0.f);
        a.y = fmaxf(fmaf(a.y, sc, sh), 0.f);
        a.z = fmaxf(fmaf(a.z, sc, sh), 0.f);
        a.w = fmaxf(fmaf(a.w, sc, sh), 0.f);
    } else if (epilogue == 2) {
        a.x = sigmoidf_(a.x); a.y = sigmoidf_(a.y);
        a.z = sigmoidf_(a.z); a.w = sigmoidf_(a.w);
    }
    *(float4*)(out + e) = a;
}

// ---------------- depthwise 3x3 SAME + bias + SiLU ----------------
__global__ void dwconv_kernel(const float* __restrict__ xmn, const float* __restrict__ xp,
                              const float* __restrict__ wm, const float* __restrict__ bm,
                              const float* __restrict__ wr, const float* __restrict__ brr,
                              float* __restrict__ xm, float* __restrict__ xr) {
    int b = blockIdx.z;
    int c2 = blockIdx.y;
    int l = blockIdx.x * blockDim.x + threadIdx.x;
    int h = l >> 6, w = l & 63;
    bool mamba = (c2 < 128);
    const float* in = mamba ? (xmn + ((size_t)b * 128 + c2) * Ln)
                            : (xp + ((size_t)b * 256 + c2) * Ln);
    const float* wt = mamba ? (wm + c2 * 9) : (wr + (c2 - 128) * 9);
    float acc = mamba ? bm[c2] : brr[c2 - 128];
#pragma unroll
    for (int dh = -1; dh <= 1; dh++) {
#pragma unroll
        for (int dw = -1; dw <= 1; dw++) {
            int hh = h + dh, ww = w + dw;
            if (hh < 0 || hh > 63 || ww < 0 || ww > 63) continue;
            acc = fmaf(in[hh * 64 + ww], wt[(dh + 1) * 3 + (dw + 1)], acc);
        }
    }
    float o = acc * sigmoidf_(acc);
    if (mamba) xm[((size_t)b * 128 + c2) * Ln + l] = o;
    else       xr[((size_t)b * 128 + (c2 - 128)) * Ln + l] = o;
}

// ---------------- counting sort (4 classes) per batch; within class, index DESCENDING ----------------
__global__ __launch_bounds__(1024) void sort_kernel(const float* __restrict__ mfg,
                                                    const float* __restrict__ mbg,
                                                    const float* __restrict__ muc,
                                                    int* __restrict__ sidx) {
    int b = blockIdx.x;
    int t = threadIdx.x;
    const int PT = 4;
    __shared__ unsigned int wsum0[16], wsum1[16];
    __shared__ unsigned int tot01s, tot23s;

    int cls[PT];
    unsigned int c01 = 0, c23 = 0;
#pragma unroll
    for (int q = 0; q < PT; q++) {
        int j = t * PT + q;
        int i = Ln - 1 - j;
        float f = mfg[b * Ln + i], g = mbg[b * Ln + i], u = muc[b * Ln + i];
        int k = (f > 0.5f) ? 3 : (g > 0.5f) ? 2 : (u > 0.5f) ? 1 : 0;
        cls[q] = k;
        if (k == 0) c01 += 1u;
        else if (k == 1) c01 += (1u << 16);
        else if (k == 2) c23 += 1u;
        else c23 += (1u << 16);
    }
    unsigned int s01 = c01, s23 = c23;
    int lane = t & 63;
    for (int d = 1; d < 64; d <<= 1) {
        unsigned int o01 = __shfl_up(s01, (unsigned)d, 64);
        unsigned int o23 = __shfl_up(s23, (unsigned)d, 64);
        if (lane >= d) { s01 += o01; s23 += o23; }
    }
    int wid = t >> 6;
    if (lane == 63) { wsum0[wid] = s01; wsum1[wid] = s23; }
    __syncthreads();
    if (t == 0) {
        unsigned int a0 = 0, a1 = 0;
        for (int k2 = 0; k2 < 16; k2++) {
            unsigned int v0 = wsum0[k2], v1 = wsum1[k2];
            wsum0[k2] = a0; wsum1[k2] = a1;
            a0 += v0; a1 += v1;
        }
        tot01s = a0; tot23s = a1;
    }
    __syncthreads();
    unsigned int ex01 = s01 - c01 + wsum0[wid];
    unsigned int ex23 = s23 - c23 + wsum1[wid];
    unsigned int cnt1 = tot01s >> 16;
    unsigned int cnt2 = tot23s & 0xffffu, cnt3 = tot23s >> 16;
    unsigned int off3 = 0, off2 = cnt3, off1 = cnt3 + cnt2, off0 = cnt3 + cnt2 + cnt1;
    unsigned int run0 = ex01 & 0xffffu, run1 = ex01 >> 16;
    unsigned int run2 = ex23 & 0xffffu, run3 = ex23 >> 16;
#pragma unroll
    for (int q = 0; q < PT; q++) {
        int j = t * PT + q;
        int i = Ln - 1 - j;
        int k = cls[q];
        unsigned int pos;
        if (k == 0) pos = off0 + run0++;
        else if (k == 1) pos = off1 + run1++;
        else if (k == 2) pos = off2 + run2++;
        else pos = off3 + run3++;
        sidx[b * Ln + pos] = i;
    }
}

// ---------------- gather ----------------
__global__ __launch_bounds__(256) void gather_kernel(const float* __restrict__ xm,
                                                     const int* __restrict__ sidx,
                                                     float* __restrict__ us) {
    int b = blockIdx.z;
    int c = blockIdx.y;
    int t = blockIdx.x * 256 + threadIdx.x;
    int pix = sidx[b * Ln + t];
    us[((size_t)b * 128 + c) * Ln + t] = xm[((size_t)b * 128 + c) * Ln + pix];
}

// ---------------- delta (packed output): dpk[b][c/4][l/4][(c&3)*4+(l&3)] ----------------
template <int R, int NQ>
__global__ __launch_bounds__(256) void delta_kernel(
    const float* __restrict__ dbl, int nout,
    const float* __restrict__ dtw, const float* __restrict__ dtb,
    float* __restrict__ dpk) {
    int b = blockIdx.z;
    int c0 = blockIdx.y * 8;
    int l = (blockIdx.x * blockDim.x + threadIdx.x) * 4;
    float4 a[R];
#pragma unroll
    for (int r = 0; r < R; r++) a[r] = *(const float4*)(dbl + ((size_t)b * nout + r) * Ln + l);
#pragma unroll
    for (int j = 0; j < 8; j++) {
        int c = c0 + j;
        float bj = dtb[c];
        float4 acc = make_float4(bj, bj, bj, bj);
#pragma unroll
        for (int r = 0; r < R; r++) {
            float wv = dtw[c * R + r];
            acc.x = fmaf(wv, a[r].x, acc.x);
            acc.y = fmaf(wv, a[r].y, acc.y);
            acc.z = fmaf(wv, a[r].z, acc.z);
            acc.w = fmaf(wv, a[r].w, acc.w);
        }
        float4 o;
        o.x = softplusf_(acc.x); o.y = softplusf_(acc.y);
        o.z = softplusf_(acc.z); o.w = softplusf_(acc.w);
        *(float4*)(dpk + (((size_t)b * NQ + (c >> 2)) * 1024 + (l >> 2)) * 16 + (c & 3) * 4) = o;
    }
}

// ---------------- pack B/C: bpk[b][t/4][n*4+(t&3)] ----------------
__global__ __launch_bounds__(256) void pack_bc_kernel(
    const float* __restrict__ dblf, const float* __restrict__ dblb, const float* __restrict__ dbls,
    float* __restrict__ bf, float* __restrict__ cf,
    float* __restrict__ bb2, float* __restrict__ cb2,
    float* __restrict__ bs, float* __restrict__ cs) {
    int br = blockIdx.z;
    int b = blockIdx.y;
    int idx = blockIdx.x * 256 + threadIdx.x;   // 0..16383
    int tb = idx >> 4, n = idx & 15;
    const float* src; float* dB; float* dC; int RT, rB, rC;
    if (br == 0)      { src = dblf; dB = bf;  dC = cf;  RT = 36; rB = 4; rC = 20; }
    else if (br == 1) { src = dblb; dB = bb2; dC = cb2; RT = 36; rB = 4; rC = 20; }
    else              { src = dbls; dB = bs;  dC = cs;  RT = 40; rB = 8; rC = 24; }
    float4 vB = *(const float4*)(src + ((size_t)b * RT + rB + n) * Ln + tb * 4);
    float4 vC = *(const float4*)(src + ((size_t)b * RT + rC + n) * Ln + tb * 4);
    *(float4*)(dB + ((size_t)b * 1024 + tb) * 64 + n * 4) = vB;
    *(float4*)(dC + ((size_t)b * 1024 + tb) * 64 + n * 4) = vC;
}

// ================= chunked selective scan (packed d/B/C) =================
#define NCHUNK 64
#define CG 4   // 16-step groups per chunk (chunk = 64 steps)

#define DPPADD(p) do { \
    p += __int_as_float(__builtin_amdgcn_update_dpp(0, __float_as_int(p), 0xB1, 0xF, 0xF, true)); \
    p += __int_as_float(__builtin_amdgcn_update_dpp(0, __float_as_int(p), 0x4E, 0xF, 0xF, true)); \
    p += __int_as_float(__builtin_amdgcn_update_dpp(0, __float_as_int(p), 0x124, 0xF, 0xF, true)); \
    p += __int_as_float(__builtin_amdgcn_update_dpp(0, __float_as_int(p), 0x128, 0xF, 0xF, true)); \
} while (0)

// ---- phase 1 ----
template <int REV>
__device__ __forceinline__ void p1_chunk(const float* __restrict__ up, const float* __restrict__ dp,
                                         const float* __restrict__ bp, float A, int c0,
                                         float& hout, float& Pout) {
    float h = 0.f, P = 1.f;
    float4 U0[4], D0[4], B0[4], U1[4], D1[4], B1[4];
#define PHYS1(ci) (REV ? (255 - (ci)) : (ci))
#define LOAD1(U, D, Bb, ci) do { int pb_ = PHYS1(ci) * 16; int tb_ = PHYS1(ci) * 4; \
    _Pragma("unroll") for (int j_ = 0; j_ < 4; ++j_) { \
        U[j_]  = *(const float4*)(up + pb_ + 4 * j_); \
        D[j_]  = *(const float4*)(dp + (size_t)(tb_ + j_) * 16); \
        Bb[j_] = *(const float4*)(bp + (size_t)(tb_ + j_) * 64); \
    } } while (0)
#define STEP1(u_, d_, B_) do { float a_ = __expf((d_) * A); h = fmaf(a_, h, (d_) * (u_) * (B_)); P *= a_; } while (0)
#define COMP1(U, D, Bb) do { \
    if (!REV) { _Pragma("unroll") for (int j_ = 0; j_ < 4; ++j_) { \
        STEP1(U[j_].x, D[j_].x, Bb[j_].x); STEP1(U[j_].y, D[j_].y, Bb[j_].y); \
        STEP1(U[j_].z, D[j_].z, Bb[j_].z); STEP1(U[j_].w, D[j_].w, Bb[j_].w); } } \
    else { _Pragma("unroll") for (int j_ = 3; j_ >= 0; --j_) { \
        STEP1(U[j_].w, D[j_].w, Bb[j_].w); STEP1(U[j_].z, D[j_].z, Bb[j_].z); \
        STEP1(U[j_].y, D[j_].y, Bb[j_].y); STEP1(U[j_].x, D[j_].x, Bb[j_].x); } } } while (0)
    LOAD1(U0, D0, B0, c0);
    for (int it = 0; it < CG; it += 2) {
        LOAD1(U1, D1, B1, c0 + it + 1);
        COMP1(U0, D0, B0);
        if (it + 2 < CG) LOAD1(U0, D0, B0, c0 + it + 2);
        COMP1(U1, D1, B1);
    }
    hout = h; Pout = P;
#undef PHYS1
#undef LOAD1
#undef STEP1
#undef COMP1
}

__global__ __launch_bounds__(64) void scan_p1_kernel(
    const float* __restrict__ xm, const float* __restrict__ us,
    const float* __restrict__ dfpk, const float* __restrict__ bpkf, const float* __restrict__ Alf,
    const float* __restrict__ dbpk, const float* __restrict__ bpkb, const float* __restrict__ Alb,
    const float* __restrict__ dspk, const float* __restrict__ bpks, const float* __restrict__ Als,
    float* __restrict__ hf, float* __restrict__ Pp) {
    int g = blockIdx.x, k = blockIdx.y;
    int lane = threadIdx.x;
    int n = lane & 15, cl = lane >> 4;
    int c0 = k * CG;
    float h, P;
    if (g < 32) {
        int b = g >> 4, cg = g & 15, c = cg * 4 + cl;
        float A = -__expf(Alf[c * 16 + n]);
        p1_chunk<0>(xm + ((size_t)b * 128 + c) * Ln,
                    dfpk + (((size_t)b * 16 + cg) * 1024) * 16 + cl * 4,
                    bpkf + (size_t)b * 65536 + n * 4, A, c0, h, P);
    } else if (g < 64) {
        int g2 = g - 32, b = g2 >> 4, cg = g2 & 15, c = cg * 4 + cl;
        float A = -__expf(Alb[c * 16 + n]);
        p1_chunk<1>(xm + ((size_t)b * 128 + 64 + c) * Ln,
                    dbpk + (((size_t)b * 16 + cg) * 1024) * 16 + cl * 4,
                    bpkb + (size_t)b * 65536 + n * 4, A, c0, h, P);
    } else {
        int g2 = g - 64, b = g2 >> 5, cg = g2 & 31, c = cg * 4 + cl;
        float A = -__expf(Als[c * 16 + n]);
        p1_chunk<0>(us + ((size_t)b * 128 + c) * Ln,
                    dspk + (((size_t)b * 32 + cg) * 1024) * 16 + cl * 4,
                    bpks + (size_t)b * 65536 + n * 4, A, c0, h, P);
    }
    int o = (g * NCHUNK + k) * 64 + lane;
    hf[o] = h; Pp[o] = P;
}

// ---- stitch (streaming, batches of 8) ----
__global__ void scan_stitch_kernel(const float* __restrict__ hf, const float* __restrict__ Pp,
                                   float* __restrict__ hi) {
    int id = blockIdx.x * blockDim.x + threadIdx.x;   // 0..8191
    int g = id >> 6, lane = id & 63;
    float h = 0.f;
    for (int kb = 0; kb < NCHUNK / 8; kb++) {
        float P8[8], H8[8];
#pragma unroll
        for (int j = 0; j < 8; j++) {
            int o = (g * NCHUNK + kb * 8 + j) * 64 + lane;
            P8[j] = Pp[o]; H8[j] = hf[o];
        }
#pragma unroll
        for (int j = 0; j < 8; j++) {
            int o = (g * NCHUNK + kb * 8 + j) * 64 + lane;
            hi[o] = h;
            h = fmaf(P8[j], h, H8[j]);
        }
    }
}

// ---- phase 2 ----
#define STEPP(u_, d_, B_, C_) ({ \
    float dA_ = __expf((d_) * A); \
    h = fmaf(dA_, h, (d_) * (u_) * (B_)); \
    float p_ = h * (C_); \
    DPPADD(p_); \
    fmaf((u_), Dc, p_); })

template <int MODE>  // 0 fwd, 1 rev, 2 sid
__device__ __forceinline__ void p2_chunk(const float* __restrict__ up, const float* __restrict__ dp,
                                         const float* __restrict__ bp, const float* __restrict__ cp,
                                         const int* __restrict__ sp, float* __restrict__ yp,
                                         float A, float Dc, int n, int c0, float h) {
    constexpr bool REV = (MODE == 1);
    constexpr bool SIDM = (MODE == 2);
    float4 U0[4], D0[4], B0[4], C0[4], U1[4], D1[4], B1[4], C1[4];
    int4 I0[4] = {}, I1[4] = {};
#define PHYS(ci) (REV ? (255 - (ci)) : (ci))
#define LOADC(U, D, Bb, Cc, I, ci) do { int pb_ = PHYS(ci) * 16; int tb_ = PHYS(ci) * 4; \
    _Pragma("unroll") for (int j_ = 0; j_ < 4; ++j_) { \
        U[j_]  = *(const float4*)(up + pb_ + 4 * j_); \
        D[j_]  = *(const float4*)(dp + (size_t)(tb_ + j_) * 16); \
        Bb[j_] = *(const float4*)(bp + (size_t)(tb_ + j_) * 64); \
        Cc[j_] = *(const float4*)(cp + (size_t)(tb_ + j_) * 64); \
        if (SIDM) I[j_] = *(const int4*)(sp + pb_ + 4 * j_); \
    } } while (0)
#define COMPC(U, D, Bb, Cc, I, ci) do { int pb_ = PHYS(ci) * 16; \
    if (SIDM) { \
        _Pragma("unroll") for (int j_ = 0; j_ < 4; ++j_) { \
            float y0_ = STEPP(U[j_].x, D[j_].x, Bb[j_].x, Cc[j_].x); if (n == 0) yp[I[j_].x] = y0_; \
            float y1_ = STEPP(U[j_].y, D[j_].y, Bb[j_].y, Cc[j_].y); if (n == 0) yp[I[j_].y] = y1_; \
            float y2_ = STEPP(U[j_].z, D[j_].z, Bb[j_].z, Cc[j_].z); if (n == 0) yp[I[j_].z] = y2_; \
            float y3_ = STEPP(U[j_].w, D[j_].w, Bb[j_].w, Cc[j_].w); if (n == 0) yp[I[j_].w] = y3_; \
        } \
    } else if (!REV) { \
        _Pragma("unroll") for (int j_ = 0; j_ < 4; ++j_) { \
            float4 y4_; \
            y4_.x = STEPP(U[j_].x, D[j_].x, Bb[j_].x, Cc[j_].x); \
            y4_.y = STEPP(U[j_].y, D[j_].y, Bb[j_].y, Cc[j_].y); \
            y4_.z = STEPP(U[j_].z, D[j_].z, Bb[j_].z, Cc[j_].z); \
            y4_.w = STEPP(U[j_].w, D[j_].w, Bb[j_].w, Cc[j_].w); \
            if (n == 0) *(float4*)(yp + pb_ + 4 * j_) = y4_; \
        } \
    } else { \
        _Pragma("unroll") for (int j_ = 3; j_ >= 0; --j_) { \
            float4 y4_; \
            y4_.w = STEPP(U[j_].w, D[j_].w, Bb[j_].w, Cc[j_].w); \
            y4_.z = STEPP(U[j_].z, D[j_].z, Bb[j_].z, Cc[j_].z); \
            y4_.y = STEPP(U[j_].y, D[j_].y, Bb[j_].y, Cc[j_].y); \
            y4_.x = STEPP(U[j_].x, D[j_].x, Bb[j_].x, Cc[j_].x); \
            if (n == 0) *(float4*)(yp + pb_ + 4 * j_) = y4_; \
        } \
    } } while (0)
    LOADC(U0, D0, B0, C0, I0, c0);
    for (int it = 0; it < CG; it += 2) {
        LOADC(U1, D1, B1, C1, I1, c0 + it + 1);
        COMPC(U0, D0, B0, C0, I0, c0 + it);
        if (it + 2 < CG) LOADC(U0, D0, B0, C0, I0, c0 + it + 2);
        COMPC(U1, D1, B1, C1, I1, c0 + it + 1);
    }
#undef PHYS
#undef LOADC
#undef COMPC
}

__global__ __launch_bounds__(64) void scan_p2_kernel(
    const float* __restrict__ xm, const float* __restrict__ us,
    const float* __restrict__ dfpk, const float* __restrict__ bpkf, const float* __restrict__ cpkf,
    const float* __restrict__ Alf, const float* __restrict__ Dfp,
    const float* __restrict__ dbpk, const float* __restrict__ bpkb, const float* __restrict__ cpkb,
    const float* __restrict__ Alb, const float* __restrict__ Dbp,
    const float* __restrict__ dspk, const float* __restrict__ bpks, const float* __restrict__ cpks,
    const float* __restrict__ Als, const float* __restrict__ Dsp,
    const int* __restrict__ sidx, const float* __restrict__ hi,
    float* __restrict__ yf, float* __restrict__ yb, float* __restrict__ ys) {
    int g = blockIdx.x, k = blockIdx.y;
    int lane = threadIdx.x;
    int n = lane & 15, cl = lane >> 4;
    int c0 = k * CG;
    float h0 = hi[(g * NCHUNK + k) * 64 + lane];
    if (g < 32) {
        int b = g >> 4, cg = g & 15, c = cg * 4 + cl;
        float A = -__expf(Alf[c * 16 + n]);
        p2_chunk<0>(xm + ((size_t)b * 128 + c) * Ln,
                    dfpk + (((size_t)b * 16 + cg) * 1024) * 16 + cl * 4,
                    bpkf + (size_t)b * 65536 + n * 4, cpkf + (size_t)b * 65536 + n * 4,
                    nullptr, yf + ((size_t)b * 64 + c) * Ln, A, Dfp[c], n, c0, h0);
    } else if (g < 64) {
        int g2 = g - 32, b = g2 >> 4, cg = g2 & 15, c = cg * 4 + cl;
        float A = -__expf(Alb[c * 16 + n]);
        p2_chunk<1>(xm + ((size_t)b * 128 + 64 + c) * Ln,
                    dbpk + (((size_t)b * 16 + cg) * 1024) * 16 + cl * 4,
                    bpkb + (size_t)b * 65536 + n * 4, cpkb + (size_t)b * 65536 + n * 4,
                    nullptr, yb + ((size_t)b * 64 + c) * Ln, A, Dbp[c], n, c0, h0);
    } else {
        int g2 = g - 64, b = g2 >> 5, cg = g2 & 31, c = cg * 4 + cl;
        float A = -__expf(Als[c * 16 + n]);
        p2_chunk<2>(us + ((size_t)b * 128 + c) * Ln,
                    dspk + (((size_t)b * 32 + cg) * 1024) * 16 + cl * 4,
                    bpks + (size_t)b * 65536 + n * 4, cpks + (size_t)b * 65536 + n * 4,
                    sidx + b * Ln, ys + ((size_t)b * 128 + c) * Ln, A, Dsp[c], n, c0, h0);
    }
}

// ---------------- fused = g*sid + (1-g)*cat (float4, in-place-safe) ----------------
__global__ void fuse_kernel(const float4* __restrict__ gate, const float4* __restrict__ ysb,
                            const float4* __restrict__ cat, float4* __restrict__ out, int n4) {
    int i = blockIdx.x * blockDim.x + threadIdx.x;
    if (i < n4) {
        float4 g = gate[i], s = ysb[i], c = cat[i], o;
        o.x = g.x * s.x + (1.f - g.x) * c.x;
        o.y = g.y * s.y + (1.f - g.y) * c.y;
        o.z = g.z * s.z + (1.f - g.z) * c.z;
        o.w = g.w * s.w + (1.f - g.w) * c.w;
        out[i] = o;
    }
}

extern "C" void kernel_launch(void* const* d_in, const int* in_sizes, int n_in,
                              void* d_out, int out_size, void* d_ws, size_t ws_size,
                              hipStream_t stream) {
    const float* x    = (const float*)d_in[0];
    const float* mfg  = (const float*)d_in[1];
    const float* mbg  = (const float*)d_in[2];
    const float* muc  = (const float*)d_in[3];
    const float* niw  = (const float*)d_in[4];
    const float* nib  = (const float*)d_in[5];
    const float* inw  = (const float*)d_in[6];
    const float* inb  = (const float*)d_in[7];
    const float* lmw  = (const float*)d_in[8];
    const float* lmb  = (const float*)d_in[9];
    const float* cmw  = (const float*)d_in[10];
    const float* cmb  = (const float*)d_in[11];
    const float* crw  = (const float*)d_in[12];
    const float* crb  = (const float*)d_in[13];
    const float* xwf  = (const float*)d_in[14];
    const float* xbf  = (const float*)d_in[15];
    const float* dtwf = (const float*)d_in[16];
    const float* dtbf = (const float*)d_in[17];
    const float* Alf  = (const float*)d_in[18];
    const float* Dfp  = (const float*)d_in[19];
    const float* xwb  = (const float*)d_in[20];
    const float* xbb  = (const float*)d_in[21];
    const float* dtwb = (const float*)d_in[22];
    const float* dtbb = (const float*)d_in[23];
    const float* Alb  = (const float*)d_in[24];
    const float* Dbp  = (const float*)d_in[25];
    const float* xws  = (const float*)d_in[26];
    const float* xbs  = (const float*)d_in[27];
    const float* dtws = (const float*)d_in[28];
    const float* dtbs = (const float*)d_in[29];
    const float* Als  = (const float*)d_in[30];
    const float* Dsp  = (const float*)d_in[31];
    const float* lcw  = (const float*)d_in[32];
    const float* lcb  = (const float*)d_in[33];
    const float* g0w  = (const float*)d_in[34];
    const float* g0b  = (const float*)d_in[35];
    const float* bng  = (const float*)d_in[36];
    const float* bnbe = (const float*)d_in[37];
    const float* bnm  = (const float*)d_in[38];
    const float* bnv  = (const float*)d_in[39];
    const float* g1w  = (const float*)d_in[40];
    const float* g1b  = (const float*)d_in[41];
    const float* outw = (const float*)d_in[42];
    const float* outb = (const float*)d_in[43];
    const float* now  = (const float*)d_in[44];
    const float* nob  = (const float*)d_in[45];

    float* W = (float*)d_ws;
    // ---- region plan (floats), total 10,493,952 (~42.0 MB) ----
    const size_t R_XP = 0;          // 2M: XP(3-5); xproj partials(7-8); s partials(11-12); HF/PP/HI(14); g0 p2/p3(16); out p2/p3(19)
    const size_t R_A  = 2097152;    // 2M: in_proj P0(2-3); BC packs(13-14)+YF/YB(14-15); g0 p0/p1(16); g1 p0/p1(17); out p0/p1(19)
    const size_t R_B  = 4194304;    // 2M: in_proj P1(2-3); DBLF/B/S(8-13)+DSPK(13-14); YS(14-18)
    const size_t R_N  = 6291456;    // 1M: XNORM(1-2); XMNORM(4-5); DFPK/DBPK(9-14); CATLN(15-18)=FUSED(18-19)
    const size_t R_XM = 7340032;    // 1M: xm(5-14); GBUF(16-17)
    const size_t R_XR = 8388608;    // 1M: xr(5-19)
    const size_t R_US = 9437184;    // 1M: us(10-14); GATE(17-18); OUTB(19-20)
    const size_t R_IDX= 10485760;   // 8192 ints
    // aliases
    const size_t XNORM = R_N, XP = R_XP, XMN = R_N;
    const size_t XPJ0 = R_XP, XPJ1 = R_XP + 294912;          // f partials; b at +589824 via pbrOff
    const size_t DBLF = R_B, DBLB = R_B + 294912, DBLS = R_B + 589824;
    const size_t DFPK = R_N, DBPK = R_N + 524288, DSPK = R_B + 1048576;
    const size_t BPKF = R_A, CPKF = R_A + 131072, BPKB = R_A + 262144,
                 CPKB = R_A + 393216, BPKS = R_A + 524288, CPKS = R_A + 655360;
    const size_t XS0 = R_XP, XS1 = R_XP + 327680, XS2 = R_XP + 655360, XS3 = R_XP + 983040;
    const size_t HF = R_XP, PP = R_XP + 524288, HI = R_XP + 1048576;
    const size_t YF = R_A + 786432, YB = R_A + 1310720, YS = R_B;
    const size_t CATLN = R_N, FUSED = R_N;
    const size_t GBUF = R_XM, GATE = R_US, OUTB = R_US;

    int* idxp = (int*)(W + R_IDX);
    dim3 blk(256);
    const float* nil = nullptr;

    // 1. LN(x) -> XNORM
    ln_kernel<<<dim3(64, 2), blk, 0, stream>>>(x, nullptr, 128, niw, nib, W + XNORM, 128);
    // 2. in_proj conv, KS=2: XNORM -> P0@R_A, P1@R_B
    conv1x1_kernel<<<dim3(4, 128, 2), blk, 0, stream>>>(
        W + XNORM, nullptr, 128, 128, 0, 0, 256, 256, inw, nullptr, inb, nullptr, 0,
        nil, nil, nil, nil, 0, nullptr, 2, 64, W + R_A, W + R_B, nullptr, nullptr, 0);
    // 3. combine -> XP
    combine_kernel<<<2048, blk, 0, stream>>>(
        W + R_A, W + R_B, nullptr, nullptr, 2, inb, nil, nil, nil, nil, 0, W + XP, 256, 524288);
    // 4. LN(xp[:,0:128]) -> XMNORM
    ln_kernel<<<dim3(64, 2), blk, 0, stream>>>(W + XP, nullptr, 256, lmw, lmb, W + XMN, 128);
    // 5. dwconv -> XM, XR
    dwconv_kernel<<<dim3(16, 256, 2), blk, 0, stream>>>(
        W + XMN, W + XP, cmw, cmb, crw, crb, W + R_XM, W + R_XR);
    // 6. sort
    sort_kernel<<<2, 1024, 0, stream>>>(mfg, mbg, muc, idxp);
    // 7. xproj f+b fused conv, KS=2
    conv1x1_kernel<<<dim3(4, 18, 4), blk, 0, stream>>>(
        W + R_XM, nullptr, 64, 128, 0, 0, 36, 36, xwf, xwb, xbf, xbb, (long)64 * Ln,
        nil, nil, nil, nil, 0, nullptr, 2, 32, W + XPJ0, W + XPJ1, nullptr, nullptr, (long)589824);
    // 8. combines -> DBLF, DBLB
    combine_kernel<<<288, blk, 0, stream>>>(
        W + XPJ0, W + XPJ1, nullptr, nullptr, 2, xbf, nil, nil, nil, nil, 0, W + DBLF, 36, 73728);
    combine_kernel<<<288, blk, 0, stream>>>(
        W + XPJ0 + 589824, W + XPJ1 + 589824, nullptr, nullptr, 2, xbb,
        nil, nil, nil, nil, 0, W + DBLB, 36, 73728);
    // 9. delta f, b (packed out)
    delta_kernel<4, 16><<<dim3(4, 8, 2), blk, 0, stream>>>(W + DBLF, 36, dtwf, dtbf, W + DFPK);
    delta_kernel<4, 16><<<dim3(4, 8, 2), blk, 0, stream>>>(W + DBLB, 36, dtwb, dtbb, W + DBPK);
    // 10. gather -> US
    gather_kernel<<<dim3(16, 128, 2), blk, 0, stream>>>(W + R_XM, idxp, W + R_US);
    // 11. xproj_s conv, KS=4
    conv1x1_kernel<<<dim3(4, 40, 2), blk, 0, stream>>>(
        W + R_US, nullptr, 128, 128, 0, 0, 40, 40, xws, nullptr, xbs, nullptr, 0,
        nil, nil, nil, nil, 0, nullptr, 4, 32, W + XS0, W + XS1, W + XS2, W + XS3, 0);
    // 12. combine -> DBLS
    combine_kernel<<<320, blk, 0, stream>>>(
        W + XS0, W + XS1, W + XS2, W + XS3, 4, xbs, nil, nil, nil, nil, 0, W + DBLS, 40, 81920);
    // 13. pack B/C (all 3 branches) + delta s (packed out)
    pack_bc_kernel<<<dim3(64, 2, 3), blk, 0, stream>>>(
        W + DBLF, W + DBLB, W + DBLS,
        W + BPKF, W + CPKF, W + BPKB, W + CPKB, W + BPKS, W + CPKS);
    delta_kernel<8, 32><<<dim3(4, 16, 2), blk, 0, stream>>>(W + DBLS, 40, dtws, dtbs, W + DSPK);
    // 14. chunked scan
    scan_p1_kernel<<<dim3(128, NCHUNK), 64, 0, stream>>>(
        W + R_XM, W + R_US,
        W + DFPK, W + BPKF, Alf,
        W + DBPK, W + BPKB, Alb,
        W + DSPK, W + BPKS, Als,
        W + HF, W + PP);
    scan_stitch_kernel<<<32, 256, 0, stream>>>(W + HF, W + PP, W + HI);
    scan_p2_kernel<<<dim3(128, NCHUNK), 64, 0, stream>>>(
        W + R_XM, W + R_US,
        W + DFPK, W + BPKF, W + CPKF, Alf, Dfp,
        W + DBPK, W + BPKB, W + CPKB, Alb, Dbp,
        W + DSPK, W + BPKS, W + CPKS, Als, Dsp,
        idxp, W + HI, W + YF, W + YB, W + YS);
    // 15. LN(concat(yf,yb)) -> CATLN
    ln_kernel<<<dim3(64, 2), blk, 0, stream>>>(W + YF, W + YB, 64, lcw, lcb, W + CATLN, 128);
    // 16. g0 conv, KS=4 + combine(BN+ReLU) -> GBUF
    conv1x1_kernel<<<dim3(4, 128, 2), blk, 0, stream>>>(
        W + CATLN, W + YS, 128, 128, 128, 128, 128, 128, g0w, nullptr, g0b, nullptr, 0,
        nil, nil, nil, nil, 0, nullptr, 4, 64,
        W + R_A, W + R_A + 1048576, W + R_XP, W + R_XP + 1048576, 0);
    combine_kernel<<<1024, blk, 0, stream>>>(
        W + R_A, W + R_A + 1048576, W + R_XP, W + R_XP + 1048576, 4, g0b,
        bng, bnbe, bnm, bnv, 1, W + GBUF, 128, 262144);
    // 17. g1 conv, KS=2 + combine(sigmoid) -> GATE
    conv1x1_kernel<<<dim3(4, 64, 2), blk, 0, stream>>>(
        W + GBUF, nullptr, 128, 128, 0, 0, 128, 128, g1w, nullptr, g1b, nullptr, 0,
        nil, nil, nil, nil, 0, nullptr, 2, 64, W + R_A, W + R_A + 1048576, nullptr, nullptr, 0);
    combine_kernel<<<1024, blk, 0, stream>>>(
        W + R_A, W + R_A + 1048576, nullptr, nullptr, 2, g1b,
        nil, nil, nil, nil, 2, W + GATE, 128, 262144);
    // 18. fuse (in-place over CATLN -> FUSED)
    fuse_kernel<<<1024, blk, 0, stream>>>(
        (const float4*)(W + GATE), (const float4*)(W + YS), (const float4*)(W + CATLN),
        (float4*)(W + FUSED), Bn * Cn_ * Ln / 4);
    // 19. out conv, KS=4 + combine -> OUTB
    conv1x1_kernel<<<dim3(4, 128, 2), blk, 0, stream>>>(
        W + FUSED, W + R_XR, 128, 128, 128, 128, 128, 128, outw, nullptr, outb, nullptr, 0,
        nil, nil, nil, nil, 0, nullptr, 4, 64,
        W + R_A, W + R_A + 1048576, W + R_XP, W + R_XP + 1048576, 0);
    combine_kernel<<<1024, blk, 0, stream>>>(
        W + R_A, W + R_A + 1048576, W + R_XP, W + R_XP + 1048576, 4, outb,
        nil, nil, nil, nil, 0, W + OUTB, 128, 262144);
    // 20. final LN -> d_out
    ln_kernel<<<dim3(64, 2), blk, 0, stream>>>(W + OUTB, nullptr, 128, now, nob,
                                               (float*)d_out, 128);
}

// Round 7
// 232.900 us; speedup vs baseline: 7.3698x; 1.3157x over previous
//
#include <hip/hip_runtime.h>
#include <math.h>

#define Bn 2
#define Cn_ 128
#define Hn 64
#define Wn 64
#define Ln 4096
#define Nn 16

static constexpr float EPS_LN_C = 1e-6f;
static constexpr float EPS_BN_C = 1e-5f;

__device__ __forceinline__ float softplusf_(float x) {
    return fmaxf(x, 0.f) + log1pf(__expf(-fabsf(x)));
}
__device__ __forceinline__ float sigmoidf_(float x) {
    return 1.f / (1.f + __expf(-x));
}

// ---------------- LayerNorm: stats + normalized output ----------------
__global__ __launch_bounds__(256) void ln_kernel(
    const float* __restrict__ inA, const float* __restrict__ inB, int csA,
    const float* __restrict__ lw, const float* __restrict__ lb,
    float* __restrict__ out, int csOut) {
    int b = blockIdx.y;
    int lane = threadIdx.x & 63;
    int q = threadIdx.x >> 6;
    int px = blockIdx.x * 64 + lane;
    __shared__ float s_s[4][64], s_s2[4][64];
    __shared__ float s_m[64], s_r[64];
    float s = 0.f, s2 = 0.f;
#pragma unroll
    for (int i = 0; i < 32; i++) {
        int c = q * 32 + i;
        const float* ptr = (inB && c >= 64) ? (inB + ((size_t)b * 64 + (c - 64)) * Ln)
                                            : (inA + ((size_t)b * csA + c) * Ln);
        float v = ptr[px];
        s += v; s2 += v * v;
    }
    s_s[q][lane] = s; s_s2[q][lane] = s2;
    __syncthreads();
    if (q == 0) {
        float ts = s_s[0][lane] + s_s[1][lane] + s_s[2][lane] + s_s[3][lane];
        float t2 = s_s2[0][lane] + s_s2[1][lane] + s_s2[2][lane] + s_s2[3][lane];
        float m = ts / 128.f;
        float var = fmaxf(t2 / 128.f - m * m, 0.f);
        s_m[lane] = m; s_r[lane] = 1.f / sqrtf(var + EPS_LN_C);
    }
    __syncthreads();
    float m = s_m[lane], r = s_r[lane];
#pragma unroll
    for (int i = 0; i < 32; i++) {
        int c = q * 32 + i;
        const float* ptr = (inB && c >= 64) ? (inB + ((size_t)b * 64 + (c - 64)) * Ln)
                                            : (inA + ((size_t)b * csA + c) * Ln);
        float v = ptr[px];
        out[((size_t)b * csOut + c) * Ln + px] = (v - m) * r * lw[c] + lb[c];
    }
}

// ---------------- 1x1 conv, split-K, 4 outputs/block, double-buffered ----------------
__global__ __launch_bounds__(256) void conv1x1_kernel(
    const float* __restrict__ inA, const float* __restrict__ inB,
    int cinA, int csA, int cinB, int csB, int cout, int csOut,
    const float* __restrict__ w, const float* __restrict__ wB,
    const float* __restrict__ bias, const float* __restrict__ biasB, long inAoffB,
    const float* __restrict__ bng, const float* __restrict__ bnbe,
    const float* __restrict__ bnm, const float* __restrict__ bnv,
    int epilogue, float* __restrict__ out,
    int ksn, int kchunk,
    float* __restrict__ p0, float* __restrict__ p1,
    float* __restrict__ p2, float* __restrict__ p3, long pbrOff) {
    int z = blockIdx.z;
    int br = 0, b = z;
    if (z >= Bn) { br = 1; b = z - Bn; }
    int ks = 0, og = blockIdx.y;
    if (ksn > 1) { ks = blockIdx.y % ksn; og = blockIdx.y / ksn; }
    int o0 = og * 4;
    int k0 = ks * kchunk;
    int CL = kchunk;
    int cin = cinA + cinB;
    const float* wsel = br ? wB : w;
    const float* bsel = br ? biasB : bias;
    const float* wrow[4];
#pragma unroll
    for (int j = 0; j < 4; j++)
        wrow[j] = wsel + (size_t)min(o0 + j, cout - 1) * cin + k0;
    int l = (blockIdx.x * 256 + threadIdx.x) * 4;
    const float* src;
    if (k0 < cinA) src = inA + (br ? inAoffB : 0) + ((size_t)b * csA + k0) * Ln + l;
    else           src = inB + ((size_t)b * csB + (k0 - cinA)) * Ln + l;
    float4 acc[4];
#pragma unroll
    for (int j = 0; j < 4; j++) {
        float bj = (ksn > 1) ? 0.f : bsel[min(o0 + j, cout - 1)];
        acc[j] = make_float4(bj, bj, bj, bj);
    }
    float4 v0[4], v1[4];
#define CLD(V, c0_) do { _Pragma("unroll") for (int j_ = 0; j_ < 4; ++j_) \
        V[j_] = *(const float4*)(src + (size_t)((c0_) + j_) * Ln); } while (0)
#define CFM(V, c0_) do { _Pragma("unroll") for (int j_ = 0; j_ < 4; ++j_) { \
        _Pragma("unroll") for (int o_ = 0; o_ < 4; ++o_) { \
            float wv_ = wrow[o_][(c0_) + j_]; \
            acc[o_].x = fmaf(wv_, V[j_].x, acc[o_].x); \
            acc[o_].y = fmaf(wv_, V[j_].y, acc[o_].y); \
            acc[o_].z = fmaf(wv_, V[j_].z, acc[o_].z); \
            acc[o_].w = fmaf(wv_, V[j_].w, acc[o_].w); } } } while (0)
    CLD(v0, 0);
    for (int cc = 0; cc < CL; cc += 8) {
        CLD(v1, cc + 4);
        CFM(v0, cc);
        if (cc + 8 < CL) CLD(v0, cc + 8);
        CFM(v1, cc + 4);
    }
#undef CLD
#undef CFM
    if (ksn > 1) {
        float* pp = (ks == 0) ? p0 : (ks == 1) ? p1 : (ks == 2) ? p2 : p3;
        if (br) pp += pbrOff;
#pragma unroll
        for (int j = 0; j < 4; j++) {
            int o = o0 + j;
            if (o >= cout) continue;
            *(float4*)(pp + ((size_t)b * cout + o) * Ln + l) = acc[j];
        }
    } else {
#pragma unroll
        for (int j = 0; j < 4; j++) {
            int o = o0 + j;
            if (o >= cout) continue;
            float4 v = acc[j];
            if (epilogue == 1) {
                float sc = (1.f / sqrtf(bnv[o] + EPS_BN_C)) * bng[o];
                float sh = bnbe[o] - bnm[o] * sc;
                v.x = fmaxf(fmaf(v.x, sc, sh), 0.f);
                v.y = fmaxf(fmaf(v.y, sc, sh), 0.f);
                v.z = fmaxf(fmaf(v.z, sc, sh), 0.f);
                v.w = fmaxf(fmaf(v.w, sc, sh), 0.f);
            } else if (epilogue == 2) {
                v.x = sigmoidf_(v.x); v.y = sigmoidf_(v.y);
                v.z = sigmoidf_(v.z); v.w = sigmoidf_(v.w);
            }
            *(float4*)(out + ((size_t)b * csOut + o) * Ln + l) = v;
        }
    }
}

// ---------------- combine: sum partials + bias + epilogue ----------------
__global__ __launch_bounds__(256) void combine_kernel(
    const float* __restrict__ p0, const float* __restrict__ p1,
    const float* __restrict__ p2, const float* __restrict__ p3, int ksn,
    const float* __restrict__ bias,
    const float* __restrict__ bng, const float* __restrict__ bnbe,
    const float* __restrict__ bnm, const float* __restrict__ bnv,
    int epilogue, float* __restrict__ out, int cout, int n4) {
    int i = blockIdx.x * 256 + threadIdx.x;
    if (i >= n4) return;
    size_t e = (size_t)i * 4;
    int o = (int)((e / Ln) % cout);
    float4 a = *(const float4*)(p0 + e);
    if (ksn > 1) { float4 t = *(const float4*)(p1 + e); a.x += t.x; a.y += t.y; a.z += t.z; a.w += t.w; }
    if (ksn > 2) { float4 t = *(const float4*)(p2 + e); a.x += t.x; a.y += t.y; a.z += t.z; a.w += t.w; }
    if (ksn > 3) { float4 t = *(const float4*)(p3 + e); a.x += t.x; a.y += t.y; a.z += t.z; a.w += t.w; }
    float bj = bias[o];
    a.x += bj; a.y += bj; a.z += bj; a.w += bj;
    if (epilogue == 1) {
        float sc = (1.f / sqrtf(bnv[o] + EPS_BN_C)) * bng[o];
        float sh = bnbe[o] - bnm[o] * sc;
        a.x = fmaxf(fmaf(a.x, sc, sh), 0.f);
        a.y = fmaxf(fmaf(a.y, sc, sh), 0.f);
        a.z = fmaxf(fmaf(a.z, sc, sh), 0.f);
        a.w = fmaxf(fmaf(a.w, sc, sh), 0.f);
    } else if (epilogue == 2) {
        a.x = sigmoidf_(a.x); a.y = sigmoidf_(a.y);
        a.z = sigmoidf_(a.z); a.w = sigmoidf_(a.w);
    }
    *(float4*)(out + e) = a;
}

// ---------------- depthwise 3x3 SAME + bias + SiLU ----------------
__global__ void dwconv_kernel(const float* __restrict__ xmn, const float* __restrict__ xp,
                              const float* __restrict__ wm, const float* __restrict__ bm,
                              const float* __restrict__ wr, const float* __restrict__ brr,
                              float* __restrict__ xm, float* __restrict__ xr) {
    int b = blockIdx.z;
    int c2 = blockIdx.y;
    int l = blockIdx.x * blockDim.x + threadIdx.x;
    int h = l >> 6, w = l & 63;
    bool mamba = (c2 < 128);
    const float* in = mamba ? (xmn + ((size_t)b * 128 + c2) * Ln)
                            : (xp + ((size_t)b * 256 + c2) * Ln);
    const float* wt = mamba ? (wm + c2 * 9) : (wr + (c2 - 128) * 9);
    float acc = mamba ? bm[c2] : brr[c2 - 128];
#pragma unroll
    for (int dh = -1; dh <= 1; dh++) {
#pragma unroll
        for (int dw = -1; dw <= 1; dw++) {
            int hh = h + dh, ww = w + dw;
            if (hh < 0 || hh > 63 || ww < 0 || ww > 63) continue;
            acc = fmaf(in[hh * 64 + ww], wt[(dh + 1) * 3 + (dw + 1)], acc);
        }
    }
    float o = acc * sigmoidf_(acc);
    if (mamba) xm[((size_t)b * 128 + c2) * Ln + l] = o;
    else       xr[((size_t)b * 128 + (c2 - 128)) * Ln + l] = o;
}

// ---------------- counting sort (4 classes) per batch; within class, index DESCENDING ----------------
__global__ __launch_bounds__(1024) void sort_kernel(const float* __restrict__ mfg,
                                                    const float* __restrict__ mbg,
                                                    const float* __restrict__ muc,
                                                    int* __restrict__ sidx) {
    int b = blockIdx.x;
    int t = threadIdx.x;
    const int PT = 4;
    __shared__ unsigned int wsum0[16], wsum1[16];
    __shared__ unsigned int tot01s, tot23s;

    int cls[PT];
    unsigned int c01 = 0, c23 = 0;
#pragma unroll
    for (int q = 0; q < PT; q++) {
        int j = t * PT + q;
        int i = Ln - 1 - j;
        float f = mfg[b * Ln + i], g = mbg[b * Ln + i], u = muc[b * Ln + i];
        int k = (f > 0.5f) ? 3 : (g > 0.5f) ? 2 : (u > 0.5f) ? 1 : 0;
        cls[q] = k;
        if (k == 0) c01 += 1u;
        else if (k == 1) c01 += (1u << 16);
        else if (k == 2) c23 += 1u;
        else c23 += (1u << 16);
    }
    unsigned int s01 = c01, s23 = c23;
    int lane = t & 63;
    for (int d = 1; d < 64; d <<= 1) {
        unsigned int o01 = __shfl_up(s01, (unsigned)d, 64);
        unsigned int o23 = __shfl_up(s23, (unsigned)d, 64);
        if (lane >= d) { s01 += o01; s23 += o23; }
    }
    int wid = t >> 6;
    if (lane == 63) { wsum0[wid] = s01; wsum1[wid] = s23; }
    __syncthreads();
    if (t == 0) {
        unsigned int a0 = 0, a1 = 0;
        for (int k2 = 0; k2 < 16; k2++) {
            unsigned int v0 = wsum0[k2], v1 = wsum1[k2];
            wsum0[k2] = a0; wsum1[k2] = a1;
            a0 += v0; a1 += v1;
        }
        tot01s = a0; tot23s = a1;
    }
    __syncthreads();
    unsigned int ex01 = s01 - c01 + wsum0[wid];
    unsigned int ex23 = s23 - c23 + wsum1[wid];
    unsigned int cnt1 = tot01s >> 16;
    unsigned int cnt2 = tot23s & 0xffffu, cnt3 = tot23s >> 16;
    unsigned int off3 = 0, off2 = cnt3, off1 = cnt3 + cnt2, off0 = cnt3 + cnt2 + cnt1;
    unsigned int run0 = ex01 & 0xffffu, run1 = ex01 >> 16;
    unsigned int run2 = ex23 & 0xffffu, run3 = ex23 >> 16;
#pragma unroll
    for (int q = 0; q < PT; q++) {
        int j = t * PT + q;
        int i = Ln - 1 - j;
        int k = cls[q];
        unsigned int pos;
        if (k == 0) pos = off0 + run0++;
        else if (k == 1) pos = off1 + run1++;
        else if (k == 2) pos = off2 + run2++;
        else pos = off3 + run3++;
        sidx[b * Ln + pos] = i;
    }
}

// ---------------- gather ----------------
__global__ __launch_bounds__(256) void gather_kernel(const float* __restrict__ xm,
                                                     const int* __restrict__ sidx,
                                                     float* __restrict__ us) {
    int b = blockIdx.z;
    int c = blockIdx.y;
    int t = blockIdx.x * 256 + threadIdx.x;
    int pix = sidx[b * Ln + t];
    us[((size_t)b * 128 + c) * Ln + t] = xm[((size_t)b * 128 + c) * Ln + pix];
}

// ---------------- delta -> packed layout, COALESCED writes ----------------
// dpk[b][cq][tq][(c&3)*4 + (t&3)]; thread = tq_local*4 + clow so consecutive
// lanes write byte-consecutive float4s. dbl reads broadcast across the 4 clow lanes.
template <int R, int NQ>
__global__ __launch_bounds__(256) void delta_pack_kernel(
    const float* __restrict__ dbl, int nout,
    const float* __restrict__ dtw, const float* __restrict__ dtb,
    float* __restrict__ dpk) {
    int b = blockIdx.z;
    int cq = blockIdx.y;
    int tq = blockIdx.x * 64 + (threadIdx.x >> 2);
    int clow = threadIdx.x & 3;
    int c = cq * 4 + clow;
    int t0 = tq * 4;
    float4 a[R];
#pragma unroll
    for (int r = 0; r < R; r++) a[r] = *(const float4*)(dbl + ((size_t)b * nout + r) * Ln + t0);
    float bj = dtb[c];
    float4 acc = make_float4(bj, bj, bj, bj);
#pragma unroll
    for (int r = 0; r < R; r++) {
        float wv = dtw[c * R + r];
        acc.x = fmaf(wv, a[r].x, acc.x);
        acc.y = fmaf(wv, a[r].y, acc.y);
        acc.z = fmaf(wv, a[r].z, acc.z);
        acc.w = fmaf(wv, a[r].w, acc.w);
    }
    float4 o;
    o.x = softplusf_(acc.x); o.y = softplusf_(acc.y);
    o.z = softplusf_(acc.z); o.w = softplusf_(acc.w);
    *(float4*)(dpk + (((size_t)b * NQ + cq) * 1024 + tq) * 16 + clow * 4) = o;
}

// ---------------- pack B/C: bpk[b][t/4][n*4+(t&3)] ----------------
__global__ __launch_bounds__(256) void pack_bc_kernel(
    const float* __restrict__ dblf, const float* __restrict__ dblb, const float* __restrict__ dbls,
    float* __restrict__ bf, float* __restrict__ cf,
    float* __restrict__ bb2, float* __restrict__ cb2,
    float* __restrict__ bs, float* __restrict__ cs) {
    int br = blockIdx.z;
    int b = blockIdx.y;
    int idx = blockIdx.x * 256 + threadIdx.x;   // 0..16383
    int tb = idx >> 4, n = idx & 15;
    const float* src; float* dB; float* dC; int RT, rB, rC;
    if (br == 0)      { src = dblf; dB = bf;  dC = cf;  RT = 36; rB = 4; rC = 20; }
    else if (br == 1) { src = dblb; dB = bb2; dC = cb2; RT = 36; rB = 4; rC = 20; }
    else              { src = dbls; dB = bs;  dC = cs;  RT = 40; rB = 8; rC = 24; }
    float4 vB = *(const float4*)(src + ((size_t)b * RT + rB + n) * Ln + tb * 4);
    float4 vC = *(const float4*)(src + ((size_t)b * RT + rC + n) * Ln + tb * 4);
    *(float4*)(dB + ((size_t)b * 1024 + tb) * 64 + n * 4) = vB;
    *(float4*)(dC + ((size_t)b * 1024 + tb) * 64 + n * 4) = vC;
}

// ================= chunked selective scan (packed d/B/C), 4 chunk-waves/block =================
#define NCHUNK 64
#define CG 4   // 16-step groups per chunk (chunk = 64 steps)

#define DPPADD(p) do { \
    p += __int_as_float(__builtin_amdgcn_update_dpp(0, __float_as_int(p), 0xB1, 0xF, 0xF, true)); \
    p += __int_as_float(__builtin_amdgcn_update_dpp(0, __float_as_int(p), 0x4E, 0xF, 0xF, true)); \
    p += __int_as_float(__builtin_amdgcn_update_dpp(0, __float_as_int(p), 0x124, 0xF, 0xF, true)); \
    p += __int_as_float(__builtin_amdgcn_update_dpp(0, __float_as_int(p), 0x128, 0xF, 0xF, true)); \
} while (0)

// ---- phase 1 ----
template <int REV>
__device__ __forceinline__ void p1_chunk(const float* __restrict__ up, const float* __restrict__ dp,
                                         const float* __restrict__ bp, float A, int c0,
                                         float& hout, float& Pout) {
    float h = 0.f, P = 1.f;
    float4 U0[4], D0[4], B0[4], U1[4], D1[4], B1[4];
#define PHYS1(ci) (REV ? (255 - (ci)) : (ci))
#define LOAD1(U, D, Bb, ci) do { int pb_ = PHYS1(ci) * 16; int tb_ = PHYS1(ci) * 4; \
    _Pragma("unroll") for (int j_ = 0; j_ < 4; ++j_) { \
        U[j_]  = *(const float4*)(up + pb_ + 4 * j_); \
        D[j_]  = *(const float4*)(dp + (size_t)(tb_ + j_) * 16); \
        Bb[j_] = *(const float4*)(bp + (size_t)(tb_ + j_) * 64); \
    } } while (0)
#define STEP1(u_, d_, B_) do { float a_ = __expf((d_) * A); h = fmaf(a_, h, (d_) * (u_) * (B_)); P *= a_; } while (0)
#define COMP1(U, D, Bb) do { \
    if (!REV) { _Pragma("unroll") for (int j_ = 0; j_ < 4; ++j_) { \
        STEP1(U[j_].x, D[j_].x, Bb[j_].x); STEP1(U[j_].y, D[j_].y, Bb[j_].y); \
        STEP1(U[j_].z, D[j_].z, Bb[j_].z); STEP1(U[j_].w, D[j_].w, Bb[j_].w); } } \
    else { _Pragma("unroll") for (int j_ = 3; j_ >= 0; --j_) { \
        STEP1(U[j_].w, D[j_].w, Bb[j_].w); STEP1(U[j_].z, D[j_].z, Bb[j_].z); \
        STEP1(U[j_].y, D[j_].y, Bb[j_].y); STEP1(U[j_].x, D[j_].x, Bb[j_].x); } } } while (0)
    LOAD1(U0, D0, B0, c0);
    for (int it = 0; it < CG; it += 2) {
        LOAD1(U1, D1, B1, c0 + it + 1);
        COMP1(U0, D0, B0);
        if (it + 2 < CG) LOAD1(U0, D0, B0, c0 + it + 2);
        COMP1(U1, D1, B1);
    }
    hout = h; Pout = P;
#undef PHYS1
#undef LOAD1
#undef STEP1
#undef COMP1
}

__global__ __launch_bounds__(256) void scan_p1_kernel(
    const float* __restrict__ xm, const float* __restrict__ us,
    const float* __restrict__ dfpk, const float* __restrict__ bpkf, const float* __restrict__ Alf,
    const float* __restrict__ dbpk, const float* __restrict__ bpkb, const float* __restrict__ Alb,
    const float* __restrict__ dspk, const float* __restrict__ bpks, const float* __restrict__ Als,
    float* __restrict__ hf, float* __restrict__ Pp) {
    int g = blockIdx.x * 4 + (threadIdx.x >> 6), k = blockIdx.y;
    int lane = threadIdx.x & 63;
    int n = lane & 15, cl = lane >> 4;
    int c0 = k * CG;
    float h, P;
    if (g < 32) {
        int b = g >> 4, cg = g & 15, c = cg * 4 + cl;
        float A = -__expf(Alf[c * 16 + n]);
        p1_chunk<0>(xm + ((size_t)b * 128 + c) * Ln,
                    dfpk + (((size_t)b * 16 + cg) * 1024) * 16 + cl * 4,
                    bpkf + (size_t)b * 65536 + n * 4, A, c0, h, P);
    } else if (g < 64) {
        int g2 = g - 32, b = g2 >> 4, cg = g2 & 15, c = cg * 4 + cl;
        float A = -__expf(Alb[c * 16 + n]);
        p1_chunk<1>(xm + ((size_t)b * 128 + 64 + c) * Ln,
                    dbpk + (((size_t)b * 16 + cg) * 1024) * 16 + cl * 4,
                    bpkb + (size_t)b * 65536 + n * 4, A, c0, h, P);
    } else {
        int g2 = g - 64, b = g2 >> 5, cg = g2 & 31, c = cg * 4 + cl;
        float A = -__expf(Als[c * 16 + n]);
        p1_chunk<0>(us + ((size_t)b * 128 + c) * Ln,
                    dspk + (((size_t)b * 32 + cg) * 1024) * 16 + cl * 4,
                    bpks + (size_t)b * 65536 + n * 4, A, c0, h, P);
    }
    int o = (g * NCHUNK + k) * 64 + lane;
    hf[o] = h; Pp[o] = P;
}

// ---- stitch (streaming, batches of 8) ----
__global__ void scan_stitch_kernel(const float* __restrict__ hf, const float* __restrict__ Pp,
                                   float* __restrict__ hi) {
    int id = blockIdx.x * blockDim.x + threadIdx.x;   // 0..8191
    int g = id >> 6, lane = id & 63;
    float h = 0.f;
    for (int kb = 0; kb < NCHUNK / 8; kb++) {
        float P8[8], H8[8];
#pragma unroll
        for (int j = 0; j < 8; j++) {
            int o = (g * NCHUNK + kb * 8 + j) * 64 + lane;
            P8[j] = Pp[o]; H8[j] = hf[o];
        }
#pragma unroll
        for (int j = 0; j < 8; j++) {
            int o = (g * NCHUNK + kb * 8 + j) * 64 + lane;
            hi[o] = h;
            h = fmaf(P8[j], h, H8[j]);
        }
    }
}

// ---- phase 2 ----
#define STEPP(u_, d_, B_, C_) ({ \
    float dA_ = __expf((d_) * A); \
    h = fmaf(dA_, h, (d_) * (u_) * (B_)); \
    float p_ = h * (C_); \
    DPPADD(p_); \
    fmaf((u_), Dc, p_); })

template <int MODE>  // 0 fwd, 1 rev, 2 sid
__device__ __forceinline__ void p2_chunk(const float* __restrict__ up, const float* __restrict__ dp,
                                         const float* __restrict__ bp, const float* __restrict__ cp,
                                         const int* __restrict__ sp, float* __restrict__ yp,
                                         float A, float Dc, int n, int c0, float h) {
    constexpr bool REV = (MODE == 1);
    constexpr bool SIDM = (MODE == 2);
    float4 U0[4], D0[4], B0[4], C0[4], U1[4], D1[4], B1[4], C1[4];
    int4 I0[4] = {}, I1[4] = {};
#define PHYS(ci) (REV ? (255 - (ci)) : (ci))
#define LOADC(U, D, Bb, Cc, I, ci) do { int pb_ = PHYS(ci) * 16; int tb_ = PHYS(ci) * 4; \
    _Pragma("unroll") for (int j_ = 0; j_ < 4; ++j_) { \
        U[j_]  = *(const float4*)(up + pb_ + 4 * j_); \
        D[j_]  = *(const float4*)(dp + (size_t)(tb_ + j_) * 16); \
        Bb[j_] = *(const float4*)(bp + (size_t)(tb_ + j_) * 64); \
        Cc[j_] = *(const float4*)(cp + (size_t)(tb_ + j_) * 64); \
        if (SIDM) I[j_] = *(const int4*)(sp + pb_ + 4 * j_); \
    } } while (0)
#define COMPC(U, D, Bb, Cc, I, ci) do { int pb_ = PHYS(ci) * 16; \
    if (SIDM) { \
        _Pragma("unroll") for (int j_ = 0; j_ < 4; ++j_) { \
            float y0_ = STEPP(U[j_].x, D[j_].x, Bb[j_].x, Cc[j_].x); if (n == 0) yp[I[j_].x] = y0_; \
            float y1_ = STEPP(U[j_].y, D[j_].y, Bb[j_].y, Cc[j_].y); if (n == 0) yp[I[j_].y] = y1_; \
            float y2_ = STEPP(U[j_].z, D[j_].z, Bb[j_].z, Cc[j_].z); if (n == 0) yp[I[j_].z] = y2_; \
            float y3_ = STEPP(U[j_].w, D[j_].w, Bb[j_].w, Cc[j_].w); if (n == 0) yp[I[j_].w] = y3_; \
        } \
    } else if (!REV) { \
        _Pragma("unroll") for (int j_ = 0; j_ < 4; ++j_) { \
            float4 y4_; \
            y4_.x = STEPP(U[j_].x, D[j_].x, Bb[j_].x, Cc[j_].x); \
            y4_.y = STEPP(U[j_].y, D[j_].y, Bb[j_].y, Cc[j_].y); \
            y4_.z = STEPP(U[j_].z, D[j_].z, Bb[j_].z, Cc[j_].z); \
            y4_.w = STEPP(U[j_].w, D[j_].w, Bb[j_].w, Cc[j_].w); \
            if (n == 0) *(float4*)(yp + pb_ + 4 * j_) = y4_; \
        } \
    } else { \
        _Pragma("unroll") for (int j_ = 3; j_ >= 0; --j_) { \
            float4 y4_; \
            y4_.w = STEPP(U[j_].w, D[j_].w, Bb[j_].w, Cc[j_].w); \
            y4_.z = STEPP(U[j_].z, D[j_].z, Bb[j_].z, Cc[j_].z); \
            y4_.y = STEPP(U[j_].y, D[j_].y, Bb[j_].y, Cc[j_].y); \
            y4_.x = STEPP(U[j_].x, D[j_].x, Bb[j_].x, Cc[j_].x); \
            if (n == 0) *(float4*)(yp + pb_ + 4 * j_) = y4_; \
        } \
    } } while (0)
    LOADC(U0, D0, B0, C0, I0, c0);
    for (int it = 0; it < CG; it += 2) {
        LOADC(U1, D1, B1, C1, I1, c0 + it + 1);
        COMPC(U0, D0, B0, C0, I0, c0 + it);
        if (it + 2 < CG) LOADC(U0, D0, B0, C0, I0, c0 + it + 2);
        COMPC(U1, D1, B1, C1, I1, c0 + it + 1);
    }
#undef PHYS
#undef LOADC
#undef COMPC
}

__global__ __launch_bounds__(256) void scan_p2_kernel(
    const float* __restrict__ xm, const float* __restrict__ us,
    const float* __restrict__ dfpk, const float* __restrict__ bpkf, const float* __restrict__ cpkf,
    const float* __restrict__ Alf, const float* __restrict__ Dfp,
    const float* __restrict__ dbpk, const float* __restrict__ bpkb, const float* __restrict__ cpkb,
    const float* __restrict__ Alb, const float* __restrict__ Dbp,
    const float* __restrict__ dspk, const float* __restrict__ bpks, const float* __restrict__ cpks,
    const float* __restrict__ Als, const float* __restrict__ Dsp,
    const int* __restrict__ sidx, const float* __restrict__ hi,
    float* __restrict__ yf, float* __restrict__ yb, float* __restrict__ ys) {
    int g = blockIdx.x * 4 + (threadIdx.x >> 6), k = blockIdx.y;
    int lane = threadIdx.x & 63;
    int n = lane & 15, cl = lane >> 4;
    int c0 = k * CG;
    float h0 = hi[(g * NCHUNK + k) * 64 + lane];
    if (g < 32) {
        int b = g >> 4, cg = g & 15, c = cg * 4 + cl;
        float A = -__expf(Alf[c * 16 + n]);
        p2_chunk<0>(xm + ((size_t)b * 128 + c) * Ln,
                    dfpk + (((size_t)b * 16 + cg) * 1024) * 16 + cl * 4,
                    bpkf + (size_t)b * 65536 + n * 4, cpkf + (size_t)b * 65536 + n * 4,
                    nullptr, yf + ((size_t)b * 64 + c) * Ln, A, Dfp[c], n, c0, h0);
    } else if (g < 64) {
        int g2 = g - 32, b = g2 >> 4, cg = g2 & 15, c = cg * 4 + cl;
        float A = -__expf(Alb[c * 16 + n]);
        p2_chunk<1>(xm + ((size_t)b * 128 + 64 + c) * Ln,
                    dbpk + (((size_t)b * 16 + cg) * 1024) * 16 + cl * 4,
                    bpkb + (size_t)b * 65536 + n * 4, cpkb + (size_t)b * 65536 + n * 4,
                    nullptr, yb + ((size_t)b * 64 + c) * Ln, A, Dbp[c], n, c0, h0);
    } else {
        int g2 = g - 64, b = g2 >> 5, cg = g2 & 31, c = cg * 4 + cl;
        float A = -__expf(Als[c * 16 + n]);
        p2_chunk<2>(us + ((size_t)b * 128 + c) * Ln,
                    dspk + (((size_t)b * 32 + cg) * 1024) * 16 + cl * 4,
                    bpks + (size_t)b * 65536 + n * 4, cpks + (size_t)b * 65536 + n * 4,
                    sidx + b * Ln, ys + ((size_t)b * 128 + c) * Ln, A, Dsp[c], n, c0, h0);
    }
}

// ---------------- fused = g*sid + (1-g)*cat (float4, in-place-safe) ----------------
__global__ void fuse_kernel(const float4* __restrict__ gate, const float4* __restrict__ ysb,
                            const float4* __restrict__ cat, float4* __restrict__ out, int n4) {
    int i = blockIdx.x * blockDim.x + threadIdx.x;
    if (i < n4) {
        float4 g = gate[i], s = ysb[i], c = cat[i], o;
        o.x = g.x * s.x + (1.f - g.x) * c.x;
        o.y = g.y * s.y + (1.f - g.y) * c.y;
        o.z = g.z * s.z + (1.f - g.z) * c.z;
        o.w = g.w * s.w + (1.f - g.w) * c.w;
        out[i] = o;
    }
}

extern "C" void kernel_launch(void* const* d_in, const int* in_sizes, int n_in,
                              void* d_out, int out_size, void* d_ws, size_t ws_size,
                              hipStream_t stream) {
    const float* x    = (const float*)d_in[0];
    const float* mfg  = (const float*)d_in[1];
    const float* mbg  = (const float*)d_in[2];
    const float* muc  = (const float*)d_in[3];
    const float* niw  = (const float*)d_in[4];
    const float* nib  = (const float*)d_in[5];
    const float* inw  = (const float*)d_in[6];
    const float* inb  = (const float*)d_in[7];
    const float* lmw  = (const float*)d_in[8];
    const float* lmb  = (const float*)d_in[9];
    const float* cmw  = (const float*)d_in[10];
    const float* cmb  = (const float*)d_in[11];
    const float* crw  = (const float*)d_in[12];
    const float* crb  = (const float*)d_in[13];
    const float* xwf  = (const float*)d_in[14];
    const float* xbf  = (const float*)d_in[15];
    const float* dtwf = (const float*)d_in[16];
    const float* dtbf = (const float*)d_in[17];
    const float* Alf  = (const float*)d_in[18];
    const float* Dfp  = (const float*)d_in[19];
    const float* xwb  = (const float*)d_in[20];
    const float* xbb  = (const float*)d_in[21];
    const float* dtwb = (const float*)d_in[22];
    const float* dtbb = (const float*)d_in[23];
    const float* Alb  = (const float*)d_in[24];
    const float* Dbp  = (const float*)d_in[25];
    const float* xws  = (const float*)d_in[26];
    const float* xbs  = (const float*)d_in[27];
    const float* dtws = (const float*)d_in[28];
    const float* dtbs = (const float*)d_in[29];
    const float* Als  = (const float*)d_in[30];
    const float* Dsp  = (const float*)d_in[31];
    const float* lcw  = (const float*)d_in[32];
    const float* lcb  = (const float*)d_in[33];
    const float* g0w  = (const float*)d_in[34];
    const float* g0b  = (const float*)d_in[35];
    const float* bng  = (const float*)d_in[36];
    const float* bnbe = (const float*)d_in[37];
    const float* bnm  = (const float*)d_in[38];
    const float* bnv  = (const float*)d_in[39];
    const float* g1w  = (const float*)d_in[40];
    const float* g1b  = (const float*)d_in[41];
    const float* outw = (const float*)d_in[42];
    const float* outb = (const float*)d_in[43];
    const float* now  = (const float*)d_in[44];
    const float* nob  = (const float*)d_in[45];

    float* W = (float*)d_ws;
    // ---- region plan (floats), total 10,493,952 (~42.0 MB) ----
    const size_t R_XP = 0;
    const size_t R_A  = 2097152;
    const size_t R_B  = 4194304;
    const size_t R_N  = 6291456;
    const size_t R_XM = 7340032;
    const size_t R_XR = 8388608;
    const size_t R_US = 9437184;
    const size_t R_IDX= 10485760;
    const size_t XNORM = R_N, XP = R_XP, XMN = R_N;
    const size_t XPJ0 = R_XP, XPJ1 = R_XP + 294912;
    const size_t DBLF = R_B, DBLB = R_B + 294912, DBLS = R_B + 589824;
    const size_t DFPK = R_N, DBPK = R_N + 524288, DSPK = R_B + 1048576;
    const size_t BPKF = R_A, CPKF = R_A + 131072, BPKB = R_A + 262144,
                 CPKB = R_A + 393216, BPKS = R_A + 524288, CPKS = R_A + 655360;
    const size_t XS0 = R_XP, XS1 = R_XP + 327680, XS2 = R_XP + 655360, XS3 = R_XP + 983040;
    const size_t HF = R_XP, PP = R_XP + 524288, HI = R_XP + 1048576;
    const size_t YF = R_A + 786432, YB = R_A + 1310720, YS = R_B;
    const size_t CATLN = R_N, FUSED = R_N;
    const size_t GBUF = R_XM, GATE = R_US, OUTB = R_US;

    int* idxp = (int*)(W + R_IDX);
    dim3 blk(256);
    const float* nil = nullptr;

    // 1. LN(x) -> XNORM
    ln_kernel<<<dim3(64, 2), blk, 0, stream>>>(x, nullptr, 128, niw, nib, W + XNORM, 128);
    // 2. in_proj conv, KS=2
    conv1x1_kernel<<<dim3(4, 128, 2), blk, 0, stream>>>(
        W + XNORM, nullptr, 128, 128, 0, 0, 256, 256, inw, nullptr, inb, nullptr, 0,
        nil, nil, nil, nil, 0, nullptr, 2, 64, W + R_A, W + R_B, nullptr, nullptr, 0);
    // 3. combine -> XP
    combine_kernel<<<2048, blk, 0, stream>>>(
        W + R_A, W + R_B, nullptr, nullptr, 2, inb, nil, nil, nil, nil, 0, W + XP, 256, 524288);
    // 4. LN(xp[:,0:128]) -> XMNORM
    ln_kernel<<<dim3(64, 2), blk, 0, stream>>>(W + XP, nullptr, 256, lmw, lmb, W + XMN, 128);
    // 5. dwconv -> XM, XR
    dwconv_kernel<<<dim3(16, 256, 2), blk, 0, stream>>>(
        W + XMN, W + XP, cmw, cmb, crw, crb, W + R_XM, W + R_XR);
    // 6. sort
    sort_kernel<<<2, 1024, 0, stream>>>(mfg, mbg, muc, idxp);
    // 7. xproj f+b fused conv, KS=2
    conv1x1_kernel<<<dim3(4, 18, 4), blk, 0, stream>>>(
        W + R_XM, nullptr, 64, 128, 0, 0, 36, 36, xwf, xwb, xbf, xbb, (long)64 * Ln,
        nil, nil, nil, nil, 0, nullptr, 2, 32, W + XPJ0, W + XPJ1, nullptr, nullptr, (long)589824);
    // 8. combines -> DBLF, DBLB
    combine_kernel<<<288, blk, 0, stream>>>(
        W + XPJ0, W + XPJ1, nullptr, nullptr, 2, xbf, nil, nil, nil, nil, 0, W + DBLF, 36, 73728);
    combine_kernel<<<288, blk, 0, stream>>>(
        W + XPJ0 + 589824, W + XPJ1 + 589824, nullptr, nullptr, 2, xbb,
        nil, nil, nil, nil, 0, W + DBLB, 36, 73728);
    // 9. delta f, b (packed, coalesced)
    delta_pack_kernel<4, 16><<<dim3(16, 16, 2), blk, 0, stream>>>(W + DBLF, 36, dtwf, dtbf, W + DFPK);
    delta_pack_kernel<4, 16><<<dim3(16, 16, 2), blk, 0, stream>>>(W + DBLB, 36, dtwb, dtbb, W + DBPK);
    // 10. gather -> US
    gather_kernel<<<dim3(16, 128, 2), blk, 0, stream>>>(W + R_XM, idxp, W + R_US);
    // 11. xproj_s conv, KS=4
    conv1x1_kernel<<<dim3(4, 40, 2), blk, 0, stream>>>(
        W + R_US, nullptr, 128, 128, 0, 0, 40, 40, xws, nullptr, xbs, nullptr, 0,
        nil, nil, nil, nil, 0, nullptr, 4, 32, W + XS0, W + XS1, W + XS2, W + XS3, 0);
    // 12. combine -> DBLS
    combine_kernel<<<320, blk, 0, stream>>>(
        W + XS0, W + XS1, W + XS2, W + XS3, 4, xbs, nil, nil, nil, nil, 0, W + DBLS, 40, 81920);
    // 13. pack B/C + delta s (packed, coalesced)
    pack_bc_kernel<<<dim3(64, 2, 3), blk, 0, stream>>>(
        W + DBLF, W + DBLB, W + DBLS,
        W + BPKF, W + CPKF, W + BPKB, W + CPKB, W + BPKS, W + CPKS);
    delta_pack_kernel<8, 32><<<dim3(16, 32, 2), blk, 0, stream>>>(W + DBLS, 40, dtws, dtbs, W + DSPK);
    // 14. chunked scan (4 chunk-waves per 256-thread block)
    scan_p1_kernel<<<dim3(32, NCHUNK), blk, 0, stream>>>(
        W + R_XM, W + R_US,
        W + DFPK, W + BPKF, Alf,
        W + DBPK, W + BPKB, Alb,
        W + DSPK, W + BPKS, Als,
        W + HF, W + PP);
    scan_stitch_kernel<<<32, 256, 0, stream>>>(W + HF, W + PP, W + HI);
    scan_p2_kernel<<<dim3(32, NCHUNK), blk, 0, stream>>>(
        W + R_XM, W + R_US,
        W + DFPK, W + BPKF, W + CPKF, Alf, Dfp,
        W + DBPK, W + BPKB, W + CPKB, Alb, Dbp,
        W + DSPK, W + BPKS, W + CPKS, Als, Dsp,
        idxp, W + HI, W + YF, W + YB, W + YS);
    // 15. LN(concat(yf,yb)) -> CATLN
    ln_kernel<<<dim3(64, 2), blk, 0, stream>>>(W + YF, W + YB, 64, lcw, lcb, W + CATLN, 128);
    // 16. g0 conv, KS=4 + combine(BN+ReLU) -> GBUF
    conv1x1_kernel<<<dim3(4, 128, 2), blk, 0, stream>>>(
        W + CATLN, W + YS, 128, 128, 128, 128, 128, 128, g0w, nullptr, g0b, nullptr, 0,
        nil, nil, nil, nil, 0, nullptr, 4, 64,
        W + R_A, W + R_A + 1048576, W + R_XP, W + R_XP + 1048576, 0);
    combine_kernel<<<1024, blk, 0, stream>>>(
        W + R_A, W + R_A + 1048576, W + R_XP, W + R_XP + 1048576, 4, g0b,
        bng, bnbe, bnm, bnv, 1, W + GBUF, 128, 262144);
    // 17. g1 conv, KS=2 + combine(sigmoid) -> GATE
    conv1x1_kernel<<<dim3(4, 64, 2), blk, 0, stream>>>(
        W + GBUF, nullptr, 128, 128, 0, 0, 128, 128, g1w, nullptr, g1b, nullptr, 0,
        nil, nil, nil, nil, 0, nullptr, 2, 64, W + R_A, W + R_A + 1048576, nullptr, nullptr, 0);
    combine_kernel<<<1024, blk, 0, stream>>>(
        W + R_A, W + R_A + 1048576, nullptr, nullptr, 2, g1b,
        nil, nil, nil, nil, 2, W + GATE, 128, 262144);
    // 18. fuse
    fuse_kernel<<<1024, blk, 0, stream>>>(
        (const float4*)(W + GATE), (const float4*)(W + YS), (const float4*)(W + CATLN),
        (float4*)(W + FUSED), Bn * Cn_ * Ln / 4);
    // 19. out conv, KS=4 + combine -> OUTB
    conv1x1_kernel<<<dim3(4, 128, 2), blk, 0, stream>>>(
        W + FUSED, W + R_XR, 128, 128, 128, 128, 128, 128, outw, nullptr, outb, nullptr, 0,
        nil, nil, nil, nil, 0, nullptr, 4, 64,
        W + R_A, W + R_A + 1048576, W + R_XP, W + R_XP + 1048576, 0);
    combine_kernel<<<1024, blk, 0, stream>>>(
        W + R_A, W + R_A + 1048576, W + R_XP, W + R_XP + 1048576, 4, outb,
        nil, nil, nil, nil, 0, W + OUTB, 128, 262144);
    // 20. final LN -> d_out
    ln_kernel<<<dim3(64, 2), blk, 0, stream>>>(W + OUTB, nullptr, 128, now, nob,
                                               (float*)d_out, 128);
}